// Round 10
// baseline (1105.185 us; speedup 1.0000x reference)
//
#include <hip/hip_runtime.h>
#include <math.h>

#define E_Nc 50000
#define F_Nc 25000
#define M_Nc 100000
#define P_Nc 75000
// D=128, HD=384, HEADS=3, DH=128

typedef unsigned short ushort;
typedef unsigned int uint;
typedef __attribute__((ext_vector_type(8))) short short8v;
typedef __attribute__((ext_vector_type(4))) float float4v;

static inline int cdiv(long a, long b) { return (int)((a + b - 1) / b); }

// ---------------------------------------------------------------------------
__device__ inline ushort f2b(float f) {  // RNE fp32 -> bf16
    uint u = __float_as_uint(f);
    u += 0x7fffu + ((u >> 16) & 1u);
    return (ushort)(u >> 16);
}
__device__ inline float b2f(ushort b) { return __uint_as_float((uint)b << 16); }

// Bijective XCD-chunked block swizzle (m204).
__device__ inline int xcd_swz(int bid, int nb) {
    int q = nb >> 3, r = nb & 7;
    int xcd = bid & 7, w = bid >> 3;
    return (xcd < r ? xcd * (q + 1) : r * (q + 1) + (xcd - r) * q) + w;
}

// 32-lane sum (within each 32-half of the wave), result in all lanes.
__device__ inline float rsum32(float v) {
    v += __uint_as_float(__builtin_amdgcn_update_dpp(
        0, __float_as_uint(v), 0xB1, 0xF, 0xF, true));   // quad_perm xor1
    v += __uint_as_float(__builtin_amdgcn_update_dpp(
        0, __float_as_uint(v), 0x4E, 0xF, 0xF, true));   // quad_perm xor2
    v += __uint_as_float(__builtin_amdgcn_update_dpp(
        0, __float_as_uint(v), 0x124, 0xF, 0xF, true));  // row_ror:4
    v += __uint_as_float(__builtin_amdgcn_update_dpp(
        0, __float_as_uint(v), 0x128, 0xF, 0xF, true));  // row_ror:8
    v += __shfl_xor(v, 16);
    return v;
}

// ---------------------------------------------------------------------------
__global__ void zero_f(float* __restrict__ p, int n) {
    int i = blockIdx.x * blockDim.x + threadIdx.x;
    if (i < n) p[i] = 0.f;
}

// ---------------------------------------------------------------------------
// Batched CSR build: 3 graphs in y-indexed jobs, 7 dispatches total.
// Scatter writes packed {src, aux} per edge.
struct CsrJob {
    const int* idx3;
    int col, srccol, P, n;
    int* cnt;
    int* rp;
    int2* epack;
    int* bsum;
};
struct CsrJobs { CsrJob j[3]; };

__global__ __launch_bounds__(256) void csr_zero(CsrJobs js) {
    const CsrJob& j = js.j[blockIdx.y];
    int i = blockIdx.x * 256 + threadIdx.x;
    if (i < j.n) j.cnt[i] = 0;
}

__global__ __launch_bounds__(256) void csr_count(CsrJobs js) {
    const CsrJob& j = js.j[blockIdx.y];
    int i = blockIdx.x * 256 + threadIdx.x;
    if (i < j.P) atomicAdd(&j.cnt[j.idx3[(size_t)i * 3 + j.col]], 1);
}

__global__ __launch_bounds__(256) void csr_scan_partial(CsrJobs js) {
    const CsrJob& j = js.j[blockIdx.y];
    __shared__ int lds[256];
    int b = blockIdx.x, t = threadIdx.x;
    int base = b * 1024 + t * 4;
    int s = 0;
    #pragma unroll
    for (int k = 0; k < 4; k++) { int i = base + k; if (i < j.n) s += j.cnt[i]; }
    lds[t] = s;
    __syncthreads();
    for (int off = 128; off > 0; off >>= 1) {
        if (t < off) lds[t] += lds[t + off];
        __syncthreads();
    }
    if (t == 0) j.bsum[b] = lds[0];
}

__global__ __launch_bounds__(64) void csr_scan_bsum(CsrJobs js) {
    const CsrJob& j = js.j[blockIdx.y];
    __shared__ int lds[64];
    int t = threadIdx.x;
    int v = j.bsum[t];
    lds[t] = v;
    __syncthreads();
    for (int off = 1; off < 64; off <<= 1) {
        int x = (t >= off) ? lds[t - off] : 0;
        __syncthreads();
        lds[t] += x;
        __syncthreads();
    }
    j.bsum[t] = lds[t] - v;  // exclusive
}

__global__ __launch_bounds__(256) void csr_scan_final(CsrJobs js) {
    const CsrJob& j = js.j[blockIdx.y];
    __shared__ int lds[256];
    int b = blockIdx.x, t = threadIdx.x;
    int base = b * 1024 + t * 4;
    int v[4];
    int s = 0;
    #pragma unroll
    for (int k = 0; k < 4; k++) {
        int i = base + k;
        v[k] = (i < j.n) ? j.cnt[i] : 0;
        s += v[k];
    }
    lds[t] = s;
    __syncthreads();
    for (int off = 1; off < 256; off <<= 1) {
        int x = (t >= off) ? lds[t - off] : 0;
        __syncthreads();
        lds[t] += x;
        __syncthreads();
    }
    int pre = j.bsum[b] + lds[t] - s;
    #pragma unroll
    for (int k = 0; k < 4; k++) {
        int i = base + k;
        if (i < j.n) j.rp[i] = pre;
        pre += v[k];
        if (i == j.n - 1) j.rp[j.n] = pre;
    }
}

__global__ __launch_bounds__(256) void csr_scatter(CsrJobs js) {
    const CsrJob& j = js.j[blockIdx.y];
    int i = blockIdx.x * 256 + threadIdx.x;
    if (i >= j.P) return;
    const int* row = j.idx3 + (size_t)i * 3;
    int d = row[j.col];
    int pos = atomicAdd(&j.cnt[d], 1);
    int2 pk;
    pk.x = row[j.srccol];
    pk.y = row[2];
    j.epack[j.rp[d] + pos] = pk;
}

// ---------------------------------------------------------------------------
// Wu_h = Wq_h @ We_h^T and G_h = Wq_h @ Wk_h^T (both fp32)
struct GuArgs { const float* wq[4]; const float* we[4]; const float* wk[4]; };
__global__ __launch_bounds__(256) void compute_gu(GuArgs a,
        float* __restrict__ Wu32, float* __restrict__ G32) {
    int idx = blockIdx.x * 256 + threadIdx.x;
    if (idx >= 2 * 12 * 16384) return;
    int sel = idx / (12 * 16384);
    int rem0 = idx - sel * (12 * 16384);
    int lh = rem0 >> 14;
    int l = lh / 3, h = lh - l * 3;
    int rem = rem0 & 16383;
    int c = rem >> 7, d = rem & 127;
    const float* Wq = a.wq[l];
    const float* Wo = sel ? a.wk[l] : a.we[l];
    float s = 0.f;
    #pragma unroll 4
    for (int jj = 0; jj < 128; jj++)
        s += Wq[d * 384 + h * 128 + jj] * Wo[c * 384 + h * 128 + jj];
    (sel ? G32 : Wu32)[rem0] = s;
}

// wkb[l][h*128+d] = sum_j Wk_l[d, h*128+j] * bq_l[h*128+j]
struct WkbArgs { const float* wk[4]; const float* bq[4]; };
__global__ void wkb_k(WkbArgs a, float* __restrict__ wkb32) {
    int idx = blockIdx.x * blockDim.x + threadIdx.x;
    if (idx >= 4 * 384) return;
    int l = idx / 384;
    int r = idx - l * 384;
    int h = r >> 7, d = r & 127;
    const float* Wk = a.wk[l];
    const float* bq = a.bq[l];
    float s = 0.f;
    for (int jj = 0; jj < 128; jj++)
        s += Wk[d * 384 + h * 128 + jj] * bq[h * 128 + jj];
    wkb32[idx] = s;
}

// bvm[l][c] = mean_h bv_l[h*128+c] -> biasPool slots
struct BvArgs { const float* bv[4]; };
__global__ void bvmean_k(BvArgs a, float* __restrict__ pool) {
    int idx = blockIdx.x * blockDim.x + threadIdx.x;
    if (idx >= 4 * 128) return;
    int l = idx >> 7, c = idx & 127;
    float v = (a.bv[l][c] + a.bv[l][128 + c] + a.bv[l][256 + c]) * (1.f / 3.f);
    pool[(l < 3 ? 3840 + l * 128 : 4224) + c] = v;
}

// bu_h[c] = sum_j bq_h[j] * We[c, h*128+j] -> biasPool slots
struct BuArgs { const float* bq[4]; const float* we[4]; };
__global__ void bias_u(BuArgs a, float* __restrict__ pool) {
    int idx = blockIdx.x * blockDim.x + threadIdx.x;
    if (idx >= 12 * 128) return;
    int lh = idx >> 7, c = idx & 127;
    int l = lh / 3, h = lh - l * 3;
    const float* bq = a.bq[l];
    const float* We = a.we[l];
    float s = 0.f;
    for (int jj = 0; jj < 128; jj++)
        s += bq[h * 128 + jj] * We[c * 384 + h * 128 + jj];
    int slot = (l < 3) ? (l * 960 + 384 + h * 128 + c)
                       : (2880 + 384 + h * 128 + c);
    pool[slot] = s;
}

// plain bias copies into biasPool
struct BDesc { const float* src; int dstoff, n; };
struct BDescs { BDesc d[8]; };
__global__ void copy_bias(BDescs ds, float* __restrict__ pool) {
    const BDesc b = ds.d[blockIdx.y];
    int i = blockIdx.x * 256 + threadIdx.x;
    if (i < b.n) pool[b.dstoff + i] = b.src[i];
}

// ---------------------------------------------------------------------------
// Weight prep: split fp32 weight into bf16 [hi(KK) | lo(KK)] rows.
struct WDesc {
    const float* in;
    long outoff;
    int ldin, coloff, NN, KK, trans, ldo;
};
struct WDescs { WDesc d[44]; int cnt; };

__global__ __launch_bounds__(256) void prep_weights(WDescs ds, ushort* __restrict__ out) {
    const WDesc w = ds.d[blockIdx.y];
    int i = blockIdx.x * 256 + threadIdx.x;
    if (i >= w.NN * w.KK) return;
    int n = i / w.KK, k = i - n * w.KK;
    float v = w.trans ? w.in[(size_t)k * w.ldin + w.coloff + n]
                      : w.in[(size_t)n * w.ldin + w.coloff + k];
    ushort hi = f2b(v);
    ushort lo = f2b(v - b2f(hi));
    long ro = w.outoff + (size_t)n * w.ldo;
    out[ro + k] = hi;
    out[ro + w.KK + k] = lo;
}

// ---------------------------------------------------------------------------
// CSR gather (fp32 out): aggr[f] = sum sgn * h_dE[e]
__global__ __launch_bounds__(256) void cob_gather(
        const float* __restrict__ h_dE, const int2* __restrict__ epack,
        const int* __restrict__ rp, float* __restrict__ out, int Fn) {
    int wave = (int)((blockIdx.x * (size_t)blockDim.x + threadIdx.x) >> 6);
    int lane = threadIdx.x & 63;
    if (wave >= Fn) return;
    float2 s = make_float2(0.f, 0.f);
    int beg = rp[wave], end = rp[wave + 1];
    for (int e = beg; e < end; e++) {
        int2 sp = epack[e];
        float sg = (float)sp.y;
        float2 v = *(const float2*)(h_dE + (size_t)sp.x * 128 + lane * 2);
        s.x += sg * v.x;
        s.y += sg * v.y;
    }
    *(float2*)(out + (size_t)wave * 128 + lane * 2) = s;
}

// ---------------------------------------------------------------------------
// Persistent-A split-bf16 x-projection GEMM (K = 128, 3-term fp32-accurate).
// Flattened grid + XCD-chunked swizzle. Store guard col < ldc allows narrow
// segments (Kvb ld=4 holds only 3 meaningful kvec cols).
#define TPB 3
struct SegInfo {
    float* base[5];
    int ld[5];
    int start[6];
    int nseg;
};

__global__ __launch_bounds__(256) void gemm_xproj(
        const float* __restrict__ A, int lda, int M,
        const ushort* __restrict__ Wt,
        const float* __restrict__ biasAll,
        SegInfo segs, int nys) {
    __shared__ ushort LDSu[64][264];  // A-stage, then B-tile [hi | lo]
    const int j = xcd_swz(blockIdx.x, gridDim.x);
    const int ys = j % nys;
    const int bm = (j / nys) * 64;
    const int t = threadIdx.x;
    const int lane = t & 63;
    const int wv = t >> 6;
    #pragma unroll
    for (int i = 0; i < 8; i++) {
        int li = t + i * 256;
        int r = li >> 5, q4 = li & 31;
        int m = bm + r;
        float4 v = make_float4(0.f, 0.f, 0.f, 0.f);
        if (m < M) v = *(const float4*)(A + (size_t)m * lda + q4 * 4);
        ushort h0 = f2b(v.x), h1 = f2b(v.y), h2 = f2b(v.z), h3 = f2b(v.w);
        ushort l0 = f2b(v.x - b2f(h0)), l1 = f2b(v.y - b2f(h1));
        ushort l2 = f2b(v.z - b2f(h2)), l3 = f2b(v.w - b2f(h3));
        *(uint2*)&LDSu[r][q4 * 4] =
            make_uint2((uint)h0 | ((uint)h1 << 16), (uint)h2 | ((uint)h3 << 16));
        *(uint2*)&LDSu[r][128 + q4 * 4] =
            make_uint2((uint)l0 | ((uint)l1 << 16), (uint)l2 | ((uint)l3 << 16));
    }
    __syncthreads();
    const int arow = wv * 16 + (lane & 15);
    const int kb = (lane >> 4) * 8;
    const int bcol = lane & 15;
    short8v a_hi[4], a_lo[4];
    #pragma unroll
    for (int kc = 0; kc < 4; kc++) {
        a_hi[kc] = *(const short8v*)&LDSu[arow][kc * 32 + kb];
        a_lo[kc] = *(const short8v*)&LDSu[arow][128 + kc * 32 + kb];
    }
    const int Ntot = segs.start[segs.nseg];
    const int bn0 = ys * (TPB * 64);
    const int bn1 = min(bn0 + TPB * 64, Ntot);
    if (bn0 >= Ntot) return;
    short8v breg[8];
    #pragma unroll
    for (int i = 0; i < 8; i++) {
        int li = t + i * 256;
        int r = li >> 5, g = li & 31;
        breg[i] = *(const short8v*)(Wt + (size_t)(bn0 + r) * 256 + g * 8);
    }
    int seg = 0;
    while (bn0 >= segs.start[seg + 1]) seg++;
    for (int bn = bn0; bn < bn1; bn += 64) {
        while (bn >= segs.start[seg + 1]) seg++;
        __syncthreads();
        #pragma unroll
        for (int i = 0; i < 8; i++) {
            int li = t + i * 256;
            int r = li >> 5, g = li & 31;
            *(short8v*)&LDSu[r][g * 8] = breg[i];
        }
        __syncthreads();
        if (bn + 64 < bn1) {
            #pragma unroll
            for (int i = 0; i < 8; i++) {
                int li = t + i * 256;
                int r = li >> 5, g = li & 31;
                breg[i] = *(const short8v*)(Wt + (size_t)(bn + 64 + r) * 256 + g * 8);
            }
        }
        float4v acc[4] = {{0.f, 0.f, 0.f, 0.f}, {0.f, 0.f, 0.f, 0.f},
                          {0.f, 0.f, 0.f, 0.f}, {0.f, 0.f, 0.f, 0.f}};
        #pragma unroll
        for (int kc = 0; kc < 4; kc++) {
            #pragma unroll
            for (int f = 0; f < 4; f++) {
                short8v bh = *(const short8v*)&LDSu[f * 16 + bcol][kc * 32 + kb];
                short8v bl = *(const short8v*)&LDSu[f * 16 + bcol][128 + kc * 32 + kb];
                acc[f] = __builtin_amdgcn_mfma_f32_16x16x32_bf16(a_hi[kc], bh, acc[f], 0, 0, 0);
                acc[f] = __builtin_amdgcn_mfma_f32_16x16x32_bf16(a_lo[kc], bh, acc[f], 0, 0, 0);
                acc[f] = __builtin_amdgcn_mfma_f32_16x16x32_bf16(a_hi[kc], bl, acc[f], 0, 0, 0);
            }
        }
        float* Cb = segs.base[seg];
        const int ldc = segs.ld[seg];
        const int coff = segs.start[seg];
        const int rb = bm + wv * 16 + ((lane >> 4) << 2);
        #pragma unroll
        for (int f = 0; f < 4; f++) {
            int ng = bn + f * 16 + bcol;
            float bias = biasAll[ng];
            int col = ng - coff;
            #pragma unroll
            for (int r = 0; r < 4; r++) {
                int row = rb + r;
                if (row < M && col < ldc)
                    Cb[(size_t)row * ldc + col] = acc[f][r] + bias;
            }
        }
    }
}

// ---------------------------------------------------------------------------
// Split-bf16 3-term GEMM, direct-register A (stage 2 only).
template <int OUTM, bool HASBIAS>
__global__ __launch_bounds__(256) void gemm_split(
        const float* __restrict__ A, int lda,
        const ushort* __restrict__ Wt, int ldw,
        const float* __restrict__ bias,
        float* __restrict__ C, int ldc,
        int M, int N, int kper) {
    __shared__ ushort Bs[64][264];
    const int koff = blockIdx.z * kper;
    const int bm = blockIdx.x * 64;
    const int bn = blockIdx.y * 64;
    const int t = threadIdx.x;
    const int lane = t & 63;
    const int wv = t >> 6;
    const int arow = wv * 16 + (lane & 15);
    const int kb = (lane >> 4) * 8;
    const int bcol = lane & 15;
    const int m = bm + arow;
    const bool mok = (m < M);
    const float* Arow = A + (size_t)m * lda + koff + kb;
    float4v acc[4] = {{0.f, 0.f, 0.f, 0.f}, {0.f, 0.f, 0.f, 0.f},
                      {0.f, 0.f, 0.f, 0.f}, {0.f, 0.f, 0.f, 0.f}};
    short8v breg[8];
    #pragma unroll
    for (int i = 0; i < 8; i++) {
        int li = t + i * 256;
        int r = li >> 5, g = li & 31;
        breg[i] = *(const short8v*)(Wt + (size_t)(bn + r) * ldw + (koff >> 7) * 256 + g * 8);
    }
    for (int c = 0; c < kper; c += 128) {
        __syncthreads();
        #pragma unroll
        for (int i = 0; i < 8; i++) {
            int li = t + i * 256;
            int r = li >> 5, g = li & 31;
            *(short8v*)&Bs[r][g * 8] = breg[i];
        }
        __syncthreads();
        if (c + 128 < kper) {
            const int nchunk = (koff + c + 128) >> 7;
            #pragma unroll
            for (int i = 0; i < 8; i++) {
                int li = t + i * 256;
                int r = li >> 5, g = li & 31;
                breg[i] = *(const short8v*)(Wt + (size_t)(bn + r) * ldw + nchunk * 256 + g * 8);
            }
        }
        short8v a_hi[4], a_lo[4];
        #pragma unroll
        for (int kc = 0; kc < 4; kc++) {
            float4 v0 = make_float4(0.f, 0.f, 0.f, 0.f);
            float4 v1 = make_float4(0.f, 0.f, 0.f, 0.f);
            if (mok) {
                v0 = *(const float4*)(Arow + c + kc * 32);
                v1 = *(const float4*)(Arow + c + kc * 32 + 4);
            }
            union { short8v v; ushort u[8]; } hi, lo;
            float vv[8] = {v0.x, v0.y, v0.z, v0.w, v1.x, v1.y, v1.z, v1.w};
            #pragma unroll
            for (int jj = 0; jj < 8; jj++) {
                ushort hj = f2b(vv[jj]);
                hi.u[jj] = hj;
                lo.u[jj] = f2b(vv[jj] - b2f(hj));
            }
            a_hi[kc] = hi.v;
            a_lo[kc] = lo.v;
        }
        #pragma unroll
        for (int kc = 0; kc < 4; kc++) {
            #pragma unroll
            for (int f = 0; f < 4; f++) {
                short8v bh = *(const short8v*)&Bs[f * 16 + bcol][kc * 32 + kb];
                short8v bl = *(const short8v*)&Bs[f * 16 + bcol][128 + kc * 32 + kb];
                acc[f] = __builtin_amdgcn_mfma_f32_16x16x32_bf16(a_hi[kc], bh, acc[f], 0, 0, 0);
                acc[f] = __builtin_amdgcn_mfma_f32_16x16x32_bf16(a_lo[kc], bh, acc[f], 0, 0, 0);
                acc[f] = __builtin_amdgcn_mfma_f32_16x16x32_bf16(a_hi[kc], bl, acc[f], 0, 0, 0);
            }
        }
    }
    const int rb = bm + wv * 16 + ((lane >> 4) << 2);
    #pragma unroll
    for (int f = 0; f < 4; f++) {
        int col = bn + f * 16 + bcol;
        #pragma unroll
        for (int r = 0; r < 4; r++) {
            int row = rb + r;
            if (row >= M) continue;
            float val = acc[f][r];
            if (HASBIAS) val += bias[col];
            size_t idx = (size_t)row * ldc + col;
            if (OUTM == 0) {
                C[idx] = val;
            } else if (OUTM == 1) {
                C[idx] += val;
            } else {
                atomicAdd(&C[idx], val);
            }
        }
    }
}

// ---------------------------------------------------------------------------
// YZ -> out projection GEMM v2: barrier-free, LDS-free, 64 rows x 32 cols.
// A row layout (from attn_fused): [hi(768) | lo(768)] ushorts; ping-pong
// chunk prefetch. B read per-wave directly from L2-resident Wyz (393 KB).
// Grid = cdiv(M,64)*4 blocks (4 col-tiles) -> ~6 blocks/CU, no barriers.
// Epilogue fuses bv-indicator (deg>0 from rp) and the residual add:
//   HASSEED=true  (stage 3): out[idx] += acc + seed[idx] + ind*bv  (out=h)
//   HASSEED=false (stage 4): out[idx] += acc + ind*bv  (out=dout, pre-seeded)
template <bool HASSEED>
__global__ __launch_bounds__(256) void gemm_yz(
        const ushort* __restrict__ A,
        const ushort* __restrict__ Wt,
        const float* __restrict__ seed,
        float* __restrict__ out,
        const int* __restrict__ rp,
        const float* __restrict__ bvm, int M) {
    const int j = xcd_swz(blockIdx.x, gridDim.x);
    const int by = j & 3;
    const int bm = (j >> 2) * 64;
    const int bn = by * 32;
    const int t = threadIdx.x;
    const int lane = t & 63;
    const int wv = t >> 6;
    const int arow = wv * 16 + (lane & 15);
    const int kb = (lane >> 4) * 8;
    const int bcol = lane & 15;
    const int m = bm + arow;
    const bool mok = (m < M);
    const ushort* Ar = A + (size_t)m * 1536 + kb;
    const ushort* Wb = Wt + (size_t)(bn + bcol) * 1536 + kb;
    const short8v z8 = {0, 0, 0, 0, 0, 0, 0, 0};
    short8v aH[2][4], aL[2][4];
    #pragma unroll
    for (int kc = 0; kc < 4; kc++) {
        aH[0][kc] = mok ? *(const short8v*)(Ar + kc * 32) : z8;
        aL[0][kc] = mok ? *(const short8v*)(Ar + 768 + kc * 32) : z8;
    }
    float4v acc[2] = {{0.f, 0.f, 0.f, 0.f}, {0.f, 0.f, 0.f, 0.f}};
    #pragma unroll
    for (int c = 0; c < 6; c++) {
        const int cur = c & 1, nxt = cur ^ 1;
        if (c < 5) {
            #pragma unroll
            for (int kc = 0; kc < 4; kc++) {
                aH[nxt][kc] = mok ? *(const short8v*)(Ar + (c + 1) * 128 + kc * 32) : z8;
                aL[nxt][kc] = mok ? *(const short8v*)(Ar + 768 + (c + 1) * 128 + kc * 32) : z8;
            }
        }
        #pragma unroll
        for (int kc = 0; kc < 4; kc++) {
            short8v bh0 = *(const short8v*)(Wb + c * 256 + kc * 32);
            short8v bl0 = *(const short8v*)(Wb + c * 256 + kc * 32 + 128);
            short8v bh1 = *(const short8v*)(Wb + 16 * 1536 + c * 256 + kc * 32);
            short8v bl1 = *(const short8v*)(Wb + 16 * 1536 + c * 256 + kc * 32 + 128);
            short8v ah = aH[cur][kc];
            short8v al = aL[cur][kc];
            acc[0] = __builtin_amdgcn_mfma_f32_16x16x32_bf16(ah, bh0, acc[0], 0, 0, 0);
            acc[0] = __builtin_amdgcn_mfma_f32_16x16x32_bf16(al, bh0, acc[0], 0, 0, 0);
            acc[0] = __builtin_amdgcn_mfma_f32_16x16x32_bf16(ah, bl0, acc[0], 0, 0, 0);
            acc[1] = __builtin_amdgcn_mfma_f32_16x16x32_bf16(ah, bh1, acc[1], 0, 0, 0);
            acc[1] = __builtin_amdgcn_mfma_f32_16x16x32_bf16(al, bh1, acc[1], 0, 0, 0);
            acc[1] = __builtin_amdgcn_mfma_f32_16x16x32_bf16(ah, bl1, acc[1], 0, 0, 0);
        }
    }
    const int rb = bm + wv * 16 + ((lane >> 4) << 2);
    float ind[4];
    #pragma unroll
    for (int r = 0; r < 4; r++) {
        int row = rb + r;
        ind[r] = (row < M && rp[row + 1] > rp[row]) ? 1.f : 0.f;
    }
    #pragma unroll
    for (int f = 0; f < 2; f++) {
        int col = bn + f * 16 + bcol;
        float bv = bvm[col];
        #pragma unroll
        for (int r = 0; r < 4; r++) {
            int row = rb + r;
            if (row >= M) continue;
            size_t idx = (size_t)row * 128 + col;
            float val = acc[f][r] + ind[r] * bv;
            if (HASSEED) val += seed[idx];
            out[idx] += val;
        }
    }
}

// ---------------------------------------------------------------------------
// Fused attention: 32 lanes per dst (2 dsts per wave), float4 per lane.
// alpha = (A1[dst]·x_s + U[dst]·ea + kvec[src])/sqrt(128).
// Reduce: DPP VALU tree (4 levels) + one xor-16 shfl.
// 3-deep rotating edge prefetch covers gather latency.
// YZ written as split-bf16 [hi(768)|lo(768)] ushorts per row for gemm_yz.
// (bv-indicator handled in gemm_yz epilogue via rp — no output RMW here.)
template <int EMODE>
__global__ __launch_bounds__(256) void attn_fused(
        const float* __restrict__ A1, const float* __restrict__ U,
        const float* __restrict__ X, const float* __restrict__ Esrc,
        const float* __restrict__ kvec, const int2* __restrict__ epack,
        const int* __restrict__ rp,
        ushort* __restrict__ YZ, int n_dst) {
    int dst = (int)((blockIdx.x * (size_t)blockDim.x + threadIdx.x) >> 5);
    int lane = threadIdx.x & 31;
    if (dst >= n_dst) return;
    const float* ap = A1 + (size_t)dst * 384;
    const float* up = U + (size_t)dst * 384;
    float4 a1[3], u[3], y[3], za[3];
    float m[3], den[3];
    #pragma unroll
    for (int h = 0; h < 3; h++) {
        a1[h] = *(const float4*)(ap + h * 128 + lane * 4);
        u[h] = *(const float4*)(up + h * 128 + lane * 4);
        y[h] = make_float4(0.f, 0.f, 0.f, 0.f);
        za[h] = make_float4(0.f, 0.f, 0.f, 0.f);
        m[h] = -INFINITY;
        den[h] = 0.f;
    }
    int beg = rp[dst], end = rp[dst + 1];
    auto loadE = [&](int e, float4& xs, float4& ea, float4& kv) {
        int2 sp = epack[e];
        xs = *(const float4*)(X + (size_t)sp.x * 128 + lane * 4);
        if (EMODE == 0) {
            ea = *(const float4*)(Esrc + (size_t)sp.y * 128 + lane * 4);
        } else {
            float sgn = (float)sp.y;
            ea = make_float4(xs.x * sgn, xs.y * sgn, xs.z * sgn, xs.w * sgn);
        }
        kv = *(const float4*)(kvec + (size_t)sp.x * 4);
    };
    float4 xA, eA, kA, xB, eB, kB;
    if (beg < end) loadE(beg, xA, eA, kA);
    if (beg + 1 < end) loadE(beg + 1, xB, eB, kB);
    for (int e = beg; e < end; e++) {
        float4 xC, eC, kC;
        if (e + 2 < end) loadE(e + 2, xC, eC, kC);
        float dot[3];
        #pragma unroll
        for (int h = 0; h < 3; h++)
            dot[h] = a1[h].x * xA.x + a1[h].y * xA.y +
                     a1[h].z * xA.z + a1[h].w * xA.w +
                     u[h].x * eA.x + u[h].y * eA.y +
                     u[h].z * eA.z + u[h].w * eA.w;
        #pragma unroll
        for (int h = 0; h < 3; h++) dot[h] = rsum32(dot[h]);
        float kvh[3] = {kA.x, kA.y, kA.z};
        #pragma unroll
        for (int h = 0; h < 3; h++) {
            float a = (dot[h] + kvh[h]) * 0.08838834764831845f;  // 1/sqrt(128)
            float mn = fmaxf(m[h], a);
            float scale = __expf(m[h] - mn);  // first edge: exp(-inf)=0
            float w = __expf(a - mn);
            den[h] = den[h] * scale + w;
            y[h].x = y[h].x * scale + w * xA.x;
            y[h].y = y[h].y * scale + w * xA.y;
            y[h].z = y[h].z * scale + w * xA.z;
            y[h].w = y[h].w * scale + w * xA.w;
            za[h].x = za[h].x * scale + w * eA.x;
            za[h].y = za[h].y * scale + w * eA.y;
            za[h].z = za[h].z * scale + w * eA.z;
            za[h].w = za[h].w * scale + w * eA.w;
            m[h] = mn;
        }
        xA = xB; eA = eB; kA = kB;
        xB = xC; eB = eC; kB = kC;
    }
    ushort* yrow = YZ + (size_t)dst * 1536;
    #pragma unroll
    for (int h = 0; h < 3; h++) {
        float inv = 1.f / (den[h] + 1e-16f) * (1.f / 3.f);
        float vy[4] = {y[h].x * inv, y[h].y * inv, y[h].z * inv, y[h].w * inv};
        float vz[4] = {za[h].x * inv, za[h].y * inv, za[h].z * inv, za[h].w * inv};
        ushort hy[4], ly[4], hz[4], lz[4];
        #pragma unroll
        for (int jj = 0; jj < 4; jj++) {
            hy[jj] = f2b(vy[jj]);
            ly[jj] = f2b(vy[jj] - b2f(hy[jj]));
            hz[jj] = f2b(vz[jj]);
            lz[jj] = f2b(vz[jj] - b2f(hz[jj]));
        }
        *(uint2*)(yrow + h * 128 + lane * 4) =
            make_uint2((uint)hy[0] | ((uint)hy[1] << 16), (uint)hy[2] | ((uint)hy[3] << 16));
        *(uint2*)(yrow + 768 + h * 128 + lane * 4) =
            make_uint2((uint)ly[0] | ((uint)ly[1] << 16), (uint)ly[2] | ((uint)ly[3] << 16));
        *(uint2*)(yrow + 384 + h * 128 + lane * 4) =
            make_uint2((uint)hz[0] | ((uint)hz[1] << 16), (uint)hz[2] | ((uint)hz[3] << 16));
        *(uint2*)(yrow + 768 + 384 + h * 128 + lane * 4) =
            make_uint2((uint)lz[0] | ((uint)lz[1] << 16), (uint)lz[2] | ((uint)lz[3] << 16));
    }
}

// ---------------------------------------------------------------------------
extern "C" void kernel_launch(void* const* d_in, const int* in_sizes, int n_in,
                              void* d_out, int out_size, void* d_ws, size_t ws_size,
                              hipStream_t stream) {
    const float* h_dE  = (const float*)d_in[0];
    const float* h_dF  = (const float*)d_in[1];
    const int*   cob   = (const int*)d_in[2];
    const int*   nn    = (const int*)d_in[3];
    const float* aggrW = (const float*)d_in[4];
    const float* aggrB = (const float*)d_in[5];
    const float* ctrW  = (const float*)d_in[6];
    const float* ctrB  = (const float*)d_in[7];
    const float* f_Wq  = (const float*)d_in[8];
    const float* f_bq  = (const float*)d_in[9];
    const float* f_Wk  = (const float*)d_in[10];
    const float* f_bk  = (const float*)d_in[11];
    const float* f_Wv  = (const float*)d_in[12];
    const float* f_bv  = (const float*)d_in[13];
    const float* f_We  = (const float*)d_in[14];
    const float* f_Ws  = (const float*)d_in[15];
    const float* f_bs  = (const float*)d_in[16];
    const float* e_Wq  = (const float*)d_in[17];
    const float* e_bq  = (const float*)d_in[18];
    const float* e_Wk  = (const float*)d_in[19];
    const float* e_bk  = (const float*)d_in[20];
    const float* e_Wv  = (const float*)d_in[21];
    const float* e_bv  = (const float*)d_in[22];
    const float* e_We  = (const float*)d_in[23];
    const float* e_Ws  = (const float*)d_in[24];
    const float* e_bs  = (const float*)d_in[25];

    const int CH = 25000;  // stage-4 dst chunk

    // ---- workspace ----
    char* base = (char*)d_ws;
    size_t off = 0;
    auto takeB = [&](size_t bytes) {
        char* p = base + off;
        off += (bytes + 15) & ~(size_t)15;
        return p;
    };
    float*  h     = (float*)takeB((size_t)F_Nc * 128 * 4);
    float*  A1f   = (float*)takeB((size_t)CH * 384 * 4);
    float*  Uf    = (float*)takeB((size_t)CH * 384 * 4);
    float*  YZb   = (float*)takeB((size_t)CH * 768 * 4);  // YZ bf16 rows / fp32 scratch
    float*  Kvb   = (float*)takeB((size_t)CH * 4 * 4);
    float*  Wu32  = (float*)takeB((size_t)12 * 16384 * 4);
    float*  G32   = (float*)takeB((size_t)12 * 16384 * 4);
    float*  wkb32 = (float*)takeB((size_t)4 * 384 * 4);
    float*  biasPool = (float*)takeB(4608 * 4);
    ushort* WtPool = (ushort*)takeB((size_t)2200000 * 2);
    int* rp_nn   = (int*)takeB((F_Nc + 1) * 4);
    int* rp_cobE = (int*)takeB((E_Nc + 1) * 4);
    int* rp_cobF = (int*)takeB((F_Nc + 1) * 4);
    int2* epk_nn = (int2*)takeB((size_t)P_Nc * 8);
    int2* epk_cE = (int2*)takeB((size_t)M_Nc * 8);
    int2* epk_cF = (int2*)takeB((size_t)M_Nc * 8);
    int* cnt_nn  = (int*)takeB((size_t)F_Nc * 4);
    int* cnt_cE  = (int*)takeB((size_t)E_Nc * 4);
    int* cnt_cF  = (int*)takeB((size_t)F_Nc * 4);
    int* bsum3   = (int*)takeB(3 * 64 * 4);
    if (ws_size < off) return;  // fail loud, not a fault

    const int BLK = 256;
    float* dout = (float*)d_out;
    ushort* YZu = (ushort*)YZb;

    const float* Wq4[4] = {f_Wq, f_Wq + 49152, f_Wq + 98304, e_Wq};
    const float* Wk4[4] = {f_Wk, f_Wk + 49152, f_Wk + 98304, e_Wk};
    const float* Wv4[4] = {f_Wv, f_Wv + 49152, f_Wv + 98304, e_Wv};
    const float* We4[4] = {f_We, f_We + 49152, f_We + 98304, e_We};
    const float* Ws4[4] = {f_Ws, f_Ws + 16384, f_Ws + 32768, e_Ws};
    const float* bq4[4] = {f_bq, f_bq + 384, f_bq + 768, e_bq};
    const float* bv4[4] = {f_bv, f_bv + 384, f_bv + 768, e_bv};

    // ---- derived weights (fp32) ----
    zero_f<<<cdiv(4608, BLK), BLK, 0, stream>>>(biasPool, 4608);
    GuArgs gua;
    BuArgs bua;
    WkbArgs wka;
    BvArgs bva;
    for (int l = 0; l < 4; l++) {
        gua.wq[l] = Wq4[l]; gua.we[l] = We4[l]; gua.wk[l] = Wk4[l];
        bua.bq[l] = bq4[l]; bua.we[l] = We4[l];
        wka.wk[l] = Wk4[l]; wka.bq[l] = bq4[l];
        bva.bv[l] = bv4[l];
    }
    compute_gu<<<cdiv(2 * 12 * 16384, BLK), BLK, 0, stream>>>(gua, Wu32, G32);
    bias_u<<<cdiv(12 * 128, BLK), BLK, 0, stream>>>(bua, biasPool);
    wkb_k<<<cdiv(4 * 384, BLK), BLK, 0, stream>>>(wka, wkb32);
    bvmean_k<<<cdiv(4 * 128, BLK), BLK, 0, stream>>>(bva, biasPool);

    // ---- bias copies: bs into xproj bias slots ----
    BDescs bd;
    int bi = 0;
    auto addb = [&](const float* s, int o, int n2) { bd.d[bi].src = s; bd.d[bi].dstoff = o; bd.d[bi].n = n2; bi++; };
    for (int l = 0; l < 3; l++) addb(f_bs + l * 128, l * 960 + 832, 128);
    addb(e_bs, 2880 + 768, 128);
    copy_bias<<<dim3(1, 4), BLK, 0, stream>>>(bd, biasPool);

    // ---- weight prep descriptors (split [hi|lo]) ----
    WDescs wd;
    int dc = 0;
    long wto = 0;
    auto addw = [&](const float* in, int ldin, int coloff, long outoff,
                    int NN, int KK, int trans, int ldo) {
        wd.d[dc].in = in; wd.d[dc].ldin = ldin; wd.d[dc].coloff = coloff;
        wd.d[dc].outoff = outoff; wd.d[dc].NN = NN; wd.d[dc].KK = KK;
        wd.d[dc].trans = trans; wd.d[dc].ldo = ldo; dc++;
    };
    long wx[3], w4e, w4h, wyz[4], waggr, wctr;
    for (int l = 0; l < 3; l++) {
        wx[l] = wto;
        addw(G32 + (long)l * 49152, 128, 0, wto, 384, 128, 0, 256);
        addw(Wu32 + (long)l * 49152, 128, 0, wto + 384L * 256, 384, 128, 0, 256);
        addw(wkb32 + (long)l * 384, 128, 0, wto + 768L * 256, 3, 128, 0, 256);
        addw(Ws4[l], 128, 0, wto + 832L * 256, 128, 128, 1, 256);
        wto += 960L * 256;
    }
    w4e = wto;
    addw(G32 + 3L * 49152, 128, 0, wto, 384, 128, 0, 256);
    addw(Wu32 + 3L * 49152, 128, 0, wto + 384L * 256, 384, 128, 0, 256);
    addw(e_Ws, 128, 0, wto + 768L * 256, 128, 128, 1, 256);
    wto += 896L * 256;
    w4h = wto;
    addw(wkb32 + 3L * 384, 128, 0, wto, 3, 128, 0, 256);
    wto += 64L * 256;
    for (int l = 0; l < 4; l++) {
        wyz[l] = wto;
        for (int hh = 0; hh < 3; hh++) {
            addw(Wv4[l], 384, hh * 128, wto + hh * 256, 128, 128, 1, 1536);
            addw(We4[l], 384, hh * 128, wto + (3 + hh) * 256, 128, 128, 1, 1536);
        }
        wto += 128L * 1536;
    }
    waggr = wto; addw(aggrW, 128, 0, wto, 128, 128, 1, 256); wto += 128 * 256;
    wctr  = wto; addw(ctrW,  128, 0, wto, 128, 128, 1, 256); wto += 128 * 256;
    wd.cnt = dc;  // 42
    prep_weights<<<dim3(192, dc), BLK, 0, stream>>>(wd, WtPool);

    // ---- batched CSR builds (7 dispatches) ----
    CsrJobs cj;
    cj.j[0] = {nn, 1, 0, P_Nc, F_Nc, cnt_nn, rp_nn, epk_nn, bsum3};
    cj.j[1] = {cob, 0, 1, M_Nc, E_Nc, cnt_cE, rp_cobE, epk_cE, bsum3 + 64};
    cj.j[2] = {cob, 1, 0, M_Nc, F_Nc, cnt_cF, rp_cobF, epk_cF, bsum3 + 128};
    csr_zero<<<dim3(cdiv(E_Nc, BLK), 3), BLK, 0, stream>>>(cj);
    csr_count<<<dim3(cdiv(M_Nc, BLK), 3), BLK, 0, stream>>>(cj);
    csr_scan_partial<<<dim3(cdiv(E_Nc, 1024), 3), BLK, 0, stream>>>(cj);
    csr_scan_bsum<<<dim3(1, 3), 64, 0, stream>>>(cj);
    csr_scan_final<<<dim3(cdiv(E_Nc, 1024), 3), BLK, 0, stream>>>(cj);
    csr_zero<<<dim3(cdiv(E_Nc, BLK), 3), BLK, 0, stream>>>(cj);
    csr_scatter<<<dim3(cdiv(M_Nc, BLK), 3), BLK, 0, stream>>>(cj);

    // ---- stage 1: aggr (fp32, in YZb scratch) ----
    cob_gather<<<cdiv((long)F_Nc * 64, BLK), BLK, 0, stream>>>(
        h_dE, epk_cF, rp_cobF, YZb, F_Nc);

    // ---- stage 2: h = aggr@aggrW + aggrB + h_dF@ctrW + ctrB ----
    gemm_split<0, true><<<dim3(cdiv(F_Nc, 64), 2, 1), BLK, 0, stream>>>(
        YZb, 128, WtPool + waggr, 256, aggrB, h, 128, F_Nc, 128, 128);
    gemm_split<1, true><<<dim3(cdiv(F_Nc, 64), 2, 1), BLK, 0, stream>>>(
        h_dF, 128, WtPool + wctr, 256, ctrB, h, 128, F_Nc, 128, 128);

    const int NXB = cdiv(F_Nc, 64);  // 391

    // ---- stage 3: three residual attention layers ----
    for (int l = 0; l < 3; l++) {
        SegInfo s3;
        s3.base[0] = A1f; s3.ld[0] = 384;
        s3.base[1] = Uf;  s3.ld[1] = 384;
        s3.base[2] = Kvb; s3.ld[2] = 4;      // 3 kvec cols, col<ld guard
        s3.base[3] = dout; s3.ld[3] = 128;   // Ws-skip + bs seeded into dout
        s3.base[4] = nullptr; s3.ld[4] = 0;
        s3.start[0] = 0; s3.start[1] = 384; s3.start[2] = 768;
        s3.start[3] = 832; s3.start[4] = 960; s3.start[5] = 960;
        s3.nseg = 4;
        gemm_xproj<<<dim3(NXB * 5), BLK, 0, stream>>>(
            h, 128, F_Nc, WtPool + wx[l], biasPool + l * 960, s3, 5);
        attn_fused<0><<<cdiv((long)F_Nc * 32, BLK), BLK, 0, stream>>>(
            A1f, Uf, h, h_dE, Kvb, epk_nn, rp_nn, YZu, F_Nc);
        gemm_yz<true><<<dim3(NXB * 4), BLK, 0, stream>>>(
            YZu, WtPool + wyz[l], dout, h, rp_nn,
            biasPool + 3840 + l * 128, F_Nc);
    }

    // ---- stage 4: final attention F -> E ----
    {   // kvec for all F src nodes (from h)
        SegInfo s4h;
        s4h.base[0] = Kvb; s4h.ld[0] = 4;
        s4h.base[1] = nullptr; s4h.base[2] = nullptr; s4h.base[3] = nullptr; s4h.base[4] = nullptr;
        s4h.ld[1] = 0; s4h.ld[2] = 0; s4h.ld[3] = 0; s4h.ld[4] = 0;
        s4h.start[0] = 0; s4h.start[1] = 64; s4h.start[2] = 64;
        s4h.start[3] = 64; s4h.start[4] = 64; s4h.start[5] = 64;
        s4h.nseg = 1;
        gemm_xproj<<<dim3(NXB), BLK, 0, stream>>>(
            h, 128, F_Nc, WtPool + w4h, biasPool + 3776, s4h, 1);
    }
    for (int c = 0; c < 2; c++) {
        int c0 = c * CH;
        SegInfo s4e;
        s4e.base[0] = A1f; s4e.ld[0] = 384;
        s4e.base[1] = Uf;  s4e.ld[1] = 384;
        s4e.base[2] = dout + (size_t)c0 * 128; s4e.ld[2] = 128;
        s4e.base[3] = nullptr; s4e.base[4] = nullptr; s4e.ld[3] = 0; s4e.ld[4] = 0;
        s4e.start[0] = 0; s4e.start[1] = 384; s4e.start[2] = 768;
        s4e.start[3] = 896; s4e.start[4] = 896; s4e.start[5] = 896;
        s4e.nseg = 3;
        gemm_xproj<<<dim3(cdiv(CH, 64) * 5), BLK, 0, stream>>>(
            h_dE + (size_t)c0 * 128, 128, CH, WtPool + w4e, biasPool + 2880, s4e, 5);
        attn_fused<1><<<cdiv((long)CH * 32, BLK), BLK, 0, stream>>>(
            A1f, Uf, h, h, Kvb, epk_cE, rp_cobE + c0, YZu, CH);
        gemm_yz<false><<<dim3(cdiv(CH, 64) * 4), BLK, 0, stream>>>(
            YZu, WtPool + wyz[3], nullptr, dout + (size_t)c0 * 128, rp_cobE + c0,
            biasPool + 4224, CH);
    }
}

// Round 11
// 783.176 us; speedup vs baseline: 1.4112x; 1.4112x over previous
//
#include <hip/hip_runtime.h>
#include <math.h>

#define E_Nc 50000
#define F_Nc 25000
#define M_Nc 100000
#define P_Nc 75000
// D=128, HD=384, HEADS=3, DH=128

typedef unsigned short ushort;
typedef unsigned int uint;
typedef __attribute__((ext_vector_type(8))) short short8v;
typedef __attribute__((ext_vector_type(4))) float float4v;

static inline int cdiv(long a, long b) { return (int)((a + b - 1) / b); }

// ---------------------------------------------------------------------------
__device__ inline ushort f2b(float f) {  // RNE fp32 -> bf16
    uint u = __float_as_uint(f);
    u += 0x7fffu + ((u >> 16) & 1u);
    return (ushort)(u >> 16);
}
__device__ inline float b2f(ushort b) { return __uint_as_float((uint)b << 16); }

// Bijective XCD-chunked block swizzle (m204).
__device__ inline int xcd_swz(int bid, int nb) {
    int q = nb >> 3, r = nb & 7;
    int xcd = bid & 7, w = bid >> 3;
    return (xcd < r ? xcd * (q + 1) : r * (q + 1) + (xcd - r) * q) + w;
}

// 32-lane sum (within each 32-half of the wave), result in all lanes.
__device__ inline float rsum32(float v) {
    v += __uint_as_float(__builtin_amdgcn_update_dpp(
        0, __float_as_uint(v), 0xB1, 0xF, 0xF, true));   // quad_perm xor1
    v += __uint_as_float(__builtin_amdgcn_update_dpp(
        0, __float_as_uint(v), 0x4E, 0xF, 0xF, true));   // quad_perm xor2
    v += __uint_as_float(__builtin_amdgcn_update_dpp(
        0, __float_as_uint(v), 0x124, 0xF, 0xF, true));  // row_ror:4
    v += __uint_as_float(__builtin_amdgcn_update_dpp(
        0, __float_as_uint(v), 0x128, 0xF, 0xF, true));  // row_ror:8
    v += __shfl_xor(v, 16);
    return v;
}

// ---------------------------------------------------------------------------
__global__ void zero_f(float* __restrict__ p, int n) {
    int i = blockIdx.x * blockDim.x + threadIdx.x;
    if (i < n) p[i] = 0.f;
}

// ---------------------------------------------------------------------------
// Batched CSR build: 3 graphs in y-indexed jobs, 7 dispatches total.
// Scatter writes packed {src, aux} per edge.
struct CsrJob {
    const int* idx3;
    int col, srccol, P, n;
    int* cnt;
    int* rp;
    int2* epack;
    int* bsum;
};
struct CsrJobs { CsrJob j[3]; };

__global__ __launch_bounds__(256) void csr_zero(CsrJobs js) {
    const CsrJob& j = js.j[blockIdx.y];
    int i = blockIdx.x * 256 + threadIdx.x;
    if (i < j.n) j.cnt[i] = 0;
}

__global__ __launch_bounds__(256) void csr_count(CsrJobs js) {
    const CsrJob& j = js.j[blockIdx.y];
    int i = blockIdx.x * 256 + threadIdx.x;
    if (i < j.P) atomicAdd(&j.cnt[j.idx3[(size_t)i * 3 + j.col]], 1);
}

__global__ __launch_bounds__(256) void csr_scan_partial(CsrJobs js) {
    const CsrJob& j = js.j[blockIdx.y];
    __shared__ int lds[256];
    int b = blockIdx.x, t = threadIdx.x;
    int base = b * 1024 + t * 4;
    int s = 0;
    #pragma unroll
    for (int k = 0; k < 4; k++) { int i = base + k; if (i < j.n) s += j.cnt[i]; }
    lds[t] = s;
    __syncthreads();
    for (int off = 128; off > 0; off >>= 1) {
        if (t < off) lds[t] += lds[t + off];
        __syncthreads();
    }
    if (t == 0) j.bsum[b] = lds[0];
}

__global__ __launch_bounds__(64) void csr_scan_bsum(CsrJobs js) {
    const CsrJob& j = js.j[blockIdx.y];
    __shared__ int lds[64];
    int t = threadIdx.x;
    int v = j.bsum[t];
    lds[t] = v;
    __syncthreads();
    for (int off = 1; off < 64; off <<= 1) {
        int x = (t >= off) ? lds[t - off] : 0;
        __syncthreads();
        lds[t] += x;
        __syncthreads();
    }
    j.bsum[t] = lds[t] - v;  // exclusive
}

__global__ __launch_bounds__(256) void csr_scan_final(CsrJobs js) {
    const CsrJob& j = js.j[blockIdx.y];
    __shared__ int lds[256];
    int b = blockIdx.x, t = threadIdx.x;
    int base = b * 1024 + t * 4;
    int v[4];
    int s = 0;
    #pragma unroll
    for (int k = 0; k < 4; k++) {
        int i = base + k;
        v[k] = (i < j.n) ? j.cnt[i] : 0;
        s += v[k];
    }
    lds[t] = s;
    __syncthreads();
    for (int off = 1; off < 256; off <<= 1) {
        int x = (t >= off) ? lds[t - off] : 0;
        __syncthreads();
        lds[t] += x;
        __syncthreads();
    }
    int pre = j.bsum[b] + lds[t] - s;
    #pragma unroll
    for (int k = 0; k < 4; k++) {
        int i = base + k;
        if (i < j.n) j.rp[i] = pre;
        pre += v[k];
        if (i == j.n - 1) j.rp[j.n] = pre;
    }
}

__global__ __launch_bounds__(256) void csr_scatter(CsrJobs js) {
    const CsrJob& j = js.j[blockIdx.y];
    int i = blockIdx.x * 256 + threadIdx.x;
    if (i >= j.P) return;
    const int* row = j.idx3 + (size_t)i * 3;
    int d = row[j.col];
    int pos = atomicAdd(&j.cnt[d], 1);
    int2 pk;
    pk.x = row[j.srccol];
    pk.y = row[2];
    j.epack[j.rp[d] + pos] = pk;
}

// ---------------------------------------------------------------------------
// Wu_h = Wq_h @ We_h^T and G_h = Wq_h @ Wk_h^T (both fp32)
struct GuArgs { const float* wq[4]; const float* we[4]; const float* wk[4]; };
__global__ __launch_bounds__(256) void compute_gu(GuArgs a,
        float* __restrict__ Wu32, float* __restrict__ G32) {
    int idx = blockIdx.x * 256 + threadIdx.x;
    if (idx >= 2 * 12 * 16384) return;
    int sel = idx / (12 * 16384);
    int rem0 = idx - sel * (12 * 16384);
    int lh = rem0 >> 14;
    int l = lh / 3, h = lh - l * 3;
    int rem = rem0 & 16383;
    int c = rem >> 7, d = rem & 127;
    const float* Wq = a.wq[l];
    const float* Wo = sel ? a.wk[l] : a.we[l];
    float s = 0.f;
    #pragma unroll 4
    for (int jj = 0; jj < 128; jj++)
        s += Wq[d * 384 + h * 128 + jj] * Wo[c * 384 + h * 128 + jj];
    (sel ? G32 : Wu32)[rem0] = s;
}

// wkb[l][h*128+d] = sum_j Wk_l[d, h*128+j] * bq_l[h*128+j]
struct WkbArgs { const float* wk[4]; const float* bq[4]; };
__global__ void wkb_k(WkbArgs a, float* __restrict__ wkb32) {
    int idx = blockIdx.x * blockDim.x + threadIdx.x;
    if (idx >= 4 * 384) return;
    int l = idx / 384;
    int r = idx - l * 384;
    int h = r >> 7, d = r & 127;
    const float* Wk = a.wk[l];
    const float* bq = a.bq[l];
    float s = 0.f;
    for (int jj = 0; jj < 128; jj++)
        s += Wk[d * 384 + h * 128 + jj] * bq[h * 128 + jj];
    wkb32[idx] = s;
}

// bvm[l][c] = mean_h bv_l[h*128+c] -> biasPool slots
struct BvArgs { const float* bv[4]; };
__global__ void bvmean_k(BvArgs a, float* __restrict__ pool) {
    int idx = blockIdx.x * blockDim.x + threadIdx.x;
    if (idx >= 4 * 128) return;
    int l = idx >> 7, c = idx & 127;
    float v = (a.bv[l][c] + a.bv[l][128 + c] + a.bv[l][256 + c]) * (1.f / 3.f);
    pool[(l < 3 ? 3840 + l * 128 : 4224) + c] = v;
}

// bu_h[c] = sum_j bq_h[j] * We[c, h*128+j] -> biasPool slots
struct BuArgs { const float* bq[4]; const float* we[4]; };
__global__ void bias_u(BuArgs a, float* __restrict__ pool) {
    int idx = blockIdx.x * blockDim.x + threadIdx.x;
    if (idx >= 12 * 128) return;
    int lh = idx >> 7, c = idx & 127;
    int l = lh / 3, h = lh - l * 3;
    const float* bq = a.bq[l];
    const float* We = a.we[l];
    float s = 0.f;
    for (int jj = 0; jj < 128; jj++)
        s += bq[h * 128 + jj] * We[c * 384 + h * 128 + jj];
    int slot = (l < 3) ? (l * 960 + 384 + h * 128 + c)
                       : (2880 + 384 + h * 128 + c);
    pool[slot] = s;
}

// plain bias copies into biasPool
struct BDesc { const float* src; int dstoff, n; };
struct BDescs { BDesc d[8]; };
__global__ void copy_bias(BDescs ds, float* __restrict__ pool) {
    const BDesc b = ds.d[blockIdx.y];
    int i = blockIdx.x * 256 + threadIdx.x;
    if (i < b.n) pool[b.dstoff + i] = b.src[i];
}

// ---------------------------------------------------------------------------
// Weight prep: split fp32 weight into bf16 [hi(KK) | lo(KK)] rows.
struct WDesc {
    const float* in;
    long outoff;
    int ldin, coloff, NN, KK, trans, ldo;
};
struct WDescs { WDesc d[44]; int cnt; };

__global__ __launch_bounds__(256) void prep_weights(WDescs ds, ushort* __restrict__ out) {
    const WDesc w = ds.d[blockIdx.y];
    int i = blockIdx.x * 256 + threadIdx.x;
    if (i >= w.NN * w.KK) return;
    int n = i / w.KK, k = i - n * w.KK;
    float v = w.trans ? w.in[(size_t)k * w.ldin + w.coloff + n]
                      : w.in[(size_t)n * w.ldin + w.coloff + k];
    ushort hi = f2b(v);
    ushort lo = f2b(v - b2f(hi));
    long ro = w.outoff + (size_t)n * w.ldo;
    out[ro + k] = hi;
    out[ro + w.KK + k] = lo;
}

// ---------------------------------------------------------------------------
// CSR gather (fp32 out): aggr[f] = sum sgn * h_dE[e]
__global__ __launch_bounds__(256) void cob_gather(
        const float* __restrict__ h_dE, const int2* __restrict__ epack,
        const int* __restrict__ rp, float* __restrict__ out, int Fn) {
    int wave = (int)((blockIdx.x * (size_t)blockDim.x + threadIdx.x) >> 6);
    int lane = threadIdx.x & 63;
    if (wave >= Fn) return;
    float2 s = make_float2(0.f, 0.f);
    int beg = rp[wave], end = rp[wave + 1];
    for (int e = beg; e < end; e++) {
        int2 sp = epack[e];
        float sg = (float)sp.y;
        float2 v = *(const float2*)(h_dE + (size_t)sp.x * 128 + lane * 2);
        s.x += sg * v.x;
        s.y += sg * v.y;
    }
    *(float2*)(out + (size_t)wave * 128 + lane * 2) = s;
}

// ---------------------------------------------------------------------------
// Persistent-A split-bf16 x-projection GEMM (K = 128, 3-term fp32-accurate).
// Flattened grid + XCD-chunked swizzle. Store guard col < ldc allows narrow
// segments (Kvb ld=4 holds only 3 meaningful kvec cols).
#define TPB 3
struct SegInfo {
    float* base[5];
    int ld[5];
    int start[6];
    int nseg;
};

__global__ __launch_bounds__(256) void gemm_xproj(
        const float* __restrict__ A, int lda, int M,
        const ushort* __restrict__ Wt,
        const float* __restrict__ biasAll,
        SegInfo segs, int nys) {
    __shared__ ushort LDSu[64][264];  // A-stage, then B-tile [hi | lo]
    const int j = xcd_swz(blockIdx.x, gridDim.x);
    const int ys = j % nys;
    const int bm = (j / nys) * 64;
    const int t = threadIdx.x;
    const int lane = t & 63;
    const int wv = t >> 6;
    #pragma unroll
    for (int i = 0; i < 8; i++) {
        int li = t + i * 256;
        int r = li >> 5, q4 = li & 31;
        int m = bm + r;
        float4 v = make_float4(0.f, 0.f, 0.f, 0.f);
        if (m < M) v = *(const float4*)(A + (size_t)m * lda + q4 * 4);
        ushort h0 = f2b(v.x), h1 = f2b(v.y), h2 = f2b(v.z), h3 = f2b(v.w);
        ushort l0 = f2b(v.x - b2f(h0)), l1 = f2b(v.y - b2f(h1));
        ushort l2 = f2b(v.z - b2f(h2)), l3 = f2b(v.w - b2f(h3));
        *(uint2*)&LDSu[r][q4 * 4] =
            make_uint2((uint)h0 | ((uint)h1 << 16), (uint)h2 | ((uint)h3 << 16));
        *(uint2*)&LDSu[r][128 + q4 * 4] =
            make_uint2((uint)l0 | ((uint)l1 << 16), (uint)l2 | ((uint)l3 << 16));
    }
    __syncthreads();
    const int arow = wv * 16 + (lane & 15);
    const int kb = (lane >> 4) * 8;
    const int bcol = lane & 15;
    short8v a_hi[4], a_lo[4];
    #pragma unroll
    for (int kc = 0; kc < 4; kc++) {
        a_hi[kc] = *(const short8v*)&LDSu[arow][kc * 32 + kb];
        a_lo[kc] = *(const short8v*)&LDSu[arow][128 + kc * 32 + kb];
    }
    const int Ntot = segs.start[segs.nseg];
    const int bn0 = ys * (TPB * 64);
    const int bn1 = min(bn0 + TPB * 64, Ntot);
    if (bn0 >= Ntot) return;
    short8v breg[8];
    #pragma unroll
    for (int i = 0; i < 8; i++) {
        int li = t + i * 256;
        int r = li >> 5, g = li & 31;
        breg[i] = *(const short8v*)(Wt + (size_t)(bn0 + r) * 256 + g * 8);
    }
    int seg = 0;
    while (bn0 >= segs.start[seg + 1]) seg++;
    for (int bn = bn0; bn < bn1; bn += 64) {
        while (bn >= segs.start[seg + 1]) seg++;
        __syncthreads();
        #pragma unroll
        for (int i = 0; i < 8; i++) {
            int li = t + i * 256;
            int r = li >> 5, g = li & 31;
            *(short8v*)&LDSu[r][g * 8] = breg[i];
        }
        __syncthreads();
        if (bn + 64 < bn1) {
            #pragma unroll
            for (int i = 0; i < 8; i++) {
                int li = t + i * 256;
                int r = li >> 5, g = li & 31;
                breg[i] = *(const short8v*)(Wt + (size_t)(bn + 64 + r) * 256 + g * 8);
            }
        }
        float4v acc[4] = {{0.f, 0.f, 0.f, 0.f}, {0.f, 0.f, 0.f, 0.f},
                          {0.f, 0.f, 0.f, 0.f}, {0.f, 0.f, 0.f, 0.f}};
        #pragma unroll
        for (int kc = 0; kc < 4; kc++) {
            #pragma unroll
            for (int f = 0; f < 4; f++) {
                short8v bh = *(const short8v*)&LDSu[f * 16 + bcol][kc * 32 + kb];
                short8v bl = *(const short8v*)&LDSu[f * 16 + bcol][128 + kc * 32 + kb];
                acc[f] = __builtin_amdgcn_mfma_f32_16x16x32_bf16(a_hi[kc], bh, acc[f], 0, 0, 0);
                acc[f] = __builtin_amdgcn_mfma_f32_16x16x32_bf16(a_lo[kc], bh, acc[f], 0, 0, 0);
                acc[f] = __builtin_amdgcn_mfma_f32_16x16x32_bf16(a_hi[kc], bl, acc[f], 0, 0, 0);
            }
        }
        float* Cb = segs.base[seg];
        const int ldc = segs.ld[seg];
        const int coff = segs.start[seg];
        const int rb = bm + wv * 16 + ((lane >> 4) << 2);
        #pragma unroll
        for (int f = 0; f < 4; f++) {
            int ng = bn + f * 16 + bcol;
            float bias = biasAll[ng];
            int col = ng - coff;
            #pragma unroll
            for (int r = 0; r < 4; r++) {
                int row = rb + r;
                if (row < M && col < ldc)
                    Cb[(size_t)row * ldc + col] = acc[f][r] + bias;
            }
        }
    }
}

// ---------------------------------------------------------------------------
// Split-bf16 3-term GEMM, direct-register A (stage 2 only).
template <int OUTM, bool HASBIAS>
__global__ __launch_bounds__(256) void gemm_split(
        const float* __restrict__ A, int lda,
        const ushort* __restrict__ Wt, int ldw,
        const float* __restrict__ bias,
        float* __restrict__ C, int ldc,
        int M, int N, int kper) {
    __shared__ ushort Bs[64][264];
    const int koff = blockIdx.z * kper;
    const int bm = blockIdx.x * 64;
    const int bn = blockIdx.y * 64;
    const int t = threadIdx.x;
    const int lane = t & 63;
    const int wv = t >> 6;
    const int arow = wv * 16 + (lane & 15);
    const int kb = (lane >> 4) * 8;
    const int bcol = lane & 15;
    const int m = bm + arow;
    const bool mok = (m < M);
    const float* Arow = A + (size_t)m * lda + koff + kb;
    float4v acc[4] = {{0.f, 0.f, 0.f, 0.f}, {0.f, 0.f, 0.f, 0.f},
                      {0.f, 0.f, 0.f, 0.f}, {0.f, 0.f, 0.f, 0.f}};
    short8v breg[8];
    #pragma unroll
    for (int i = 0; i < 8; i++) {
        int li = t + i * 256;
        int r = li >> 5, g = li & 31;
        breg[i] = *(const short8v*)(Wt + (size_t)(bn + r) * ldw + (koff >> 7) * 256 + g * 8);
    }
    for (int c = 0; c < kper; c += 128) {
        __syncthreads();
        #pragma unroll
        for (int i = 0; i < 8; i++) {
            int li = t + i * 256;
            int r = li >> 5, g = li & 31;
            *(short8v*)&Bs[r][g * 8] = breg[i];
        }
        __syncthreads();
        if (c + 128 < kper) {
            const int nchunk = (koff + c + 128) >> 7;
            #pragma unroll
            for (int i = 0; i < 8; i++) {
                int li = t + i * 256;
                int r = li >> 5, g = li & 31;
                breg[i] = *(const short8v*)(Wt + (size_t)(bn + r) * ldw + nchunk * 256 + g * 8);
            }
        }
        short8v a_hi[4], a_lo[4];
        #pragma unroll
        for (int kc = 0; kc < 4; kc++) {
            float4 v0 = make_float4(0.f, 0.f, 0.f, 0.f);
            float4 v1 = make_float4(0.f, 0.f, 0.f, 0.f);
            if (mok) {
                v0 = *(const float4*)(Arow + c + kc * 32);
                v1 = *(const float4*)(Arow + c + kc * 32 + 4);
            }
            union { short8v v; ushort u[8]; } hi, lo;
            float vv[8] = {v0.x, v0.y, v0.z, v0.w, v1.x, v1.y, v1.z, v1.w};
            #pragma unroll
            for (int jj = 0; jj < 8; jj++) {
                ushort hj = f2b(vv[jj]);
                hi.u[jj] = hj;
                lo.u[jj] = f2b(vv[jj] - b2f(hj));
            }
            a_hi[kc] = hi.v;
            a_lo[kc] = lo.v;
        }
        #pragma unroll
        for (int kc = 0; kc < 4; kc++) {
            #pragma unroll
            for (int f = 0; f < 4; f++) {
                short8v bh = *(const short8v*)&Bs[f * 16 + bcol][kc * 32 + kb];
                short8v bl = *(const short8v*)&Bs[f * 16 + bcol][128 + kc * 32 + kb];
                acc[f] = __builtin_amdgcn_mfma_f32_16x16x32_bf16(a_hi[kc], bh, acc[f], 0, 0, 0);
                acc[f] = __builtin_amdgcn_mfma_f32_16x16x32_bf16(a_lo[kc], bh, acc[f], 0, 0, 0);
                acc[f] = __builtin_amdgcn_mfma_f32_16x16x32_bf16(a_hi[kc], bl, acc[f], 0, 0, 0);
            }
        }
    }
    const int rb = bm + wv * 16 + ((lane >> 4) << 2);
    #pragma unroll
    for (int f = 0; f < 4; f++) {
        int col = bn + f * 16 + bcol;
        #pragma unroll
        for (int r = 0; r < 4; r++) {
            int row = rb + r;
            if (row >= M) continue;
            float val = acc[f][r];
            if (HASBIAS) val += bias[col];
            size_t idx = (size_t)row * ldc + col;
            if (OUTM == 0) {
                C[idx] = val;
            } else if (OUTM == 1) {
                C[idx] += val;
            } else {
                atomicAdd(&C[idx], val);
            }
        }
    }
}

// ---------------------------------------------------------------------------
// YZ -> out projection GEMM v3: LDS-staged (proven), 64 rows x 32 cols
// per block -> 4 col-tiles, grid = cdiv(M,64)*4 (~2x blocks vs v1), LDS
// halved to 16.9 KB. A row layout: [hi(768)|lo(768)] ushorts, ping-pong
// chunk prefetch; B staged via breg -> Bs per chunk.
// Epilogue fuses bv-indicator (deg>0 from rp) and the residual add:
//   HASSEED=true  (stage 3): out[idx] += acc + seed[idx] + ind*bv  (out=h)
//   HASSEED=false (stage 4): out[idx] += acc + ind*bv  (out=dout, pre-seeded)
template <bool HASSEED>
__global__ __launch_bounds__(256) void gemm_yz(
        const ushort* __restrict__ A,
        const ushort* __restrict__ Wt,
        const float* __restrict__ seed,
        float* __restrict__ out,
        const int* __restrict__ rp,
        const float* __restrict__ bvm, int M) {
    __shared__ ushort Bs[32][264];
    const int j = xcd_swz(blockIdx.x, gridDim.x);
    const int by = j & 3;
    const int bm = (j >> 2) * 64;
    const int bn = by * 32;
    const int t = threadIdx.x;
    const int lane = t & 63;
    const int wv = t >> 6;
    const int arow = wv * 16 + (lane & 15);
    const int kb = (lane >> 4) * 8;
    const int bcol = lane & 15;
    const int m = bm + arow;
    const bool mok = (m < M);
    const ushort* Ar = A + (size_t)m * 1536 + kb;
    const short8v z8 = {0, 0, 0, 0, 0, 0, 0, 0};
    short8v breg[4];
    #pragma unroll
    for (int i = 0; i < 4; i++) {
        int li = t + i * 256;
        int r = li >> 5, g = li & 31;
        breg[i] = *(const short8v*)(Wt + (size_t)(bn + r) * 1536 + g * 8);
    }
    short8v aH[2][4], aL[2][4];
    #pragma unroll
    for (int kc = 0; kc < 4; kc++) {
        aH[0][kc] = mok ? *(const short8v*)(Ar + kc * 32) : z8;
        aL[0][kc] = mok ? *(const short8v*)(Ar + 768 + kc * 32) : z8;
    }
    float4v acc[2] = {{0.f, 0.f, 0.f, 0.f}, {0.f, 0.f, 0.f, 0.f}};
    #pragma unroll
    for (int c = 0; c < 6; c++) {
        const int cur = c & 1, nxt = cur ^ 1;
        __syncthreads();
        #pragma unroll
        for (int i = 0; i < 4; i++) {
            int li = t + i * 256;
            int r = li >> 5, g = li & 31;
            *(short8v*)&Bs[r][g * 8] = breg[i];
        }
        __syncthreads();
        if (c < 5) {
            #pragma unroll
            for (int i = 0; i < 4; i++) {
                int li = t + i * 256;
                int r = li >> 5, g = li & 31;
                breg[i] = *(const short8v*)(Wt + (size_t)(bn + r) * 1536 + (c + 1) * 256 + g * 8);
            }
            #pragma unroll
            for (int kc = 0; kc < 4; kc++) {
                aH[nxt][kc] = mok ? *(const short8v*)(Ar + (c + 1) * 128 + kc * 32) : z8;
                aL[nxt][kc] = mok ? *(const short8v*)(Ar + 768 + (c + 1) * 128 + kc * 32) : z8;
            }
        }
        #pragma unroll
        for (int kc = 0; kc < 4; kc++) {
            short8v ah = aH[cur][kc];
            short8v al = aL[cur][kc];
            #pragma unroll
            for (int f = 0; f < 2; f++) {
                short8v bh = *(const short8v*)&Bs[f * 16 + bcol][kc * 32 + kb];
                short8v bl = *(const short8v*)&Bs[f * 16 + bcol][128 + kc * 32 + kb];
                acc[f] = __builtin_amdgcn_mfma_f32_16x16x32_bf16(ah, bh, acc[f], 0, 0, 0);
                acc[f] = __builtin_amdgcn_mfma_f32_16x16x32_bf16(al, bh, acc[f], 0, 0, 0);
                acc[f] = __builtin_amdgcn_mfma_f32_16x16x32_bf16(ah, bl, acc[f], 0, 0, 0);
            }
        }
    }
    const int rb = bm + wv * 16 + ((lane >> 4) << 2);
    float ind[4];
    #pragma unroll
    for (int r = 0; r < 4; r++) {
        int row = rb + r;
        ind[r] = (row < M && rp[row + 1] > rp[row]) ? 1.f : 0.f;
    }
    #pragma unroll
    for (int f = 0; f < 2; f++) {
        int col = bn + f * 16 + bcol;
        float bv = bvm[col];
        #pragma unroll
        for (int r = 0; r < 4; r++) {
            int row = rb + r;
            if (row >= M) continue;
            size_t idx = (size_t)row * 128 + col;
            float val = acc[f][r] + ind[r] * bv;
            if (HASSEED) val += seed[idx];
            out[idx] += val;
        }
    }
}

// ---------------------------------------------------------------------------
// Fused attention: 32 lanes per dst (2 dsts per wave), float4 per lane.
// alpha = (A1[dst]·x_s + U[dst]·ea + kvec[src])/sqrt(128).
// Reduce: DPP VALU tree (4 levels) + one xor-16 shfl.
// 3-deep rotating edge prefetch covers gather latency.
// YZ written as split-bf16 [hi(768)|lo(768)] ushorts per row for gemm_yz.
// (bv-indicator handled in gemm_yz epilogue via rp — no output RMW here.)
template <int EMODE>
__global__ __launch_bounds__(256) void attn_fused(
        const float* __restrict__ A1, const float* __restrict__ U,
        const float* __restrict__ X, const float* __restrict__ Esrc,
        const float* __restrict__ kvec, const int2* __restrict__ epack,
        const int* __restrict__ rp,
        ushort* __restrict__ YZ, int n_dst) {
    int dst = (int)((blockIdx.x * (size_t)blockDim.x + threadIdx.x) >> 5);
    int lane = threadIdx.x & 31;
    if (dst >= n_dst) return;
    const float* ap = A1 + (size_t)dst * 384;
    const float* up = U + (size_t)dst * 384;
    float4 a1[3], u[3], y[3], za[3];
    float m[3], den[3];
    #pragma unroll
    for (int h = 0; h < 3; h++) {
        a1[h] = *(const float4*)(ap + h * 128 + lane * 4);
        u[h] = *(const float4*)(up + h * 128 + lane * 4);
        y[h] = make_float4(0.f, 0.f, 0.f, 0.f);
        za[h] = make_float4(0.f, 0.f, 0.f, 0.f);
        m[h] = -INFINITY;
        den[h] = 0.f;
    }
    int beg = rp[dst], end = rp[dst + 1];
    auto loadE = [&](int e, float4& xs, float4& ea, float4& kv) {
        int2 sp = epack[e];
        xs = *(const float4*)(X + (size_t)sp.x * 128 + lane * 4);
        if (EMODE == 0) {
            ea = *(const float4*)(Esrc + (size_t)sp.y * 128 + lane * 4);
        } else {
            float sgn = (float)sp.y;
            ea = make_float4(xs.x * sgn, xs.y * sgn, xs.z * sgn, xs.w * sgn);
        }
        kv = *(const float4*)(kvec + (size_t)sp.x * 4);
    };
    float4 xA, eA, kA, xB, eB, kB;
    if (beg < end) loadE(beg, xA, eA, kA);
    if (beg + 1 < end) loadE(beg + 1, xB, eB, kB);
    for (int e = beg; e < end; e++) {
        float4 xC, eC, kC;
        if (e + 2 < end) loadE(e + 2, xC, eC, kC);
        float dot[3];
        #pragma unroll
        for (int h = 0; h < 3; h++)
            dot[h] = a1[h].x * xA.x + a1[h].y * xA.y +
                     a1[h].z * xA.z + a1[h].w * xA.w +
                     u[h].x * eA.x + u[h].y * eA.y +
                     u[h].z * eA.z + u[h].w * eA.w;
        #pragma unroll
        for (int h = 0; h < 3; h++) dot[h] = rsum32(dot[h]);
        float kvh[3] = {kA.x, kA.y, kA.z};
        #pragma unroll
        for (int h = 0; h < 3; h++) {
            float a = (dot[h] + kvh[h]) * 0.08838834764831845f;  // 1/sqrt(128)
            float mn = fmaxf(m[h], a);
            float scale = __expf(m[h] - mn);  // first edge: exp(-inf)=0
            float w = __expf(a - mn);
            den[h] = den[h] * scale + w;
            y[h].x = y[h].x * scale + w * xA.x;
            y[h].y = y[h].y * scale + w * xA.y;
            y[h].z = y[h].z * scale + w * xA.z;
            y[h].w = y[h].w * scale + w * xA.w;
            za[h].x = za[h].x * scale + w * eA.x;
            za[h].y = za[h].y * scale + w * eA.y;
            za[h].z = za[h].z * scale + w * eA.z;
            za[h].w = za[h].w * scale + w * eA.w;
            m[h] = mn;
        }
        xA = xB; eA = eB; kA = kB;
        xB = xC; eB = eC; kB = kC;
    }
    ushort* yrow = YZ + (size_t)dst * 1536;
    #pragma unroll
    for (int h = 0; h < 3; h++) {
        float inv = 1.f / (den[h] + 1e-16f) * (1.f / 3.f);
        float vy[4] = {y[h].x * inv, y[h].y * inv, y[h].z * inv, y[h].w * inv};
        float vz[4] = {za[h].x * inv, za[h].y * inv, za[h].z * inv, za[h].w * inv};
        ushort hy[4], ly[4], hz[4], lz[4];
        #pragma unroll
        for (int jj = 0; jj < 4; jj++) {
            hy[jj] = f2b(vy[jj]);
            ly[jj] = f2b(vy[jj] - b2f(hy[jj]));
            hz[jj] = f2b(vz[jj]);
            lz[jj] = f2b(vz[jj] - b2f(hz[jj]));
        }
        *(uint2*)(yrow + h * 128 + lane * 4) =
            make_uint2((uint)hy[0] | ((uint)hy[1] << 16), (uint)hy[2] | ((uint)hy[3] << 16));
        *(uint2*)(yrow + 768 + h * 128 + lane * 4) =
            make_uint2((uint)ly[0] | ((uint)ly[1] << 16), (uint)ly[2] | ((uint)ly[3] << 16));
        *(uint2*)(yrow + 384 + h * 128 + lane * 4) =
            make_uint2((uint)hz[0] | ((uint)hz[1] << 16), (uint)hz[2] | ((uint)hz[3] << 16));
        *(uint2*)(yrow + 768 + 384 + h * 128 + lane * 4) =
            make_uint2((uint)lz[0] | ((uint)lz[1] << 16), (uint)lz[2] | ((uint)lz[3] << 16));
    }
}

// ---------------------------------------------------------------------------
extern "C" void kernel_launch(void* const* d_in, const int* in_sizes, int n_in,
                              void* d_out, int out_size, void* d_ws, size_t ws_size,
                              hipStream_t stream) {
    const float* h_dE  = (const float*)d_in[0];
    const float* h_dF  = (const float*)d_in[1];
    const int*   cob   = (const int*)d_in[2];
    const int*   nn    = (const int*)d_in[3];
    const float* aggrW = (const float*)d_in[4];
    const float* aggrB = (const float*)d_in[5];
    const float* ctrW  = (const float*)d_in[6];
    const float* ctrB  = (const float*)d_in[7];
    const float* f_Wq  = (const float*)d_in[8];
    const float* f_bq  = (const float*)d_in[9];
    const float* f_Wk  = (const float*)d_in[10];
    const float* f_bk  = (const float*)d_in[11];
    const float* f_Wv  = (const float*)d_in[12];
    const float* f_bv  = (const float*)d_in[13];
    const float* f_We  = (const float*)d_in[14];
    const float* f_Ws  = (const float*)d_in[15];
    const float* f_bs  = (const float*)d_in[16];
    const float* e_Wq  = (const float*)d_in[17];
    const float* e_bq  = (const float*)d_in[18];
    const float* e_Wk  = (const float*)d_in[19];
    const float* e_bk  = (const float*)d_in[20];
    const float* e_Wv  = (const float*)d_in[21];
    const float* e_bv  = (const float*)d_in[22];
    const float* e_We  = (const float*)d_in[23];
    const float* e_Ws  = (const float*)d_in[24];
    const float* e_bs  = (const float*)d_in[25];

    const int CH = 25000;  // stage-4 dst chunk

    // ---- workspace ----
    char* base = (char*)d_ws;
    size_t off = 0;
    auto takeB = [&](size_t bytes) {
        char* p = base + off;
        off += (bytes + 15) & ~(size_t)15;
        return p;
    };
    float*  h     = (float*)takeB((size_t)F_Nc * 128 * 4);
    float*  A1f   = (float*)takeB((size_t)CH * 384 * 4);
    float*  Uf    = (float*)takeB((size_t)CH * 384 * 4);
    float*  YZb   = (float*)takeB((size_t)CH * 768 * 4);  // YZ bf16 rows / fp32 scratch
    float*  Kvb   = (float*)takeB((size_t)CH * 4 * 4);
    float*  Wu32  = (float*)takeB((size_t)12 * 16384 * 4);
    float*  G32   = (float*)takeB((size_t)12 * 16384 * 4);
    float*  wkb32 = (float*)takeB((size_t)4 * 384 * 4);
    float*  biasPool = (float*)takeB(4608 * 4);
    ushort* WtPool = (ushort*)takeB((size_t)2200000 * 2);
    int* rp_nn   = (int*)takeB((F_Nc + 1) * 4);
    int* rp_cobE = (int*)takeB((E_Nc + 1) * 4);
    int* rp_cobF = (int*)takeB((F_Nc + 1) * 4);
    int2* epk_nn = (int2*)takeB((size_t)P_Nc * 8);
    int2* epk_cE = (int2*)takeB((size_t)M_Nc * 8);
    int2* epk_cF = (int2*)takeB((size_t)M_Nc * 8);
    int* cnt_nn  = (int*)takeB((size_t)F_Nc * 4);
    int* cnt_cE  = (int*)takeB((size_t)E_Nc * 4);
    int* cnt_cF  = (int*)takeB((size_t)F_Nc * 4);
    int* bsum3   = (int*)takeB(3 * 64 * 4);
    if (ws_size < off) return;  // fail loud, not a fault

    const int BLK = 256;
    float* dout = (float*)d_out;
    ushort* YZu = (ushort*)YZb;

    const float* Wq4[4] = {f_Wq, f_Wq + 49152, f_Wq + 98304, e_Wq};
    const float* Wk4[4] = {f_Wk, f_Wk + 49152, f_Wk + 98304, e_Wk};
    const float* Wv4[4] = {f_Wv, f_Wv + 49152, f_Wv + 98304, e_Wv};
    const float* We4[4] = {f_We, f_We + 49152, f_We + 98304, e_We};
    const float* Ws4[4] = {f_Ws, f_Ws + 16384, f_Ws + 32768, e_Ws};
    const float* bq4[4] = {f_bq, f_bq + 384, f_bq + 768, e_bq};
    const float* bv4[4] = {f_bv, f_bv + 384, f_bv + 768, e_bv};

    // ---- derived weights (fp32) ----
    zero_f<<<cdiv(4608, BLK), BLK, 0, stream>>>(biasPool, 4608);
    GuArgs gua;
    BuArgs bua;
    WkbArgs wka;
    BvArgs bva;
    for (int l = 0; l < 4; l++) {
        gua.wq[l] = Wq4[l]; gua.we[l] = We4[l]; gua.wk[l] = Wk4[l];
        bua.bq[l] = bq4[l]; bua.we[l] = We4[l];
        wka.wk[l] = Wk4[l]; wka.bq[l] = bq4[l];
        bva.bv[l] = bv4[l];
    }
    compute_gu<<<cdiv(2 * 12 * 16384, BLK), BLK, 0, stream>>>(gua, Wu32, G32);
    bias_u<<<cdiv(12 * 128, BLK), BLK, 0, stream>>>(bua, biasPool);
    wkb_k<<<cdiv(4 * 384, BLK), BLK, 0, stream>>>(wka, wkb32);
    bvmean_k<<<cdiv(4 * 128, BLK), BLK, 0, stream>>>(bva, biasPool);

    // ---- bias copies: bs into xproj bias slots ----
    BDescs bd;
    int bi = 0;
    auto addb = [&](const float* s, int o, int n2) { bd.d[bi].src = s; bd.d[bi].dstoff = o; bd.d[bi].n = n2; bi++; };
    for (int l = 0; l < 3; l++) addb(f_bs + l * 128, l * 960 + 832, 128);
    addb(e_bs, 2880 + 768, 128);
    copy_bias<<<dim3(1, 4), BLK, 0, stream>>>(bd, biasPool);

    // ---- weight prep descriptors (split [hi|lo]) ----
    WDescs wd;
    int dc = 0;
    long wto = 0;
    auto addw = [&](const float* in, int ldin, int coloff, long outoff,
                    int NN, int KK, int trans, int ldo) {
        wd.d[dc].in = in; wd.d[dc].ldin = ldin; wd.d[dc].coloff = coloff;
        wd.d[dc].outoff = outoff; wd.d[dc].NN = NN; wd.d[dc].KK = KK;
        wd.d[dc].trans = trans; wd.d[dc].ldo = ldo; dc++;
    };
    long wx[3], w4e, w4h, wyz[4], waggr, wctr;
    for (int l = 0; l < 3; l++) {
        wx[l] = wto;
        addw(G32 + (long)l * 49152, 128, 0, wto, 384, 128, 0, 256);
        addw(Wu32 + (long)l * 49152, 128, 0, wto + 384L * 256, 384, 128, 0, 256);
        addw(wkb32 + (long)l * 384, 128, 0, wto + 768L * 256, 3, 128, 0, 256);
        addw(Ws4[l], 128, 0, wto + 832L * 256, 128, 128, 1, 256);
        wto += 960L * 256;
    }
    w4e = wto;
    addw(G32 + 3L * 49152, 128, 0, wto, 384, 128, 0, 256);
    addw(Wu32 + 3L * 49152, 128, 0, wto + 384L * 256, 384, 128, 0, 256);
    addw(e_Ws, 128, 0, wto + 768L * 256, 128, 128, 1, 256);
    wto += 896L * 256;
    w4h = wto;
    addw(wkb32 + 3L * 384, 128, 0, wto, 3, 128, 0, 256);
    wto += 64L * 256;
    for (int l = 0; l < 4; l++) {
        wyz[l] = wto;
        for (int hh = 0; hh < 3; hh++) {
            addw(Wv4[l], 384, hh * 128, wto + hh * 256, 128, 128, 1, 1536);
            addw(We4[l], 384, hh * 128, wto + (3 + hh) * 256, 128, 128, 1, 1536);
        }
        wto += 128L * 1536;
    }
    waggr = wto; addw(aggrW, 128, 0, wto, 128, 128, 1, 256); wto += 128 * 256;
    wctr  = wto; addw(ctrW,  128, 0, wto, 128, 128, 1, 256); wto += 128 * 256;
    wd.cnt = dc;  // 42
    prep_weights<<<dim3(192, dc), BLK, 0, stream>>>(wd, WtPool);

    // ---- batched CSR builds (7 dispatches) ----
    CsrJobs cj;
    cj.j[0] = {nn, 1, 0, P_Nc, F_Nc, cnt_nn, rp_nn, epk_nn, bsum3};
    cj.j[1] = {cob, 0, 1, M_Nc, E_Nc, cnt_cE, rp_cobE, epk_cE, bsum3 + 64};
    cj.j[2] = {cob, 1, 0, M_Nc, F_Nc, cnt_cF, rp_cobF, epk_cF, bsum3 + 128};
    csr_zero<<<dim3(cdiv(E_Nc, BLK), 3), BLK, 0, stream>>>(cj);
    csr_count<<<dim3(cdiv(M_Nc, BLK), 3), BLK, 0, stream>>>(cj);
    csr_scan_partial<<<dim3(cdiv(E_Nc, 1024), 3), BLK, 0, stream>>>(cj);
    csr_scan_bsum<<<dim3(1, 3), 64, 0, stream>>>(cj);
    csr_scan_final<<<dim3(cdiv(E_Nc, 1024), 3), BLK, 0, stream>>>(cj);
    csr_zero<<<dim3(cdiv(E_Nc, BLK), 3), BLK, 0, stream>>>(cj);
    csr_scatter<<<dim3(cdiv(M_Nc, BLK), 3), BLK, 0, stream>>>(cj);

    // ---- stage 1: aggr (fp32, in YZb scratch) ----
    cob_gather<<<cdiv((long)F_Nc * 64, BLK), BLK, 0, stream>>>(
        h_dE, epk_cF, rp_cobF, YZb, F_Nc);

    // ---- stage 2: h = aggr@aggrW + aggrB + h_dF@ctrW + ctrB ----
    gemm_split<0, true><<<dim3(cdiv(F_Nc, 64), 2, 1), BLK, 0, stream>>>(
        YZb, 128, WtPool + waggr, 256, aggrB, h, 128, F_Nc, 128, 128);
    gemm_split<1, true><<<dim3(cdiv(F_Nc, 64), 2, 1), BLK, 0, stream>>>(
        h_dF, 128, WtPool + wctr, 256, ctrB, h, 128, F_Nc, 128, 128);

    const int NXB = cdiv(F_Nc, 64);  // 391

    // ---- stage 3: three residual attention layers ----
    for (int l = 0; l < 3; l++) {
        SegInfo s3;
        s3.base[0] = A1f; s3.ld[0] = 384;
        s3.base[1] = Uf;  s3.ld[1] = 384;
        s3.base[2] = Kvb; s3.ld[2] = 4;      // 3 kvec cols, col<ld guard
        s3.base[3] = dout; s3.ld[3] = 128;   // Ws-skip + bs seeded into dout
        s3.base[4] = nullptr; s3.ld[4] = 0;
        s3.start[0] = 0; s3.start[1] = 384; s3.start[2] = 768;
        s3.start[3] = 832; s3.start[4] = 960; s3.start[5] = 960;
        s3.nseg = 4;
        gemm_xproj<<<dim3(NXB * 5), BLK, 0, stream>>>(
            h, 128, F_Nc, WtPool + wx[l], biasPool + l * 960, s3, 5);
        attn_fused<0><<<cdiv((long)F_Nc * 32, BLK), BLK, 0, stream>>>(
            A1f, Uf, h, h_dE, Kvb, epk_nn, rp_nn, YZu, F_Nc);
        gemm_yz<true><<<dim3(NXB * 4), BLK, 0, stream>>>(
            YZu, WtPool + wyz[l], dout, h, rp_nn,
            biasPool + 3840 + l * 128, F_Nc);
    }

    // ---- stage 4: final attention F -> E ----
    {   // kvec for all F src nodes (from h)
        SegInfo s4h;
        s4h.base[0] = Kvb; s4h.ld[0] = 4;
        s4h.base[1] = nullptr; s4h.base[2] = nullptr; s4h.base[3] = nullptr; s4h.base[4] = nullptr;
        s4h.ld[1] = 0; s4h.ld[2] = 0; s4h.ld[3] = 0; s4h.ld[4] = 0;
        s4h.start[0] = 0; s4h.start[1] = 64; s4h.start[2] = 64;
        s4h.start[3] = 64; s4h.start[4] = 64; s4h.start[5] = 64;
        s4h.nseg = 1;
        gemm_xproj<<<dim3(NXB), BLK, 0, stream>>>(
            h, 128, F_Nc, WtPool + w4h, biasPool + 3776, s4h, 1);
    }
    for (int c = 0; c < 2; c++) {
        int c0 = c * CH;
        SegInfo s4e;
        s4e.base[0] = A1f; s4e.ld[0] = 384;
        s4e.base[1] = Uf;  s4e.ld[1] = 384;
        s4e.base[2] = dout + (size_t)c0 * 128; s4e.ld[2] = 128;
        s4e.base[3] = nullptr; s4e.base[4] = nullptr; s4e.ld[3] = 0; s4e.ld[4] = 0;
        s4e.start[0] = 0; s4e.start[1] = 384; s4e.start[2] = 768;
        s4e.start[3] = 896; s4e.start[4] = 896; s4e.start[5] = 896;
        s4e.nseg = 3;
        gemm_xproj<<<dim3(cdiv(CH, 64) * 5), BLK, 0, stream>>>(
            h_dE + (size_t)c0 * 128, 128, CH, WtPool + w4e, biasPool + 2880, s4e, 5);
        attn_fused<1><<<cdiv((long)CH * 32, BLK), BLK, 0, stream>>>(
            A1f, Uf, h, h, Kvb, epk_cE, rp_cobE + c0, YZu, CH);
        gemm_yz<false><<<dim3(cdiv(CH, 64) * 4), BLK, 0, stream>>>(
            YZu, WtPool + wyz[3], nullptr, dout + (size_t)c0 * 128, rp_cobE + c0,
            biasPool + 4224, CH);
    }
}

// Round 12
// 755.704 us; speedup vs baseline: 1.4625x; 1.0364x over previous
//
#include <hip/hip_runtime.h>
#include <math.h>

#define E_Nc 50000
#define F_Nc 25000
#define M_Nc 100000
#define P_Nc 75000
// D=128, HD=384, HEADS=3, DH=128

typedef unsigned short ushort;
typedef unsigned int uint;
typedef __attribute__((ext_vector_type(8))) short short8v;
typedef __attribute__((ext_vector_type(4))) float float4v;

static inline int cdiv(long a, long b) { return (int)((a + b - 1) / b); }

// ---------------------------------------------------------------------------
__device__ inline ushort f2b(float f) {  // RNE fp32 -> bf16
    uint u = __float_as_uint(f);
    u += 0x7fffu + ((u >> 16) & 1u);
    return (ushort)(u >> 16);
}
__device__ inline float b2f(ushort b) { return __uint_as_float((uint)b << 16); }

// Bijective XCD-chunked block swizzle (m204).
__device__ inline int xcd_swz(int bid, int nb) {
    int q = nb >> 3, r = nb & 7;
    int xcd = bid & 7, w = bid >> 3;
    return (xcd < r ? xcd * (q + 1) : r * (q + 1) + (xcd - r) * q) + w;
}

// 32-lane sum (within each 32-half of the wave), result in all lanes.
__device__ inline float rsum32(float v) {
    v += __uint_as_float(__builtin_amdgcn_update_dpp(
        0, __float_as_uint(v), 0xB1, 0xF, 0xF, true));   // quad_perm xor1
    v += __uint_as_float(__builtin_amdgcn_update_dpp(
        0, __float_as_uint(v), 0x4E, 0xF, 0xF, true));   // quad_perm xor2
    v += __uint_as_float(__builtin_amdgcn_update_dpp(
        0, __float_as_uint(v), 0x124, 0xF, 0xF, true));  // row_ror:4
    v += __uint_as_float(__builtin_amdgcn_update_dpp(
        0, __float_as_uint(v), 0x128, 0xF, 0xF, true));  // row_ror:8
    v += __shfl_xor(v, 16);
    return v;
}

// ---------------------------------------------------------------------------
__global__ void zero_f(float* __restrict__ p, int n) {
    int i = blockIdx.x * blockDim.x + threadIdx.x;
    if (i < n) p[i] = 0.f;
}

// ---------------------------------------------------------------------------
// Batched CSR build: 3 graphs in y-indexed jobs, 7 dispatches total.
// Scatter writes packed {src, aux} per edge.
struct CsrJob {
    const int* idx3;
    int col, srccol, P, n;
    int* cnt;
    int* rp;
    int2* epack;
    int* bsum;
};
struct CsrJobs { CsrJob j[3]; };

__global__ __launch_bounds__(256) void csr_zero(CsrJobs js) {
    const CsrJob& j = js.j[blockIdx.y];
    int i = blockIdx.x * 256 + threadIdx.x;
    if (i < j.n) j.cnt[i] = 0;
}

__global__ __launch_bounds__(256) void csr_count(CsrJobs js) {
    const CsrJob& j = js.j[blockIdx.y];
    int i = blockIdx.x * 256 + threadIdx.x;
    if (i < j.P) atomicAdd(&j.cnt[j.idx3[(size_t)i * 3 + j.col]], 1);
}

__global__ __launch_bounds__(256) void csr_scan_partial(CsrJobs js) {
    const CsrJob& j = js.j[blockIdx.y];
    __shared__ int lds[256];
    int b = blockIdx.x, t = threadIdx.x;
    int base = b * 1024 + t * 4;
    int s = 0;
    #pragma unroll
    for (int k = 0; k < 4; k++) { int i = base + k; if (i < j.n) s += j.cnt[i]; }
    lds[t] = s;
    __syncthreads();
    for (int off = 128; off > 0; off >>= 1) {
        if (t < off) lds[t] += lds[t + off];
        __syncthreads();
    }
    if (t == 0) j.bsum[b] = lds[0];
}

__global__ __launch_bounds__(64) void csr_scan_bsum(CsrJobs js) {
    const CsrJob& j = js.j[blockIdx.y];
    __shared__ int lds[64];
    int t = threadIdx.x;
    int v = j.bsum[t];
    lds[t] = v;
    __syncthreads();
    for (int off = 1; off < 64; off <<= 1) {
        int x = (t >= off) ? lds[t - off] : 0;
        __syncthreads();
        lds[t] += x;
        __syncthreads();
    }
    j.bsum[t] = lds[t] - v;  // exclusive
}

__global__ __launch_bounds__(256) void csr_scan_final(CsrJobs js) {
    const CsrJob& j = js.j[blockIdx.y];
    __shared__ int lds[256];
    int b = blockIdx.x, t = threadIdx.x;
    int base = b * 1024 + t * 4;
    int v[4];
    int s = 0;
    #pragma unroll
    for (int k = 0; k < 4; k++) {
        int i = base + k;
        v[k] = (i < j.n) ? j.cnt[i] : 0;
        s += v[k];
    }
    lds[t] = s;
    __syncthreads();
    for (int off = 1; off < 256; off <<= 1) {
        int x = (t >= off) ? lds[t - off] : 0;
        __syncthreads();
        lds[t] += x;
        __syncthreads();
    }
    int pre = j.bsum[b] + lds[t] - s;
    #pragma unroll
    for (int k = 0; k < 4; k++) {
        int i = base + k;
        if (i < j.n) j.rp[i] = pre;
        pre += v[k];
        if (i == j.n - 1) j.rp[j.n] = pre;
    }
}

__global__ __launch_bounds__(256) void csr_scatter(CsrJobs js) {
    const CsrJob& j = js.j[blockIdx.y];
    int i = blockIdx.x * 256 + threadIdx.x;
    if (i >= j.P) return;
    const int* row = j.idx3 + (size_t)i * 3;
    int d = row[j.col];
    int pos = atomicAdd(&j.cnt[d], 1);
    int2 pk;
    pk.x = row[j.srccol];
    pk.y = row[2];
    j.epack[j.rp[d] + pos] = pk;
}

// ---------------------------------------------------------------------------
// Wu_h = Wq_h @ We_h^T and G_h = Wq_h @ Wk_h^T (both fp32)
struct GuArgs { const float* wq[4]; const float* we[4]; const float* wk[4]; };
__global__ __launch_bounds__(256) void compute_gu(GuArgs a,
        float* __restrict__ Wu32, float* __restrict__ G32) {
    int idx = blockIdx.x * 256 + threadIdx.x;
    if (idx >= 2 * 12 * 16384) return;
    int sel = idx / (12 * 16384);
    int rem0 = idx - sel * (12 * 16384);
    int lh = rem0 >> 14;
    int l = lh / 3, h = lh - l * 3;
    int rem = rem0 & 16383;
    int c = rem >> 7, d = rem & 127;
    const float* Wq = a.wq[l];
    const float* Wo = sel ? a.wk[l] : a.we[l];
    float s = 0.f;
    #pragma unroll 4
    for (int jj = 0; jj < 128; jj++)
        s += Wq[d * 384 + h * 128 + jj] * Wo[c * 384 + h * 128 + jj];
    (sel ? G32 : Wu32)[rem0] = s;
}

// wkb[l][h*128+d] = sum_j Wk_l[d, h*128+j] * bq_l[h*128+j]
struct WkbArgs { const float* wk[4]; const float* bq[4]; };
__global__ void wkb_k(WkbArgs a, float* __restrict__ wkb32) {
    int idx = blockIdx.x * blockDim.x + threadIdx.x;
    if (idx >= 4 * 384) return;
    int l = idx / 384;
    int r = idx - l * 384;
    int h = r >> 7, d = r & 127;
    const float* Wk = a.wk[l];
    const float* bq = a.bq[l];
    float s = 0.f;
    for (int jj = 0; jj < 128; jj++)
        s += Wk[d * 384 + h * 128 + jj] * bq[h * 128 + jj];
    wkb32[idx] = s;
}

// bvm[l][c] = mean_h bv_l[h*128+c] -> biasPool slots
struct BvArgs { const float* bv[4]; };
__global__ void bvmean_k(BvArgs a, float* __restrict__ pool) {
    int idx = blockIdx.x * blockDim.x + threadIdx.x;
    if (idx >= 4 * 128) return;
    int l = idx >> 7, c = idx & 127;
    float v = (a.bv[l][c] + a.bv[l][128 + c] + a.bv[l][256 + c]) * (1.f / 3.f);
    pool[(l < 3 ? 3840 + l * 128 : 4224) + c] = v;
}

// bu_h[c] = sum_j bq_h[j] * We[c, h*128+j] -> biasPool slots
struct BuArgs { const float* bq[4]; const float* we[4]; };
__global__ void bias_u(BuArgs a, float* __restrict__ pool) {
    int idx = blockIdx.x * blockDim.x + threadIdx.x;
    if (idx >= 12 * 128) return;
    int lh = idx >> 7, c = idx & 127;
    int l = lh / 3, h = lh - l * 3;
    const float* bq = a.bq[l];
    const float* We = a.we[l];
    float s = 0.f;
    for (int jj = 0; jj < 128; jj++)
        s += bq[h * 128 + jj] * We[c * 384 + h * 128 + jj];
    int slot = (l < 3) ? (l * 960 + 384 + h * 128 + c)
                       : (2880 + 384 + h * 128 + c);
    pool[slot] = s;
}

// plain bias copies into biasPool
struct BDesc { const float* src; int dstoff, n; };
struct BDescs { BDesc d[8]; };
__global__ void copy_bias(BDescs ds, float* __restrict__ pool) {
    const BDesc b = ds.d[blockIdx.y];
    int i = blockIdx.x * 256 + threadIdx.x;
    if (i < b.n) pool[b.dstoff + i] = b.src[i];
}

// ---------------------------------------------------------------------------
// Weight prep: split fp32 weight into bf16 [hi(KK) | lo(KK)] rows.
struct WDesc {
    const float* in;
    long outoff;
    int ldin, coloff, NN, KK, trans, ldo;
};
struct WDescs { WDesc d[44]; int cnt; };

__global__ __launch_bounds__(256) void prep_weights(WDescs ds, ushort* __restrict__ out) {
    const WDesc w = ds.d[blockIdx.y];
    int i = blockIdx.x * 256 + threadIdx.x;
    if (i >= w.NN * w.KK) return;
    int n = i / w.KK, k = i - n * w.KK;
    float v = w.trans ? w.in[(size_t)k * w.ldin + w.coloff + n]
                      : w.in[(size_t)n * w.ldin + w.coloff + k];
    ushort hi = f2b(v);
    ushort lo = f2b(v - b2f(hi));
    long ro = w.outoff + (size_t)n * w.ldo;
    out[ro + k] = hi;
    out[ro + w.KK + k] = lo;
}

// ---------------------------------------------------------------------------
// CSR gather (fp32 out): aggr[f] = sum sgn * h_dE[e]
__global__ __launch_bounds__(256) void cob_gather(
        const float* __restrict__ h_dE, const int2* __restrict__ epack,
        const int* __restrict__ rp, float* __restrict__ out, int Fn) {
    int wave = (int)((blockIdx.x * (size_t)blockDim.x + threadIdx.x) >> 6);
    int lane = threadIdx.x & 63;
    if (wave >= Fn) return;
    float2 s = make_float2(0.f, 0.f);
    int beg = rp[wave], end = rp[wave + 1];
    for (int e = beg; e < end; e++) {
        int2 sp = epack[e];
        float sg = (float)sp.y;
        float2 v = *(const float2*)(h_dE + (size_t)sp.x * 128 + lane * 2);
        s.x += sg * v.x;
        s.y += sg * v.y;
    }
    *(float2*)(out + (size_t)wave * 128 + lane * 2) = s;
}

// ---------------------------------------------------------------------------
// Persistent-A split-bf16 x-projection GEMM (K = 128, 3-term fp32-accurate).
// Flattened grid + XCD-chunked swizzle. Store guard col < ldc allows narrow
// segments (Kvb ld=4 holds only 3 meaningful kvec cols).
#define TPB 3
struct SegInfo {
    float* base[5];
    int ld[5];
    int start[6];
    int nseg;
};

__global__ __launch_bounds__(256) void gemm_xproj(
        const float* __restrict__ A, int lda, int M,
        const ushort* __restrict__ Wt,
        const float* __restrict__ biasAll,
        SegInfo segs, int nys) {
    __shared__ ushort LDSu[64][264];  // A-stage, then B-tile [hi | lo]
    const int j = xcd_swz(blockIdx.x, gridDim.x);
    const int ys = j % nys;
    const int bm = (j / nys) * 64;
    const int t = threadIdx.x;
    const int lane = t & 63;
    const int wv = t >> 6;
    #pragma unroll
    for (int i = 0; i < 8; i++) {
        int li = t + i * 256;
        int r = li >> 5, q4 = li & 31;
        int m = bm + r;
        float4 v = make_float4(0.f, 0.f, 0.f, 0.f);
        if (m < M) v = *(const float4*)(A + (size_t)m * lda + q4 * 4);
        ushort h0 = f2b(v.x), h1 = f2b(v.y), h2 = f2b(v.z), h3 = f2b(v.w);
        ushort l0 = f2b(v.x - b2f(h0)), l1 = f2b(v.y - b2f(h1));
        ushort l2 = f2b(v.z - b2f(h2)), l3 = f2b(v.w - b2f(h3));
        *(uint2*)&LDSu[r][q4 * 4] =
            make_uint2((uint)h0 | ((uint)h1 << 16), (uint)h2 | ((uint)h3 << 16));
        *(uint2*)&LDSu[r][128 + q4 * 4] =
            make_uint2((uint)l0 | ((uint)l1 << 16), (uint)l2 | ((uint)l3 << 16));
    }
    __syncthreads();
    const int arow = wv * 16 + (lane & 15);
    const int kb = (lane >> 4) * 8;
    const int bcol = lane & 15;
    short8v a_hi[4], a_lo[4];
    #pragma unroll
    for (int kc = 0; kc < 4; kc++) {
        a_hi[kc] = *(const short8v*)&LDSu[arow][kc * 32 + kb];
        a_lo[kc] = *(const short8v*)&LDSu[arow][128 + kc * 32 + kb];
    }
    const int Ntot = segs.start[segs.nseg];
    const int bn0 = ys * (TPB * 64);
    const int bn1 = min(bn0 + TPB * 64, Ntot);
    if (bn0 >= Ntot) return;
    short8v breg[8];
    #pragma unroll
    for (int i = 0; i < 8; i++) {
        int li = t + i * 256;
        int r = li >> 5, g = li & 31;
        breg[i] = *(const short8v*)(Wt + (size_t)(bn0 + r) * 256 + g * 8);
    }
    int seg = 0;
    while (bn0 >= segs.start[seg + 1]) seg++;
    for (int bn = bn0; bn < bn1; bn += 64) {
        while (bn >= segs.start[seg + 1]) seg++;
        __syncthreads();
        #pragma unroll
        for (int i = 0; i < 8; i++) {
            int li = t + i * 256;
            int r = li >> 5, g = li & 31;
            *(short8v*)&LDSu[r][g * 8] = breg[i];
        }
        __syncthreads();
        if (bn + 64 < bn1) {
            #pragma unroll
            for (int i = 0; i < 8; i++) {
                int li = t + i * 256;
                int r = li >> 5, g = li & 31;
                breg[i] = *(const short8v*)(Wt + (size_t)(bn + 64 + r) * 256 + g * 8);
            }
        }
        float4v acc[4] = {{0.f, 0.f, 0.f, 0.f}, {0.f, 0.f, 0.f, 0.f},
                          {0.f, 0.f, 0.f, 0.f}, {0.f, 0.f, 0.f, 0.f}};
        #pragma unroll
        for (int kc = 0; kc < 4; kc++) {
            #pragma unroll
            for (int f = 0; f < 4; f++) {
                short8v bh = *(const short8v*)&LDSu[f * 16 + bcol][kc * 32 + kb];
                short8v bl = *(const short8v*)&LDSu[f * 16 + bcol][128 + kc * 32 + kb];
                acc[f] = __builtin_amdgcn_mfma_f32_16x16x32_bf16(a_hi[kc], bh, acc[f], 0, 0, 0);
                acc[f] = __builtin_amdgcn_mfma_f32_16x16x32_bf16(a_lo[kc], bh, acc[f], 0, 0, 0);
                acc[f] = __builtin_amdgcn_mfma_f32_16x16x32_bf16(a_hi[kc], bl, acc[f], 0, 0, 0);
            }
        }
        float* Cb = segs.base[seg];
        const int ldc = segs.ld[seg];
        const int coff = segs.start[seg];
        const int rb = bm + wv * 16 + ((lane >> 4) << 2);
        #pragma unroll
        for (int f = 0; f < 4; f++) {
            int ng = bn + f * 16 + bcol;
            float bias = biasAll[ng];
            int col = ng - coff;
            #pragma unroll
            for (int r = 0; r < 4; r++) {
                int row = rb + r;
                if (row < M && col < ldc)
                    Cb[(size_t)row * ldc + col] = acc[f][r] + bias;
            }
        }
    }
}

// ---------------------------------------------------------------------------
// Split-bf16 3-term GEMM, direct-register A (stage 2 only).
template <int OUTM, bool HASBIAS>
__global__ __launch_bounds__(256) void gemm_split(
        const float* __restrict__ A, int lda,
        const ushort* __restrict__ Wt, int ldw,
        const float* __restrict__ bias,
        float* __restrict__ C, int ldc,
        int M, int N, int kper) {
    __shared__ ushort Bs[64][264];
    const int koff = blockIdx.z * kper;
    const int bm = blockIdx.x * 64;
    const int bn = blockIdx.y * 64;
    const int t = threadIdx.x;
    const int lane = t & 63;
    const int wv = t >> 6;
    const int arow = wv * 16 + (lane & 15);
    const int kb = (lane >> 4) * 8;
    const int bcol = lane & 15;
    const int m = bm + arow;
    const bool mok = (m < M);
    const float* Arow = A + (size_t)m * lda + koff + kb;
    float4v acc[4] = {{0.f, 0.f, 0.f, 0.f}, {0.f, 0.f, 0.f, 0.f},
                      {0.f, 0.f, 0.f, 0.f}, {0.f, 0.f, 0.f, 0.f}};
    short8v breg[8];
    #pragma unroll
    for (int i = 0; i < 8; i++) {
        int li = t + i * 256;
        int r = li >> 5, g = li & 31;
        breg[i] = *(const short8v*)(Wt + (size_t)(bn + r) * ldw + (koff >> 7) * 256 + g * 8);
    }
    for (int c = 0; c < kper; c += 128) {
        __syncthreads();
        #pragma unroll
        for (int i = 0; i < 8; i++) {
            int li = t + i * 256;
            int r = li >> 5, g = li & 31;
            *(short8v*)&Bs[r][g * 8] = breg[i];
        }
        __syncthreads();
        if (c + 128 < kper) {
            const int nchunk = (koff + c + 128) >> 7;
            #pragma unroll
            for (int i = 0; i < 8; i++) {
                int li = t + i * 256;
                int r = li >> 5, g = li & 31;
                breg[i] = *(const short8v*)(Wt + (size_t)(bn + r) * ldw + nchunk * 256 + g * 8);
            }
        }
        short8v a_hi[4], a_lo[4];
        #pragma unroll
        for (int kc = 0; kc < 4; kc++) {
            float4 v0 = make_float4(0.f, 0.f, 0.f, 0.f);
            float4 v1 = make_float4(0.f, 0.f, 0.f, 0.f);
            if (mok) {
                v0 = *(const float4*)(Arow + c + kc * 32);
                v1 = *(const float4*)(Arow + c + kc * 32 + 4);
            }
            union { short8v v; ushort u[8]; } hi, lo;
            float vv[8] = {v0.x, v0.y, v0.z, v0.w, v1.x, v1.y, v1.z, v1.w};
            #pragma unroll
            for (int jj = 0; jj < 8; jj++) {
                ushort hj = f2b(vv[jj]);
                hi.u[jj] = hj;
                lo.u[jj] = f2b(vv[jj] - b2f(hj));
            }
            a_hi[kc] = hi.v;
            a_lo[kc] = lo.v;
        }
        #pragma unroll
        for (int kc = 0; kc < 4; kc++) {
            #pragma unroll
            for (int f = 0; f < 4; f++) {
                short8v bh = *(const short8v*)&Bs[f * 16 + bcol][kc * 32 + kb];
                short8v bl = *(const short8v*)&Bs[f * 16 + bcol][128 + kc * 32 + kb];
                acc[f] = __builtin_amdgcn_mfma_f32_16x16x32_bf16(a_hi[kc], bh, acc[f], 0, 0, 0);
                acc[f] = __builtin_amdgcn_mfma_f32_16x16x32_bf16(a_lo[kc], bh, acc[f], 0, 0, 0);
                acc[f] = __builtin_amdgcn_mfma_f32_16x16x32_bf16(a_hi[kc], bl, acc[f], 0, 0, 0);
            }
        }
    }
    const int rb = bm + wv * 16 + ((lane >> 4) << 2);
    #pragma unroll
    for (int f = 0; f < 4; f++) {
        int col = bn + f * 16 + bcol;
        #pragma unroll
        for (int r = 0; r < 4; r++) {
            int row = rb + r;
            if (row >= M) continue;
            float val = acc[f][r];
            if (HASBIAS) val += bias[col];
            size_t idx = (size_t)row * ldc + col;
            if (OUTM == 0) {
                C[idx] = val;
            } else if (OUTM == 1) {
                C[idx] += val;
            } else {
                atomicAdd(&C[idx], val);
            }
        }
    }
}

// ---------------------------------------------------------------------------
// YZ -> out projection GEMM, single-block-owns-full-K (6 chunks, K=768).
// A row layout (from attn_fused): [hi(768) | lo(768)] ushorts.
// Software-pipelined: ping-pong A regs + B breg prefetch, fully unrolled.
// Epilogue fuses the bv-indicator (ind = deg(row)>0 from rp) and:
//   HASSEED=true  (stage 3): out[idx] += acc + seed[idx] + ind*bv  (out=h, seed=dout)
//   HASSEED=false (stage 4): out[idx] += acc + ind*bv              (out=dout, pre-seeded)
// Single non-atomic RMW per element (exclusive ownership, no z-slices).
template <bool HASSEED>
__global__ __launch_bounds__(256) void gemm_yz(
        const ushort* __restrict__ A,
        const ushort* __restrict__ Wt,
        const float* __restrict__ seed,
        float* __restrict__ out,
        const int* __restrict__ rp,
        const float* __restrict__ bvm, int M) {
    __shared__ ushort Bs[64][264];
    const int j = xcd_swz(blockIdx.x, gridDim.x);
    const int by = j & 1;
    const int bm = (j >> 1) * 64;
    const int bn = by * 64;
    const int t = threadIdx.x;
    const int lane = t & 63;
    const int wv = t >> 6;
    const int arow = wv * 16 + (lane & 15);
    const int kb = (lane >> 4) * 8;
    const int bcol = lane & 15;
    const int m = bm + arow;
    const bool mok = (m < M);
    const ushort* Ar = A + (size_t)m * 1536 + kb;
    const short8v z8 = {0, 0, 0, 0, 0, 0, 0, 0};
    short8v breg[8];
    #pragma unroll
    for (int i = 0; i < 8; i++) {
        int li = t + i * 256;
        int r = li >> 5, g = li & 31;
        breg[i] = *(const short8v*)(Wt + (size_t)(bn + r) * 1536 + g * 8);
    }
    short8v aH[2][4], aL[2][4];
    #pragma unroll
    for (int kc = 0; kc < 4; kc++) {
        aH[0][kc] = mok ? *(const short8v*)(Ar + kc * 32) : z8;
        aL[0][kc] = mok ? *(const short8v*)(Ar + 768 + kc * 32) : z8;
    }
    float4v acc[4] = {{0.f, 0.f, 0.f, 0.f}, {0.f, 0.f, 0.f, 0.f},
                      {0.f, 0.f, 0.f, 0.f}, {0.f, 0.f, 0.f, 0.f}};
    #pragma unroll
    for (int c = 0; c < 6; c++) {
        const int cur = c & 1, nxt = cur ^ 1;
        __syncthreads();
        #pragma unroll
        for (int i = 0; i < 8; i++) {
            int li = t + i * 256;
            int r = li >> 5, g = li & 31;
            *(short8v*)&Bs[r][g * 8] = breg[i];
        }
        __syncthreads();
        if (c < 5) {
            #pragma unroll
            for (int i = 0; i < 8; i++) {
                int li = t + i * 256;
                int r = li >> 5, g = li & 31;
                breg[i] = *(const short8v*)(Wt + (size_t)(bn + r) * 1536 + (c + 1) * 256 + g * 8);
            }
            #pragma unroll
            for (int kc = 0; kc < 4; kc++) {
                aH[nxt][kc] = mok ? *(const short8v*)(Ar + (c + 1) * 128 + kc * 32) : z8;
                aL[nxt][kc] = mok ? *(const short8v*)(Ar + 768 + (c + 1) * 128 + kc * 32) : z8;
            }
        }
        #pragma unroll
        for (int kc = 0; kc < 4; kc++) {
            short8v ah = aH[cur][kc];
            short8v al = aL[cur][kc];
            #pragma unroll
            for (int f = 0; f < 4; f++) {
                short8v bh = *(const short8v*)&Bs[f * 16 + bcol][kc * 32 + kb];
                short8v bl = *(const short8v*)&Bs[f * 16 + bcol][128 + kc * 32 + kb];
                acc[f] = __builtin_amdgcn_mfma_f32_16x16x32_bf16(ah, bh, acc[f], 0, 0, 0);
                acc[f] = __builtin_amdgcn_mfma_f32_16x16x32_bf16(al, bh, acc[f], 0, 0, 0);
                acc[f] = __builtin_amdgcn_mfma_f32_16x16x32_bf16(ah, bl, acc[f], 0, 0, 0);
            }
        }
    }
    const int rb = bm + wv * 16 + ((lane >> 4) << 2);
    float ind[4];
    #pragma unroll
    for (int r = 0; r < 4; r++) {
        int row = rb + r;
        ind[r] = (row < M && rp[row + 1] > rp[row]) ? 1.f : 0.f;
    }
    #pragma unroll
    for (int f = 0; f < 4; f++) {
        int col = bn + f * 16 + bcol;
        float bv = bvm[col];
        #pragma unroll
        for (int r = 0; r < 4; r++) {
            int row = rb + r;
            if (row >= M) continue;
            size_t idx = (size_t)row * 128 + col;
            float val = acc[f][r] + ind[r] * bv;
            if (HASSEED) val += seed[idx];
            out[idx] += val;
        }
    }
}

// ---------------------------------------------------------------------------
// Fused attention: 32 lanes per dst (2 dsts per wave), float4 per lane.
// alpha = (A1[dst]·x_s + U[dst]·ea + kvec[src])/sqrt(128).
// Reduce: DPP VALU tree (4 levels) + one xor-16 shfl.
// 3-deep rotating edge prefetch covers gather latency.
// YZ written as split-bf16 [hi(768)|lo(768)] ushorts per row for gemm_yz.
// (bv-indicator handled in gemm_yz epilogue via rp — no output RMW here.)
template <int EMODE>
__global__ __launch_bounds__(256) void attn_fused(
        const float* __restrict__ A1, const float* __restrict__ U,
        const float* __restrict__ X, const float* __restrict__ Esrc,
        const float* __restrict__ kvec, const int2* __restrict__ epack,
        const int* __restrict__ rp,
        ushort* __restrict__ YZ, int n_dst) {
    int dst = (int)((blockIdx.x * (size_t)blockDim.x + threadIdx.x) >> 5);
    int lane = threadIdx.x & 31;
    if (dst >= n_dst) return;
    const float* ap = A1 + (size_t)dst * 384;
    const float* up = U + (size_t)dst * 384;
    float4 a1[3], u[3], y[3], za[3];
    float m[3], den[3];
    #pragma unroll
    for (int h = 0; h < 3; h++) {
        a1[h] = *(const float4*)(ap + h * 128 + lane * 4);
        u[h] = *(const float4*)(up + h * 128 + lane * 4);
        y[h] = make_float4(0.f, 0.f, 0.f, 0.f);
        za[h] = make_float4(0.f, 0.f, 0.f, 0.f);
        m[h] = -INFINITY;
        den[h] = 0.f;
    }
    int beg = rp[dst], end = rp[dst + 1];
    auto loadE = [&](int e, float4& xs, float4& ea, float4& kv) {
        int2 sp = epack[e];
        xs = *(const float4*)(X + (size_t)sp.x * 128 + lane * 4);
        if (EMODE == 0) {
            ea = *(const float4*)(Esrc + (size_t)sp.y * 128 + lane * 4);
        } else {
            float sgn = (float)sp.y;
            ea = make_float4(xs.x * sgn, xs.y * sgn, xs.z * sgn, xs.w * sgn);
        }
        kv = *(const float4*)(kvec + (size_t)sp.x * 4);
    };
    float4 xA, eA, kA, xB, eB, kB;
    if (beg < end) loadE(beg, xA, eA, kA);
    if (beg + 1 < end) loadE(beg + 1, xB, eB, kB);
    for (int e = beg; e < end; e++) {
        float4 xC, eC, kC;
        if (e + 2 < end) loadE(e + 2, xC, eC, kC);
        float dot[3];
        #pragma unroll
        for (int h = 0; h < 3; h++)
            dot[h] = a1[h].x * xA.x + a1[h].y * xA.y +
                     a1[h].z * xA.z + a1[h].w * xA.w +
                     u[h].x * eA.x + u[h].y * eA.y +
                     u[h].z * eA.z + u[h].w * eA.w;
        #pragma unroll
        for (int h = 0; h < 3; h++) dot[h] = rsum32(dot[h]);
        float kvh[3] = {kA.x, kA.y, kA.z};
        #pragma unroll
        for (int h = 0; h < 3; h++) {
            float a = (dot[h] + kvh[h]) * 0.08838834764831845f;  // 1/sqrt(128)
            float mn = fmaxf(m[h], a);
            float scale = __expf(m[h] - mn);  // first edge: exp(-inf)=0
            float w = __expf(a - mn);
            den[h] = den[h] * scale + w;
            y[h].x = y[h].x * scale + w * xA.x;
            y[h].y = y[h].y * scale + w * xA.y;
            y[h].z = y[h].z * scale + w * xA.z;
            y[h].w = y[h].w * scale + w * xA.w;
            za[h].x = za[h].x * scale + w * eA.x;
            za[h].y = za[h].y * scale + w * eA.y;
            za[h].z = za[h].z * scale + w * eA.z;
            za[h].w = za[h].w * scale + w * eA.w;
            m[h] = mn;
        }
        xA = xB; eA = eB; kA = kB;
        xB = xC; eB = eC; kB = kC;
    }
    ushort* yrow = YZ + (size_t)dst * 1536;
    #pragma unroll
    for (int h = 0; h < 3; h++) {
        float inv = 1.f / (den[h] + 1e-16f) * (1.f / 3.f);
        float vy[4] = {y[h].x * inv, y[h].y * inv, y[h].z * inv, y[h].w * inv};
        float vz[4] = {za[h].x * inv, za[h].y * inv, za[h].z * inv, za[h].w * inv};
        ushort hy[4], ly[4], hz[4], lz[4];
        #pragma unroll
        for (int jj = 0; jj < 4; jj++) {
            hy[jj] = f2b(vy[jj]);
            ly[jj] = f2b(vy[jj] - b2f(hy[jj]));
            hz[jj] = f2b(vz[jj]);
            lz[jj] = f2b(vz[jj] - b2f(hz[jj]));
        }
        *(uint2*)(yrow + h * 128 + lane * 4) =
            make_uint2((uint)hy[0] | ((uint)hy[1] << 16), (uint)hy[2] | ((uint)hy[3] << 16));
        *(uint2*)(yrow + 768 + h * 128 + lane * 4) =
            make_uint2((uint)ly[0] | ((uint)ly[1] << 16), (uint)ly[2] | ((uint)ly[3] << 16));
        *(uint2*)(yrow + 384 + h * 128 + lane * 4) =
            make_uint2((uint)hz[0] | ((uint)hz[1] << 16), (uint)hz[2] | ((uint)hz[3] << 16));
        *(uint2*)(yrow + 768 + 384 + h * 128 + lane * 4) =
            make_uint2((uint)lz[0] | ((uint)lz[1] << 16), (uint)lz[2] | ((uint)lz[3] << 16));
    }
}

// ---------------------------------------------------------------------------
extern "C" void kernel_launch(void* const* d_in, const int* in_sizes, int n_in,
                              void* d_out, int out_size, void* d_ws, size_t ws_size,
                              hipStream_t stream) {
    const float* h_dE  = (const float*)d_in[0];
    const float* h_dF  = (const float*)d_in[1];
    const int*   cob   = (const int*)d_in[2];
    const int*   nn    = (const int*)d_in[3];
    const float* aggrW = (const float*)d_in[4];
    const float* aggrB = (const float*)d_in[5];
    const float* ctrW  = (const float*)d_in[6];
    const float* ctrB  = (const float*)d_in[7];
    const float* f_Wq  = (const float*)d_in[8];
    const float* f_bq  = (const float*)d_in[9];
    const float* f_Wk  = (const float*)d_in[10];
    const float* f_bk  = (const float*)d_in[11];
    const float* f_Wv  = (const float*)d_in[12];
    const float* f_bv  = (const float*)d_in[13];
    const float* f_We  = (const float*)d_in[14];
    const float* f_Ws  = (const float*)d_in[15];
    const float* f_bs  = (const float*)d_in[16];
    const float* e_Wq  = (const float*)d_in[17];
    const float* e_bq  = (const float*)d_in[18];
    const float* e_Wk  = (const float*)d_in[19];
    const float* e_bk  = (const float*)d_in[20];
    const float* e_Wv  = (const float*)d_in[21];
    const float* e_bv  = (const float*)d_in[22];
    const float* e_We  = (const float*)d_in[23];
    const float* e_Ws  = (const float*)d_in[24];
    const float* e_bs  = (const float*)d_in[25];

    const int CH = 25000;  // stage-4 dst chunk

    // ---- workspace ----
    char* base = (char*)d_ws;
    size_t off = 0;
    auto takeB = [&](size_t bytes) {
        char* p = base + off;
        off += (bytes + 15) & ~(size_t)15;
        return p;
    };
    float*  h     = (float*)takeB((size_t)F_Nc * 128 * 4);
    float*  A1f   = (float*)takeB((size_t)CH * 384 * 4);
    float*  Uf    = (float*)takeB((size_t)CH * 384 * 4);
    float*  YZb   = (float*)takeB((size_t)CH * 768 * 4);  // YZ bf16 rows / fp32 scratch
    float*  Kvb   = (float*)takeB((size_t)CH * 4 * 4);
    float*  Wu32  = (float*)takeB((size_t)12 * 16384 * 4);
    float*  G32   = (float*)takeB((size_t)12 * 16384 * 4);
    float*  wkb32 = (float*)takeB((size_t)4 * 384 * 4);
    float*  biasPool = (float*)takeB(4608 * 4);
    ushort* WtPool = (ushort*)takeB((size_t)2200000 * 2);
    int* rp_nn   = (int*)takeB((F_Nc + 1) * 4);
    int* rp_cobE = (int*)takeB((E_Nc + 1) * 4);
    int* rp_cobF = (int*)takeB((F_Nc + 1) * 4);
    int2* epk_nn = (int2*)takeB((size_t)P_Nc * 8);
    int2* epk_cE = (int2*)takeB((size_t)M_Nc * 8);
    int2* epk_cF = (int2*)takeB((size_t)M_Nc * 8);
    int* cnt_nn  = (int*)takeB((size_t)F_Nc * 4);
    int* cnt_cE  = (int*)takeB((size_t)E_Nc * 4);
    int* cnt_cF  = (int*)takeB((size_t)F_Nc * 4);
    int* bsum3   = (int*)takeB(3 * 64 * 4);
    if (ws_size < off) return;  // fail loud, not a fault

    const int BLK = 256;
    float* dout = (float*)d_out;
    ushort* YZu = (ushort*)YZb;

    const float* Wq4[4] = {f_Wq, f_Wq + 49152, f_Wq + 98304, e_Wq};
    const float* Wk4[4] = {f_Wk, f_Wk + 49152, f_Wk + 98304, e_Wk};
    const float* Wv4[4] = {f_Wv, f_Wv + 49152, f_Wv + 98304, e_Wv};
    const float* We4[4] = {f_We, f_We + 49152, f_We + 98304, e_We};
    const float* Ws4[4] = {f_Ws, f_Ws + 16384, f_Ws + 32768, e_Ws};
    const float* bq4[4] = {f_bq, f_bq + 384, f_bq + 768, e_bq};
    const float* bv4[4] = {f_bv, f_bv + 384, f_bv + 768, e_bv};

    // ---- derived weights (fp32) ----
    zero_f<<<cdiv(4608, BLK), BLK, 0, stream>>>(biasPool, 4608);
    GuArgs gua;
    BuArgs bua;
    WkbArgs wka;
    BvArgs bva;
    for (int l = 0; l < 4; l++) {
        gua.wq[l] = Wq4[l]; gua.we[l] = We4[l]; gua.wk[l] = Wk4[l];
        bua.bq[l] = bq4[l]; bua.we[l] = We4[l];
        wka.wk[l] = Wk4[l]; wka.bq[l] = bq4[l];
        bva.bv[l] = bv4[l];
    }
    compute_gu<<<cdiv(2 * 12 * 16384, BLK), BLK, 0, stream>>>(gua, Wu32, G32);
    bias_u<<<cdiv(12 * 128, BLK), BLK, 0, stream>>>(bua, biasPool);
    wkb_k<<<cdiv(4 * 384, BLK), BLK, 0, stream>>>(wka, wkb32);
    bvmean_k<<<cdiv(4 * 128, BLK), BLK, 0, stream>>>(bva, biasPool);

    // ---- bias copies: bs into xproj bias slots ----
    BDescs bd;
    int bi = 0;
    auto addb = [&](const float* s, int o, int n2) { bd.d[bi].src = s; bd.d[bi].dstoff = o; bd.d[bi].n = n2; bi++; };
    for (int l = 0; l < 3; l++) addb(f_bs + l * 128, l * 960 + 832, 128);
    addb(e_bs, 2880 + 768, 128);
    copy_bias<<<dim3(1, 4), BLK, 0, stream>>>(bd, biasPool);

    // ---- weight prep descriptors (split [hi|lo]) ----
    WDescs wd;
    int dc = 0;
    long wto = 0;
    auto addw = [&](const float* in, int ldin, int coloff, long outoff,
                    int NN, int KK, int trans, int ldo) {
        wd.d[dc].in = in; wd.d[dc].ldin = ldin; wd.d[dc].coloff = coloff;
        wd.d[dc].outoff = outoff; wd.d[dc].NN = NN; wd.d[dc].KK = KK;
        wd.d[dc].trans = trans; wd.d[dc].ldo = ldo; dc++;
    };
    long wx[3], w4e, w4h, wyz[4], waggr, wctr;
    for (int l = 0; l < 3; l++) {
        wx[l] = wto;
        addw(G32 + (long)l * 49152, 128, 0, wto, 384, 128, 0, 256);
        addw(Wu32 + (long)l * 49152, 128, 0, wto + 384L * 256, 384, 128, 0, 256);
        addw(wkb32 + (long)l * 384, 128, 0, wto + 768L * 256, 3, 128, 0, 256);
        addw(Ws4[l], 128, 0, wto + 832L * 256, 128, 128, 1, 256);
        wto += 960L * 256;
    }
    w4e = wto;
    addw(G32 + 3L * 49152, 128, 0, wto, 384, 128, 0, 256);
    addw(Wu32 + 3L * 49152, 128, 0, wto + 384L * 256, 384, 128, 0, 256);
    addw(e_Ws, 128, 0, wto + 768L * 256, 128, 128, 1, 256);
    wto += 896L * 256;
    w4h = wto;
    addw(wkb32 + 3L * 384, 128, 0, wto, 3, 128, 0, 256);
    wto += 64L * 256;
    for (int l = 0; l < 4; l++) {
        wyz[l] = wto;
        for (int hh = 0; hh < 3; hh++) {
            addw(Wv4[l], 384, hh * 128, wto + hh * 256, 128, 128, 1, 1536);
            addw(We4[l], 384, hh * 128, wto + (3 + hh) * 256, 128, 128, 1, 1536);
        }
        wto += 128L * 1536;
    }
    waggr = wto; addw(aggrW, 128, 0, wto, 128, 128, 1, 256); wto += 128 * 256;
    wctr  = wto; addw(ctrW,  128, 0, wto, 128, 128, 1, 256); wto += 128 * 256;
    wd.cnt = dc;  // 42
    prep_weights<<<dim3(192, dc), BLK, 0, stream>>>(wd, WtPool);

    // ---- batched CSR builds (7 dispatches) ----
    CsrJobs cj;
    cj.j[0] = {nn, 1, 0, P_Nc, F_Nc, cnt_nn, rp_nn, epk_nn, bsum3};
    cj.j[1] = {cob, 0, 1, M_Nc, E_Nc, cnt_cE, rp_cobE, epk_cE, bsum3 + 64};
    cj.j[2] = {cob, 1, 0, M_Nc, F_Nc, cnt_cF, rp_cobF, epk_cF, bsum3 + 128};
    csr_zero<<<dim3(cdiv(E_Nc, BLK), 3), BLK, 0, stream>>>(cj);
    csr_count<<<dim3(cdiv(M_Nc, BLK), 3), BLK, 0, stream>>>(cj);
    csr_scan_partial<<<dim3(cdiv(E_Nc, 1024), 3), BLK, 0, stream>>>(cj);
    csr_scan_bsum<<<dim3(1, 3), 64, 0, stream>>>(cj);
    csr_scan_final<<<dim3(cdiv(E_Nc, 1024), 3), BLK, 0, stream>>>(cj);
    csr_zero<<<dim3(cdiv(E_Nc, BLK), 3), BLK, 0, stream>>>(cj);
    csr_scatter<<<dim3(cdiv(M_Nc, BLK), 3), BLK, 0, stream>>>(cj);

    // ---- stage 1: aggr (fp32, in YZb scratch) ----
    cob_gather<<<cdiv((long)F_Nc * 64, BLK), BLK, 0, stream>>>(
        h_dE, epk_cF, rp_cobF, YZb, F_Nc);

    // ---- stage 2: h = aggr@aggrW + aggrB + h_dF@ctrW + ctrB ----
    gemm_split<0, true><<<dim3(cdiv(F_Nc, 64), 2, 1), BLK, 0, stream>>>(
        YZb, 128, WtPool + waggr, 256, aggrB, h, 128, F_Nc, 128, 128);
    gemm_split<1, true><<<dim3(cdiv(F_Nc, 64), 2, 1), BLK, 0, stream>>>(
        h_dF, 128, WtPool + wctr, 256, ctrB, h, 128, F_Nc, 128, 128);

    const int NXB = cdiv(F_Nc, 64);  // 391

    // ---- stage 3: three residual attention layers ----
    for (int l = 0; l < 3; l++) {
        SegInfo s3;
        s3.base[0] = A1f; s3.ld[0] = 384;
        s3.base[1] = Uf;  s3.ld[1] = 384;
        s3.base[2] = Kvb; s3.ld[2] = 4;      // 3 kvec cols, col<ld guard
        s3.base[3] = dout; s3.ld[3] = 128;   // Ws-skip + bs seeded into dout
        s3.base[4] = nullptr; s3.ld[4] = 0;
        s3.start[0] = 0; s3.start[1] = 384; s3.start[2] = 768;
        s3.start[3] = 832; s3.start[4] = 960; s3.start[5] = 960;
        s3.nseg = 4;
        gemm_xproj<<<dim3(NXB * 5), BLK, 0, stream>>>(
            h, 128, F_Nc, WtPool + wx[l], biasPool + l * 960, s3, 5);
        attn_fused<0><<<cdiv((long)F_Nc * 32, BLK), BLK, 0, stream>>>(
            A1f, Uf, h, h_dE, Kvb, epk_nn, rp_nn, YZu, F_Nc);
        gemm_yz<true><<<dim3(NXB * 2), BLK, 0, stream>>>(
            YZu, WtPool + wyz[l], dout, h, rp_nn,
            biasPool + 3840 + l * 128, F_Nc);
    }

    // ---- stage 4: final attention F -> E ----
    {   // kvec for all F src nodes (from h)
        SegInfo s4h;
        s4h.base[0] = Kvb; s4h.ld[0] = 4;
        s4h.base[1] = nullptr; s4h.base[2] = nullptr; s4h.base[3] = nullptr; s4h.base[4] = nullptr;
        s4h.ld[1] = 0; s4h.ld[2] = 0; s4h.ld[3] = 0; s4h.ld[4] = 0;
        s4h.start[0] = 0; s4h.start[1] = 64; s4h.start[2] = 64;
        s4h.start[3] = 64; s4h.start[4] = 64; s4h.start[5] = 64;
        s4h.nseg = 1;
        gemm_xproj<<<dim3(NXB), BLK, 0, stream>>>(
            h, 128, F_Nc, WtPool + w4h, biasPool + 3776, s4h, 1);
    }
    for (int c = 0; c < 2; c++) {
        int c0 = c * CH;
        SegInfo s4e;
        s4e.base[0] = A1f; s4e.ld[0] = 384;
        s4e.base[1] = Uf;  s4e.ld[1] = 384;
        s4e.base[2] = dout + (size_t)c0 * 128; s4e.ld[2] = 128;
        s4e.base[3] = nullptr; s4e.base[4] = nullptr; s4e.ld[3] = 0; s4e.ld[4] = 0;
        s4e.start[0] = 0; s4e.start[1] = 384; s4e.start[2] = 768;
        s4e.start[3] = 896; s4e.start[4] = 896; s4e.start[5] = 896;
        s4e.nseg = 3;
        gemm_xproj<<<dim3(cdiv(CH, 64) * 5), BLK, 0, stream>>>(
            h_dE + (size_t)c0 * 128, 128, CH, WtPool + w4e, biasPool + 2880, s4e, 5);
        attn_fused<1><<<cdiv((long)CH * 32, BLK), BLK, 0, stream>>>(
            A1f, Uf, h, h, Kvb, epk_cE, rp_cobE + c0, YZu, CH);
        gemm_yz<false><<<dim3(cdiv(CH, 64) * 2), BLK, 0, stream>>>(
            YZu, WtPool + wyz[3], nullptr, dout + (size_t)c0 * 128, rp_cobE + c0,
            biasPool + 4224, CH);
    }
}

// Round 13
// 718.490 us; speedup vs baseline: 1.5382x; 1.0518x over previous
//
#include <hip/hip_runtime.h>
#include <math.h>

#define E_Nc 50000
#define F_Nc 25000
#define M_Nc 100000
#define P_Nc 75000
// D=128, HD=384, HEADS=3, DH=128

typedef unsigned short ushort;
typedef unsigned int uint;
typedef __attribute__((ext_vector_type(8))) short short8v;
typedef __attribute__((ext_vector_type(4))) float float4v;
typedef __attribute__((ext_vector_type(4))) _Float16 half4v;

static inline int cdiv(long a, long b) { return (int)((a + b - 1) / b); }

// ---------------------------------------------------------------------------
__device__ inline ushort f2b(float f) {  // RNE fp32 -> bf16
    uint u = __float_as_uint(f);
    u += 0x7fffu + ((u >> 16) & 1u);
    return (ushort)(u >> 16);
}
__device__ inline float b2f(ushort b) { return __uint_as_float((uint)b << 16); }

// Bijective XCD-chunked block swizzle (m204).
__device__ inline int xcd_swz(int bid, int nb) {
    int q = nb >> 3, r = nb & 7;
    int xcd = bid & 7, w = bid >> 3;
    return (xcd < r ? xcd * (q + 1) : r * (q + 1) + (xcd - r) * q) + w;
}

// 32-lane sum (within each 32-half of the wave), result in all lanes.
__device__ inline float rsum32(float v) {
    v += __uint_as_float(__builtin_amdgcn_update_dpp(
        0, __float_as_uint(v), 0xB1, 0xF, 0xF, true));   // quad_perm xor1
    v += __uint_as_float(__builtin_amdgcn_update_dpp(
        0, __float_as_uint(v), 0x4E, 0xF, 0xF, true));   // quad_perm xor2
    v += __uint_as_float(__builtin_amdgcn_update_dpp(
        0, __float_as_uint(v), 0x124, 0xF, 0xF, true));  // row_ror:4
    v += __uint_as_float(__builtin_amdgcn_update_dpp(
        0, __float_as_uint(v), 0x128, 0xF, 0xF, true));  // row_ror:8
    v += __shfl_xor(v, 16);
    return v;
}

// ---------------------------------------------------------------------------
__global__ void zero_f(float* __restrict__ p, int n) {
    int i = blockIdx.x * blockDim.x + threadIdx.x;
    if (i < n) p[i] = 0.f;
}

// ---------------------------------------------------------------------------
// Batched CSR build: 3 graphs in y-indexed jobs, 7 dispatches total.
// Scatter writes packed {src, aux} per edge.
struct CsrJob {
    const int* idx3;
    int col, srccol, P, n;
    int* cnt;
    int* rp;
    int2* epack;
    int* bsum;
};
struct CsrJobs { CsrJob j[3]; };

__global__ __launch_bounds__(256) void csr_zero(CsrJobs js) {
    const CsrJob& j = js.j[blockIdx.y];
    int i = blockIdx.x * 256 + threadIdx.x;
    if (i < j.n) j.cnt[i] = 0;
}

__global__ __launch_bounds__(256) void csr_count(CsrJobs js) {
    const CsrJob& j = js.j[blockIdx.y];
    int i = blockIdx.x * 256 + threadIdx.x;
    if (i < j.P) atomicAdd(&j.cnt[j.idx3[(size_t)i * 3 + j.col]], 1);
}

__global__ __launch_bounds__(256) void csr_scan_partial(CsrJobs js) {
    const CsrJob& j = js.j[blockIdx.y];
    __shared__ int lds[256];
    int b = blockIdx.x, t = threadIdx.x;
    int base = b * 1024 + t * 4;
    int s = 0;
    #pragma unroll
    for (int k = 0; k < 4; k++) { int i = base + k; if (i < j.n) s += j.cnt[i]; }
    lds[t] = s;
    __syncthreads();
    for (int off = 128; off > 0; off >>= 1) {
        if (t < off) lds[t] += lds[t + off];
        __syncthreads();
    }
    if (t == 0) j.bsum[b] = lds[0];
}

__global__ __launch_bounds__(64) void csr_scan_bsum(CsrJobs js) {
    const CsrJob& j = js.j[blockIdx.y];
    __shared__ int lds[64];
    int t = threadIdx.x;
    int v = j.bsum[t];
    lds[t] = v;
    __syncthreads();
    for (int off = 1; off < 64; off <<= 1) {
        int x = (t >= off) ? lds[t - off] : 0;
        __syncthreads();
        lds[t] += x;
        __syncthreads();
    }
    j.bsum[t] = lds[t] - v;  // exclusive
}

__global__ __launch_bounds__(256) void csr_scan_final(CsrJobs js) {
    const CsrJob& j = js.j[blockIdx.y];
    __shared__ int lds[256];
    int b = blockIdx.x, t = threadIdx.x;
    int base = b * 1024 + t * 4;
    int v[4];
    int s = 0;
    #pragma unroll
    for (int k = 0; k < 4; k++) {
        int i = base + k;
        v[k] = (i < j.n) ? j.cnt[i] : 0;
        s += v[k];
    }
    lds[t] = s;
    __syncthreads();
    for (int off = 1; off < 256; off <<= 1) {
        int x = (t >= off) ? lds[t - off] : 0;
        __syncthreads();
        lds[t] += x;
        __syncthreads();
    }
    int pre = j.bsum[b] + lds[t] - s;
    #pragma unroll
    for (int k = 0; k < 4; k++) {
        int i = base + k;
        if (i < j.n) j.rp[i] = pre;
        pre += v[k];
        if (i == j.n - 1) j.rp[j.n] = pre;
    }
}

__global__ __launch_bounds__(256) void csr_scatter(CsrJobs js) {
    const CsrJob& j = js.j[blockIdx.y];
    int i = blockIdx.x * 256 + threadIdx.x;
    if (i >= j.P) return;
    const int* row = j.idx3 + (size_t)i * 3;
    int d = row[j.col];
    int pos = atomicAdd(&j.cnt[d], 1);
    int2 pk;
    pk.x = row[j.srccol];
    pk.y = row[2];
    j.epack[j.rp[d] + pos] = pk;
}

// ---------------------------------------------------------------------------
// Wu_h = Wq_h @ We_h^T and G_h = Wq_h @ Wk_h^T (both fp32)
struct GuArgs { const float* wq[4]; const float* we[4]; const float* wk[4]; };
__global__ __launch_bounds__(256) void compute_gu(GuArgs a,
        float* __restrict__ Wu32, float* __restrict__ G32) {
    int idx = blockIdx.x * 256 + threadIdx.x;
    if (idx >= 2 * 12 * 16384) return;
    int sel = idx / (12 * 16384);
    int rem0 = idx - sel * (12 * 16384);
    int lh = rem0 >> 14;
    int l = lh / 3, h = lh - l * 3;
    int rem = rem0 & 16383;
    int c = rem >> 7, d = rem & 127;
    const float* Wq = a.wq[l];
    const float* Wo = sel ? a.wk[l] : a.we[l];
    float s = 0.f;
    #pragma unroll 4
    for (int jj = 0; jj < 128; jj++)
        s += Wq[d * 384 + h * 128 + jj] * Wo[c * 384 + h * 128 + jj];
    (sel ? G32 : Wu32)[rem0] = s;
}

// wkb[l][h*128+d] = sum_j Wk_l[d, h*128+j] * bq_l[h*128+j]
struct WkbArgs { const float* wk[4]; const float* bq[4]; };
__global__ void wkb_k(WkbArgs a, float* __restrict__ wkb32) {
    int idx = blockIdx.x * blockDim.x + threadIdx.x;
    if (idx >= 4 * 384) return;
    int l = idx / 384;
    int r = idx - l * 384;
    int h = r >> 7, d = r & 127;
    const float* Wk = a.wk[l];
    const float* bq = a.bq[l];
    float s = 0.f;
    for (int jj = 0; jj < 128; jj++)
        s += Wk[d * 384 + h * 128 + jj] * bq[h * 128 + jj];
    wkb32[idx] = s;
}

// bvm[l][c] = mean_h bv_l[h*128+c] -> biasPool slots
struct BvArgs { const float* bv[4]; };
__global__ void bvmean_k(BvArgs a, float* __restrict__ pool) {
    int idx = blockIdx.x * blockDim.x + threadIdx.x;
    if (idx >= 4 * 128) return;
    int l = idx >> 7, c = idx & 127;
    float v = (a.bv[l][c] + a.bv[l][128 + c] + a.bv[l][256 + c]) * (1.f / 3.f);
    pool[(l < 3 ? 3840 + l * 128 : 4224) + c] = v;
}

// bu_h[c] = sum_j bq_h[j] * We[c, h*128+j] -> biasPool slots
struct BuArgs { const float* bq[4]; const float* we[4]; };
__global__ void bias_u(BuArgs a, float* __restrict__ pool) {
    int idx = blockIdx.x * blockDim.x + threadIdx.x;
    if (idx >= 12 * 128) return;
    int lh = idx >> 7, c = idx & 127;
    int l = lh / 3, h = lh - l * 3;
    const float* bq = a.bq[l];
    const float* We = a.we[l];
    float s = 0.f;
    for (int jj = 0; jj < 128; jj++)
        s += bq[h * 128 + jj] * We[c * 384 + h * 128 + jj];
    int slot = (l < 3) ? (l * 960 + 384 + h * 128 + c)
                       : (2880 + 384 + h * 128 + c);
    pool[slot] = s;
}

// plain bias copies into biasPool
struct BDesc { const float* src; int dstoff, n; };
struct BDescs { BDesc d[8]; };
__global__ void copy_bias(BDescs ds, float* __restrict__ pool) {
    const BDesc b = ds.d[blockIdx.y];
    int i = blockIdx.x * 256 + threadIdx.x;
    if (i < b.n) pool[b.dstoff + i] = b.src[i];
}

// ---------------------------------------------------------------------------
// Weight prep: split fp32 weight into bf16 [hi(KK) | lo(KK)] rows.
struct WDesc {
    const float* in;
    long outoff;
    int ldin, coloff, NN, KK, trans, ldo;
};
struct WDescs { WDesc d[44]; int cnt; };

__global__ __launch_bounds__(256) void prep_weights(WDescs ds, ushort* __restrict__ out) {
    const WDesc w = ds.d[blockIdx.y];
    int i = blockIdx.x * 256 + threadIdx.x;
    if (i >= w.NN * w.KK) return;
    int n = i / w.KK, k = i - n * w.KK;
    float v = w.trans ? w.in[(size_t)k * w.ldin + w.coloff + n]
                      : w.in[(size_t)n * w.ldin + w.coloff + k];
    ushort hi = f2b(v);
    ushort lo = f2b(v - b2f(hi));
    long ro = w.outoff + (size_t)n * w.ldo;
    out[ro + k] = hi;
    out[ro + w.KK + k] = lo;
}

// ---------------------------------------------------------------------------
// CSR gather (fp32 out): aggr[f] = sum sgn * h_dE[e]
__global__ __launch_bounds__(256) void cob_gather(
        const float* __restrict__ h_dE, const int2* __restrict__ epack,
        const int* __restrict__ rp, float* __restrict__ out, int Fn) {
    int wave = (int)((blockIdx.x * (size_t)blockDim.x + threadIdx.x) >> 6);
    int lane = threadIdx.x & 63;
    if (wave >= Fn) return;
    float2 s = make_float2(0.f, 0.f);
    int beg = rp[wave], end = rp[wave + 1];
    for (int e = beg; e < end; e++) {
        int2 sp = epack[e];
        float sg = (float)sp.y;
        float2 v = *(const float2*)(h_dE + (size_t)sp.x * 128 + lane * 2);
        s.x += sg * v.x;
        s.y += sg * v.y;
    }
    *(float2*)(out + (size_t)wave * 128 + lane * 2) = s;
}

// ---------------------------------------------------------------------------
// Persistent-A split-bf16 x-projection GEMM (K = 128, 3-term fp32-accurate).
// Flattened grid + XCD-chunked swizzle. Store guard col < ldc allows narrow
// segments (Kvb ld=4 holds only 3 meaningful kvec cols).
// Per-segment f16 flag: A1/U segments are stored as IEEE fp16 (half write
// traffic; attn converts back to fp32 on load).
#define TPB 3
struct SegInfo {
    float* base[5];
    int ld[5];
    int f16[5];
    int start[6];
    int nseg;
};

__global__ __launch_bounds__(256) void gemm_xproj(
        const float* __restrict__ A, int lda, int M,
        const ushort* __restrict__ Wt,
        const float* __restrict__ biasAll,
        SegInfo segs, int nys) {
    __shared__ ushort LDSu[64][264];  // A-stage, then B-tile [hi | lo]
    const int j = xcd_swz(blockIdx.x, gridDim.x);
    const int ys = j % nys;
    const int bm = (j / nys) * 64;
    const int t = threadIdx.x;
    const int lane = t & 63;
    const int wv = t >> 6;
    #pragma unroll
    for (int i = 0; i < 8; i++) {
        int li = t + i * 256;
        int r = li >> 5, q4 = li & 31;
        int m = bm + r;
        float4 v = make_float4(0.f, 0.f, 0.f, 0.f);
        if (m < M) v = *(const float4*)(A + (size_t)m * lda + q4 * 4);
        ushort h0 = f2b(v.x), h1 = f2b(v.y), h2 = f2b(v.z), h3 = f2b(v.w);
        ushort l0 = f2b(v.x - b2f(h0)), l1 = f2b(v.y - b2f(h1));
        ushort l2 = f2b(v.z - b2f(h2)), l3 = f2b(v.w - b2f(h3));
        *(uint2*)&LDSu[r][q4 * 4] =
            make_uint2((uint)h0 | ((uint)h1 << 16), (uint)h2 | ((uint)h3 << 16));
        *(uint2*)&LDSu[r][128 + q4 * 4] =
            make_uint2((uint)l0 | ((uint)l1 << 16), (uint)l2 | ((uint)l3 << 16));
    }
    __syncthreads();
    const int arow = wv * 16 + (lane & 15);
    const int kb = (lane >> 4) * 8;
    const int bcol = lane & 15;
    short8v a_hi[4], a_lo[4];
    #pragma unroll
    for (int kc = 0; kc < 4; kc++) {
        a_hi[kc] = *(const short8v*)&LDSu[arow][kc * 32 + kb];
        a_lo[kc] = *(const short8v*)&LDSu[arow][128 + kc * 32 + kb];
    }
    const int Ntot = segs.start[segs.nseg];
    const int bn0 = ys * (TPB * 64);
    const int bn1 = min(bn0 + TPB * 64, Ntot);
    if (bn0 >= Ntot) return;
    short8v breg[8];
    #pragma unroll
    for (int i = 0; i < 8; i++) {
        int li = t + i * 256;
        int r = li >> 5, g = li & 31;
        breg[i] = *(const short8v*)(Wt + (size_t)(bn0 + r) * 256 + g * 8);
    }
    int seg = 0;
    while (bn0 >= segs.start[seg + 1]) seg++;
    for (int bn = bn0; bn < bn1; bn += 64) {
        while (bn >= segs.start[seg + 1]) seg++;
        __syncthreads();
        #pragma unroll
        for (int i = 0; i < 8; i++) {
            int li = t + i * 256;
            int r = li >> 5, g = li & 31;
            *(short8v*)&LDSu[r][g * 8] = breg[i];
        }
        __syncthreads();
        if (bn + 64 < bn1) {
            #pragma unroll
            for (int i = 0; i < 8; i++) {
                int li = t + i * 256;
                int r = li >> 5, g = li & 31;
                breg[i] = *(const short8v*)(Wt + (size_t)(bn + 64 + r) * 256 + g * 8);
            }
        }
        float4v acc[4] = {{0.f, 0.f, 0.f, 0.f}, {0.f, 0.f, 0.f, 0.f},
                          {0.f, 0.f, 0.f, 0.f}, {0.f, 0.f, 0.f, 0.f}};
        #pragma unroll
        for (int kc = 0; kc < 4; kc++) {
            #pragma unroll
            for (int f = 0; f < 4; f++) {
                short8v bh = *(const short8v*)&LDSu[f * 16 + bcol][kc * 32 + kb];
                short8v bl = *(const short8v*)&LDSu[f * 16 + bcol][128 + kc * 32 + kb];
                acc[f] = __builtin_amdgcn_mfma_f32_16x16x32_bf16(a_hi[kc], bh, acc[f], 0, 0, 0);
                acc[f] = __builtin_amdgcn_mfma_f32_16x16x32_bf16(a_lo[kc], bh, acc[f], 0, 0, 0);
                acc[f] = __builtin_amdgcn_mfma_f32_16x16x32_bf16(a_hi[kc], bl, acc[f], 0, 0, 0);
            }
        }
        float* Cb = segs.base[seg];
        const int ldc = segs.ld[seg];
        const int coff = segs.start[seg];
        const int isf16 = segs.f16[seg];
        const int rb = bm + wv * 16 + ((lane >> 4) << 2);
        #pragma unroll
        for (int f = 0; f < 4; f++) {
            int ng = bn + f * 16 + bcol;
            float bias = biasAll[ng];
            int col = ng - coff;
            #pragma unroll
            for (int r = 0; r < 4; r++) {
                int row = rb + r;
                if (row < M && col < ldc) {
                    float val = acc[f][r] + bias;
                    if (isf16) {
                        ((_Float16*)Cb)[(size_t)row * ldc + col] = (_Float16)val;
                    } else {
                        Cb[(size_t)row * ldc + col] = val;
                    }
                }
            }
        }
    }
}

// ---------------------------------------------------------------------------
// Split-bf16 3-term GEMM, direct-register A (stage 2 only).
template <int OUTM, bool HASBIAS>
__global__ __launch_bounds__(256) void gemm_split(
        const float* __restrict__ A, int lda,
        const ushort* __restrict__ Wt, int ldw,
        const float* __restrict__ bias,
        float* __restrict__ C, int ldc,
        int M, int N, int kper) {
    __shared__ ushort Bs[64][264];
    const int koff = blockIdx.z * kper;
    const int bm = blockIdx.x * 64;
    const int bn = blockIdx.y * 64;
    const int t = threadIdx.x;
    const int lane = t & 63;
    const int wv = t >> 6;
    const int arow = wv * 16 + (lane & 15);
    const int kb = (lane >> 4) * 8;
    const int bcol = lane & 15;
    const int m = bm + arow;
    const bool mok = (m < M);
    const float* Arow = A + (size_t)m * lda + koff + kb;
    float4v acc[4] = {{0.f, 0.f, 0.f, 0.f}, {0.f, 0.f, 0.f, 0.f},
                      {0.f, 0.f, 0.f, 0.f}, {0.f, 0.f, 0.f, 0.f}};
    short8v breg[8];
    #pragma unroll
    for (int i = 0; i < 8; i++) {
        int li = t + i * 256;
        int r = li >> 5, g = li & 31;
        breg[i] = *(const short8v*)(Wt + (size_t)(bn + r) * ldw + (koff >> 7) * 256 + g * 8);
    }
    for (int c = 0; c < kper; c += 128) {
        __syncthreads();
        #pragma unroll
        for (int i = 0; i < 8; i++) {
            int li = t + i * 256;
            int r = li >> 5, g = li & 31;
            *(short8v*)&Bs[r][g * 8] = breg[i];
        }
        __syncthreads();
        if (c + 128 < kper) {
            const int nchunk = (koff + c + 128) >> 7;
            #pragma unroll
            for (int i = 0; i < 8; i++) {
                int li = t + i * 256;
                int r = li >> 5, g = li & 31;
                breg[i] = *(const short8v*)(Wt + (size_t)(bn + r) * ldw + nchunk * 256 + g * 8);
            }
        }
        short8v a_hi[4], a_lo[4];
        #pragma unroll
        for (int kc = 0; kc < 4; kc++) {
            float4 v0 = make_float4(0.f, 0.f, 0.f, 0.f);
            float4 v1 = make_float4(0.f, 0.f, 0.f, 0.f);
            if (mok) {
                v0 = *(const float4*)(Arow + c + kc * 32);
                v1 = *(const float4*)(Arow + c + kc * 32 + 4);
            }
            union { short8v v; ushort u[8]; } hi, lo;
            float vv[8] = {v0.x, v0.y, v0.z, v0.w, v1.x, v1.y, v1.z, v1.w};
            #pragma unroll
            for (int jj = 0; jj < 8; jj++) {
                ushort hj = f2b(vv[jj]);
                hi.u[jj] = hj;
                lo.u[jj] = f2b(vv[jj] - b2f(hj));
            }
            a_hi[kc] = hi.v;
            a_lo[kc] = lo.v;
        }
        #pragma unroll
        for (int kc = 0; kc < 4; kc++) {
            #pragma unroll
            for (int f = 0; f < 4; f++) {
                short8v bh = *(const short8v*)&Bs[f * 16 + bcol][kc * 32 + kb];
                short8v bl = *(const short8v*)&Bs[f * 16 + bcol][128 + kc * 32 + kb];
                acc[f] = __builtin_amdgcn_mfma_f32_16x16x32_bf16(a_hi[kc], bh, acc[f], 0, 0, 0);
                acc[f] = __builtin_amdgcn_mfma_f32_16x16x32_bf16(a_lo[kc], bh, acc[f], 0, 0, 0);
                acc[f] = __builtin_amdgcn_mfma_f32_16x16x32_bf16(a_hi[kc], bl, acc[f], 0, 0, 0);
            }
        }
    }
    const int rb = bm + wv * 16 + ((lane >> 4) << 2);
    #pragma unroll
    for (int f = 0; f < 4; f++) {
        int col = bn + f * 16 + bcol;
        #pragma unroll
        for (int r = 0; r < 4; r++) {
            int row = rb + r;
            if (row >= M) continue;
            float val = acc[f][r];
            if (HASBIAS) val += bias[col];
            size_t idx = (size_t)row * ldc + col;
            if (OUTM == 0) {
                C[idx] = val;
            } else if (OUTM == 1) {
                C[idx] += val;
            } else {
                atomicAdd(&C[idx], val);
            }
        }
    }
}

// ---------------------------------------------------------------------------
// YZ -> out projection GEMM, single-block-owns-full-K (6 chunks, K=768).
// A row layout (from attn_fused): [hi(768) | lo(768)] ushorts.
// Software-pipelined: ping-pong A regs + B breg prefetch, fully unrolled.
// Epilogue fuses the bv-indicator (ind = deg(row)>0 from rp) and:
//   HASSEED=true  (stage 3): out[idx] += acc + seed[idx] + ind*bv  (out=h, seed=dout)
//   HASSEED=false (stage 4): out[idx] += acc + ind*bv              (out=dout, pre-seeded)
// Single non-atomic RMW per element (exclusive ownership, no z-slices).
template <bool HASSEED>
__global__ __launch_bounds__(256) void gemm_yz(
        const ushort* __restrict__ A,
        const ushort* __restrict__ Wt,
        const float* __restrict__ seed,
        float* __restrict__ out,
        const int* __restrict__ rp,
        const float* __restrict__ bvm, int M) {
    __shared__ ushort Bs[64][264];
    const int j = xcd_swz(blockIdx.x, gridDim.x);
    const int by = j & 1;
    const int bm = (j >> 1) * 64;
    const int bn = by * 64;
    const int t = threadIdx.x;
    const int lane = t & 63;
    const int wv = t >> 6;
    const int arow = wv * 16 + (lane & 15);
    const int kb = (lane >> 4) * 8;
    const int bcol = lane & 15;
    const int m = bm + arow;
    const bool mok = (m < M);
    const ushort* Ar = A + (size_t)m * 1536 + kb;
    const short8v z8 = {0, 0, 0, 0, 0, 0, 0, 0};
    short8v breg[8];
    #pragma unroll
    for (int i = 0; i < 8; i++) {
        int li = t + i * 256;
        int r = li >> 5, g = li & 31;
        breg[i] = *(const short8v*)(Wt + (size_t)(bn + r) * 1536 + g * 8);
    }
    short8v aH[2][4], aL[2][4];
    #pragma unroll
    for (int kc = 0; kc < 4; kc++) {
        aH[0][kc] = mok ? *(const short8v*)(Ar + kc * 32) : z8;
        aL[0][kc] = mok ? *(const short8v*)(Ar + 768 + kc * 32) : z8;
    }
    float4v acc[4] = {{0.f, 0.f, 0.f, 0.f}, {0.f, 0.f, 0.f, 0.f},
                      {0.f, 0.f, 0.f, 0.f}, {0.f, 0.f, 0.f, 0.f}};
    #pragma unroll
    for (int c = 0; c < 6; c++) {
        const int cur = c & 1, nxt = cur ^ 1;
        __syncthreads();
        #pragma unroll
        for (int i = 0; i < 8; i++) {
            int li = t + i * 256;
            int r = li >> 5, g = li & 31;
            *(short8v*)&Bs[r][g * 8] = breg[i];
        }
        __syncthreads();
        if (c < 5) {
            #pragma unroll
            for (int i = 0; i < 8; i++) {
                int li = t + i * 256;
                int r = li >> 5, g = li & 31;
                breg[i] = *(const short8v*)(Wt + (size_t)(bn + r) * 1536 + (c + 1) * 256 + g * 8);
            }
            #pragma unroll
            for (int kc = 0; kc < 4; kc++) {
                aH[nxt][kc] = mok ? *(const short8v*)(Ar + (c + 1) * 128 + kc * 32) : z8;
                aL[nxt][kc] = mok ? *(const short8v*)(Ar + 768 + (c + 1) * 128 + kc * 32) : z8;
            }
        }
        #pragma unroll
        for (int kc = 0; kc < 4; kc++) {
            short8v ah = aH[cur][kc];
            short8v al = aL[cur][kc];
            #pragma unroll
            for (int f = 0; f < 4; f++) {
                short8v bh = *(const short8v*)&Bs[f * 16 + bcol][kc * 32 + kb];
                short8v bl = *(const short8v*)&Bs[f * 16 + bcol][128 + kc * 32 + kb];
                acc[f] = __builtin_amdgcn_mfma_f32_16x16x32_bf16(ah, bh, acc[f], 0, 0, 0);
                acc[f] = __builtin_amdgcn_mfma_f32_16x16x32_bf16(al, bh, acc[f], 0, 0, 0);
                acc[f] = __builtin_amdgcn_mfma_f32_16x16x32_bf16(ah, bl, acc[f], 0, 0, 0);
            }
        }
    }
    const int rb = bm + wv * 16 + ((lane >> 4) << 2);
    float ind[4];
    #pragma unroll
    for (int r = 0; r < 4; r++) {
        int row = rb + r;
        ind[r] = (row < M && rp[row + 1] > rp[row]) ? 1.f : 0.f;
    }
    #pragma unroll
    for (int f = 0; f < 4; f++) {
        int col = bn + f * 16 + bcol;
        float bv = bvm[col];
        #pragma unroll
        for (int r = 0; r < 4; r++) {
            int row = rb + r;
            if (row >= M) continue;
            size_t idx = (size_t)row * 128 + col;
            float val = acc[f][r] + ind[r] * bv;
            if (HASSEED) val += seed[idx];
            out[idx] += val;
        }
    }
}

// ---------------------------------------------------------------------------
// Fused attention: 32 lanes per dst (2 dsts per wave), float4 per lane.
// alpha = (A1[dst]·x_s + U[dst]·ea + kvec[src])/sqrt(128).
// A1/U are stored as fp16 (half read traffic); converted to fp32 on load.
// Reduce: DPP VALU tree (4 levels) + one xor-16 shfl.
// 3-deep rotating edge prefetch covers gather latency.
// YZ written as split-bf16 [hi(768)|lo(768)] ushorts per row for gemm_yz.
// (bv-indicator handled in gemm_yz epilogue via rp — no output RMW here.)
template <int EMODE>
__global__ __launch_bounds__(256) void attn_fused(
        const _Float16* __restrict__ A1, const _Float16* __restrict__ U,
        const float* __restrict__ X, const float* __restrict__ Esrc,
        const float* __restrict__ kvec, const int2* __restrict__ epack,
        const int* __restrict__ rp,
        ushort* __restrict__ YZ, int n_dst) {
    int dst = (int)((blockIdx.x * (size_t)blockDim.x + threadIdx.x) >> 5);
    int lane = threadIdx.x & 31;
    if (dst >= n_dst) return;
    const _Float16* ap = A1 + (size_t)dst * 384;
    const _Float16* up = U + (size_t)dst * 384;
    float4 a1[3], u[3], y[3], za[3];
    float m[3], den[3];
    #pragma unroll
    for (int h = 0; h < 3; h++) {
        half4v av = *(const half4v*)(ap + h * 128 + lane * 4);
        half4v uv = *(const half4v*)(up + h * 128 + lane * 4);
        a1[h] = make_float4((float)av[0], (float)av[1], (float)av[2], (float)av[3]);
        u[h] = make_float4((float)uv[0], (float)uv[1], (float)uv[2], (float)uv[3]);
        y[h] = make_float4(0.f, 0.f, 0.f, 0.f);
        za[h] = make_float4(0.f, 0.f, 0.f, 0.f);
        m[h] = -INFINITY;
        den[h] = 0.f;
    }
    int beg = rp[dst], end = rp[dst + 1];
    auto loadE = [&](int e, float4& xs, float4& ea, float4& kv) {
        int2 sp = epack[e];
        xs = *(const float4*)(X + (size_t)sp.x * 128 + lane * 4);
        if (EMODE == 0) {
            ea = *(const float4*)(Esrc + (size_t)sp.y * 128 + lane * 4);
        } else {
            float sgn = (float)sp.y;
            ea = make_float4(xs.x * sgn, xs.y * sgn, xs.z * sgn, xs.w * sgn);
        }
        kv = *(const float4*)(kvec + (size_t)sp.x * 4);
    };
    float4 xA, eA, kA, xB, eB, kB;
    if (beg < end) loadE(beg, xA, eA, kA);
    if (beg + 1 < end) loadE(beg + 1, xB, eB, kB);
    for (int e = beg; e < end; e++) {
        float4 xC, eC, kC;
        if (e + 2 < end) loadE(e + 2, xC, eC, kC);
        float dot[3];
        #pragma unroll
        for (int h = 0; h < 3; h++)
            dot[h] = a1[h].x * xA.x + a1[h].y * xA.y +
                     a1[h].z * xA.z + a1[h].w * xA.w +
                     u[h].x * eA.x + u[h].y * eA.y +
                     u[h].z * eA.z + u[h].w * eA.w;
        #pragma unroll
        for (int h = 0; h < 3; h++) dot[h] = rsum32(dot[h]);
        float kvh[3] = {kA.x, kA.y, kA.z};
        #pragma unroll
        for (int h = 0; h < 3; h++) {
            float a = (dot[h] + kvh[h]) * 0.08838834764831845f;  // 1/sqrt(128)
            float mn = fmaxf(m[h], a);
            float scale = __expf(m[h] - mn);  // first edge: exp(-inf)=0
            float w = __expf(a - mn);
            den[h] = den[h] * scale + w;
            y[h].x = y[h].x * scale + w * xA.x;
            y[h].y = y[h].y * scale + w * xA.y;
            y[h].z = y[h].z * scale + w * xA.z;
            y[h].w = y[h].w * scale + w * xA.w;
            za[h].x = za[h].x * scale + w * eA.x;
            za[h].y = za[h].y * scale + w * eA.y;
            za[h].z = za[h].z * scale + w * eA.z;
            za[h].w = za[h].w * scale + w * eA.w;
            m[h] = mn;
        }
        xA = xB; eA = eB; kA = kB;
        xB = xC; eB = eC; kB = kC;
    }
    ushort* yrow = YZ + (size_t)dst * 1536;
    #pragma unroll
    for (int h = 0; h < 3; h++) {
        float inv = 1.f / (den[h] + 1e-16f) * (1.f / 3.f);
        float vy[4] = {y[h].x * inv, y[h].y * inv, y[h].z * inv, y[h].w * inv};
        float vz[4] = {za[h].x * inv, za[h].y * inv, za[h].z * inv, za[h].w * inv};
        ushort hy[4], ly[4], hz[4], lz[4];
        #pragma unroll
        for (int jj = 0; jj < 4; jj++) {
            hy[jj] = f2b(vy[jj]);
            ly[jj] = f2b(vy[jj] - b2f(hy[jj]));
            hz[jj] = f2b(vz[jj]);
            lz[jj] = f2b(vz[jj] - b2f(hz[jj]));
        }
        *(uint2*)(yrow + h * 128 + lane * 4) =
            make_uint2((uint)hy[0] | ((uint)hy[1] << 16), (uint)hy[2] | ((uint)hy[3] << 16));
        *(uint2*)(yrow + 768 + h * 128 + lane * 4) =
            make_uint2((uint)ly[0] | ((uint)ly[1] << 16), (uint)ly[2] | ((uint)ly[3] << 16));
        *(uint2*)(yrow + 384 + h * 128 + lane * 4) =
            make_uint2((uint)hz[0] | ((uint)hz[1] << 16), (uint)hz[2] | ((uint)hz[3] << 16));
        *(uint2*)(yrow + 768 + 384 + h * 128 + lane * 4) =
            make_uint2((uint)lz[0] | ((uint)lz[1] << 16), (uint)lz[2] | ((uint)lz[3] << 16));
    }
}

// ---------------------------------------------------------------------------
extern "C" void kernel_launch(void* const* d_in, const int* in_sizes, int n_in,
                              void* d_out, int out_size, void* d_ws, size_t ws_size,
                              hipStream_t stream) {
    const float* h_dE  = (const float*)d_in[0];
    const float* h_dF  = (const float*)d_in[1];
    const int*   cob   = (const int*)d_in[2];
    const int*   nn    = (const int*)d_in[3];
    const float* aggrW = (const float*)d_in[4];
    const float* aggrB = (const float*)d_in[5];
    const float* ctrW  = (const float*)d_in[6];
    const float* ctrB  = (const float*)d_in[7];
    const float* f_Wq  = (const float*)d_in[8];
    const float* f_bq  = (const float*)d_in[9];
    const float* f_Wk  = (const float*)d_in[10];
    const float* f_bk  = (const float*)d_in[11];
    const float* f_Wv  = (const float*)d_in[12];
    const float* f_bv  = (const float*)d_in[13];
    const float* f_We  = (const float*)d_in[14];
    const float* f_Ws  = (const float*)d_in[15];
    const float* f_bs  = (const float*)d_in[16];
    const float* e_Wq  = (const float*)d_in[17];
    const float* e_bq  = (const float*)d_in[18];
    const float* e_Wk  = (const float*)d_in[19];
    const float* e_bk  = (const float*)d_in[20];
    const float* e_Wv  = (const float*)d_in[21];
    const float* e_bv  = (const float*)d_in[22];
    const float* e_We  = (const float*)d_in[23];
    const float* e_Ws  = (const float*)d_in[24];
    const float* e_bs  = (const float*)d_in[25];

    const int CH = 25000;  // stage-4 dst chunk

    // ---- workspace ----
    char* base = (char*)d_ws;
    size_t off = 0;
    auto takeB = [&](size_t bytes) {
        char* p = base + off;
        off += (bytes + 15) & ~(size_t)15;
        return p;
    };
    float*  h     = (float*)takeB((size_t)F_Nc * 128 * 4);
    _Float16* A1f = (_Float16*)takeB((size_t)CH * 384 * 2);
    _Float16* Uf  = (_Float16*)takeB((size_t)CH * 384 * 2);
    float*  YZb   = (float*)takeB((size_t)CH * 768 * 4);  // YZ bf16 rows / fp32 scratch
    float*  Kvb   = (float*)takeB((size_t)CH * 4 * 4);
    float*  Wu32  = (float*)takeB((size_t)12 * 16384 * 4);
    float*  G32   = (float*)takeB((size_t)12 * 16384 * 4);
    float*  wkb32 = (float*)takeB((size_t)4 * 384 * 4);
    float*  biasPool = (float*)takeB(4608 * 4);
    ushort* WtPool = (ushort*)takeB((size_t)2200000 * 2);
    int* rp_nn   = (int*)takeB((F_Nc + 1) * 4);
    int* rp_cobE = (int*)takeB((E_Nc + 1) * 4);
    int* rp_cobF = (int*)takeB((F_Nc + 1) * 4);
    int2* epk_nn = (int2*)takeB((size_t)P_Nc * 8);
    int2* epk_cE = (int2*)takeB((size_t)M_Nc * 8);
    int2* epk_cF = (int2*)takeB((size_t)M_Nc * 8);
    int* cnt_nn  = (int*)takeB((size_t)F_Nc * 4);
    int* cnt_cE  = (int*)takeB((size_t)E_Nc * 4);
    int* cnt_cF  = (int*)takeB((size_t)F_Nc * 4);
    int* bsum3   = (int*)takeB(3 * 64 * 4);
    if (ws_size < off) return;  // fail loud, not a fault

    const int BLK = 256;
    float* dout = (float*)d_out;
    ushort* YZu = (ushort*)YZb;

    const float* Wq4[4] = {f_Wq, f_Wq + 49152, f_Wq + 98304, e_Wq};
    const float* Wk4[4] = {f_Wk, f_Wk + 49152, f_Wk + 98304, e_Wk};
    const float* Wv4[4] = {f_Wv, f_Wv + 49152, f_Wv + 98304, e_Wv};
    const float* We4[4] = {f_We, f_We + 49152, f_We + 98304, e_We};
    const float* Ws4[4] = {f_Ws, f_Ws + 16384, f_Ws + 32768, e_Ws};
    const float* bq4[4] = {f_bq, f_bq + 384, f_bq + 768, e_bq};
    const float* bv4[4] = {f_bv, f_bv + 384, f_bv + 768, e_bv};

    // ---- derived weights (fp32) ----
    zero_f<<<cdiv(4608, BLK), BLK, 0, stream>>>(biasPool, 4608);
    GuArgs gua;
    BuArgs bua;
    WkbArgs wka;
    BvArgs bva;
    for (int l = 0; l < 4; l++) {
        gua.wq[l] = Wq4[l]; gua.we[l] = We4[l]; gua.wk[l] = Wk4[l];
        bua.bq[l] = bq4[l]; bua.we[l] = We4[l];
        wka.wk[l] = Wk4[l]; wka.bq[l] = bq4[l];
        bva.bv[l] = bv4[l];
    }
    compute_gu<<<cdiv(2 * 12 * 16384, BLK), BLK, 0, stream>>>(gua, Wu32, G32);
    bias_u<<<cdiv(12 * 128, BLK), BLK, 0, stream>>>(bua, biasPool);
    wkb_k<<<cdiv(4 * 384, BLK), BLK, 0, stream>>>(wka, wkb32);
    bvmean_k<<<cdiv(4 * 128, BLK), BLK, 0, stream>>>(bva, biasPool);

    // ---- bias copies: bs into xproj bias slots ----
    BDescs bd;
    int bi = 0;
    auto addb = [&](const float* s, int o, int n2) { bd.d[bi].src = s; bd.d[bi].dstoff = o; bd.d[bi].n = n2; bi++; };
    for (int l = 0; l < 3; l++) addb(f_bs + l * 128, l * 960 + 832, 128);
    addb(e_bs, 2880 + 768, 128);
    copy_bias<<<dim3(1, 4), BLK, 0, stream>>>(bd, biasPool);

    // ---- weight prep descriptors (split [hi|lo]) ----
    WDescs wd;
    int dc = 0;
    long wto = 0;
    auto addw = [&](const float* in, int ldin, int coloff, long outoff,
                    int NN, int KK, int trans, int ldo) {
        wd.d[dc].in = in; wd.d[dc].ldin = ldin; wd.d[dc].coloff = coloff;
        wd.d[dc].outoff = outoff; wd.d[dc].NN = NN; wd.d[dc].KK = KK;
        wd.d[dc].trans = trans; wd.d[dc].ldo = ldo; dc++;
    };
    long wx[3], w4e, w4h, wyz[4], waggr, wctr;
    for (int l = 0; l < 3; l++) {
        wx[l] = wto;
        addw(G32 + (long)l * 49152, 128, 0, wto, 384, 128, 0, 256);
        addw(Wu32 + (long)l * 49152, 128, 0, wto + 384L * 256, 384, 128, 0, 256);
        addw(wkb32 + (long)l * 384, 128, 0, wto + 768L * 256, 3, 128, 0, 256);
        addw(Ws4[l], 128, 0, wto + 832L * 256, 128, 128, 1, 256);
        wto += 960L * 256;
    }
    w4e = wto;
    addw(G32 + 3L * 49152, 128, 0, wto, 384, 128, 0, 256);
    addw(Wu32 + 3L * 49152, 128, 0, wto + 384L * 256, 384, 128, 0, 256);
    addw(e_Ws, 128, 0, wto + 768L * 256, 128, 128, 1, 256);
    wto += 896L * 256;
    w4h = wto;
    addw(wkb32 + 3L * 384, 128, 0, wto, 3, 128, 0, 256);
    wto += 64L * 256;
    for (int l = 0; l < 4; l++) {
        wyz[l] = wto;
        for (int hh = 0; hh < 3; hh++) {
            addw(Wv4[l], 384, hh * 128, wto + hh * 256, 128, 128, 1, 1536);
            addw(We4[l], 384, hh * 128, wto + (3 + hh) * 256, 128, 128, 1, 1536);
        }
        wto += 128L * 1536;
    }
    waggr = wto; addw(aggrW, 128, 0, wto, 128, 128, 1, 256); wto += 128 * 256;
    wctr  = wto; addw(ctrW,  128, 0, wto, 128, 128, 1, 256); wto += 128 * 256;
    wd.cnt = dc;  // 42
    prep_weights<<<dim3(192, dc), BLK, 0, stream>>>(wd, WtPool);

    // ---- batched CSR builds (7 dispatches) ----
    CsrJobs cj;
    cj.j[0] = {nn, 1, 0, P_Nc, F_Nc, cnt_nn, rp_nn, epk_nn, bsum3};
    cj.j[1] = {cob, 0, 1, M_Nc, E_Nc, cnt_cE, rp_cobE, epk_cE, bsum3 + 64};
    cj.j[2] = {cob, 1, 0, M_Nc, F_Nc, cnt_cF, rp_cobF, epk_cF, bsum3 + 128};
    csr_zero<<<dim3(cdiv(E_Nc, BLK), 3), BLK, 0, stream>>>(cj);
    csr_count<<<dim3(cdiv(M_Nc, BLK), 3), BLK, 0, stream>>>(cj);
    csr_scan_partial<<<dim3(cdiv(E_Nc, 1024), 3), BLK, 0, stream>>>(cj);
    csr_scan_bsum<<<dim3(1, 3), 64, 0, stream>>>(cj);
    csr_scan_final<<<dim3(cdiv(E_Nc, 1024), 3), BLK, 0, stream>>>(cj);
    csr_zero<<<dim3(cdiv(E_Nc, BLK), 3), BLK, 0, stream>>>(cj);
    csr_scatter<<<dim3(cdiv(M_Nc, BLK), 3), BLK, 0, stream>>>(cj);

    // ---- stage 1: aggr (fp32, in YZb scratch) ----
    cob_gather<<<cdiv((long)F_Nc * 64, BLK), BLK, 0, stream>>>(
        h_dE, epk_cF, rp_cobF, YZb, F_Nc);

    // ---- stage 2: h = aggr@aggrW + aggrB + h_dF@ctrW + ctrB ----
    gemm_split<0, true><<<dim3(cdiv(F_Nc, 64), 2, 1), BLK, 0, stream>>>(
        YZb, 128, WtPool + waggr, 256, aggrB, h, 128, F_Nc, 128, 128);
    gemm_split<1, true><<<dim3(cdiv(F_Nc, 64), 2, 1), BLK, 0, stream>>>(
        h_dF, 128, WtPool + wctr, 256, ctrB, h, 128, F_Nc, 128, 128);

    const int NXB = cdiv(F_Nc, 64);  // 391

    // ---- stage 3: three residual attention layers ----
    for (int l = 0; l < 3; l++) {
        SegInfo s3;
        s3.base[0] = (float*)A1f; s3.ld[0] = 384; s3.f16[0] = 1;
        s3.base[1] = (float*)Uf;  s3.ld[1] = 384; s3.f16[1] = 1;
        s3.base[2] = Kvb; s3.ld[2] = 4;  s3.f16[2] = 0;  // 3 kvec cols, col<ld guard
        s3.base[3] = dout; s3.ld[3] = 128; s3.f16[3] = 0; // Ws-skip + bs seeded
        s3.base[4] = nullptr; s3.ld[4] = 0; s3.f16[4] = 0;
        s3.start[0] = 0; s3.start[1] = 384; s3.start[2] = 768;
        s3.start[3] = 832; s3.start[4] = 960; s3.start[5] = 960;
        s3.nseg = 4;
        gemm_xproj<<<dim3(NXB * 5), BLK, 0, stream>>>(
            h, 128, F_Nc, WtPool + wx[l], biasPool + l * 960, s3, 5);
        attn_fused<0><<<cdiv((long)F_Nc * 32, BLK), BLK, 0, stream>>>(
            A1f, Uf, h, h_dE, Kvb, epk_nn, rp_nn, YZu, F_Nc);
        gemm_yz<true><<<dim3(NXB * 2), BLK, 0, stream>>>(
            YZu, WtPool + wyz[l], dout, h, rp_nn,
            biasPool + 3840 + l * 128, F_Nc);
    }

    // ---- stage 4: final attention F -> E ----
    {   // kvec for all F src nodes (from h)
        SegInfo s4h;
        s4h.base[0] = Kvb; s4h.ld[0] = 4; s4h.f16[0] = 0;
        s4h.base[1] = nullptr; s4h.base[2] = nullptr; s4h.base[3] = nullptr; s4h.base[4] = nullptr;
        s4h.ld[1] = 0; s4h.ld[2] = 0; s4h.ld[3] = 0; s4h.ld[4] = 0;
        s4h.f16[1] = 0; s4h.f16[2] = 0; s4h.f16[3] = 0; s4h.f16[4] = 0;
        s4h.start[0] = 0; s4h.start[1] = 64; s4h.start[2] = 64;
        s4h.start[3] = 64; s4h.start[4] = 64; s4h.start[5] = 64;
        s4h.nseg = 1;
        gemm_xproj<<<dim3(NXB), BLK, 0, stream>>>(
            h, 128, F_Nc, WtPool + w4h, biasPool + 3776, s4h, 1);
    }
    for (int c = 0; c < 2; c++) {
        int c0 = c * CH;
        SegInfo s4e;
        s4e.base[0] = (float*)A1f; s4e.ld[0] = 384; s4e.f16[0] = 1;
        s4e.base[1] = (float*)Uf;  s4e.ld[1] = 384; s4e.f16[1] = 1;
        s4e.base[2] = dout + (size_t)c0 * 128; s4e.ld[2] = 128; s4e.f16[2] = 0;
        s4e.base[3] = nullptr; s4e.base[4] = nullptr; s4e.ld[3] = 0; s4e.ld[4] = 0;
        s4e.f16[3] = 0; s4e.f16[4] = 0;
        s4e.start[0] = 0; s4e.start[1] = 384; s4e.start[2] = 768;
        s4e.start[3] = 896; s4e.start[4] = 896; s4e.start[5] = 896;
        s4e.nseg = 3;
        gemm_xproj<<<dim3(cdiv(CH, 64) * 5), BLK, 0, stream>>>(
            h_dE + (size_t)c0 * 128, 128, CH, WtPool + w4e, biasPool + 2880, s4e, 5);
        attn_fused<1><<<cdiv((long)CH * 32, BLK), BLK, 0, stream>>>(
            A1f, Uf, h, h, Kvb, epk_cE, rp_cobE + c0, YZu, CH);
        gemm_yz<false><<<dim3(cdiv(CH, 64) * 2), BLK, 0, stream>>>(
            YZu, WtPool + wyz[3], nullptr, dout + (size_t)c0 * 128, rp_cobE + c0,
            biasPool + 4224, CH);
    }
}

// Round 14
// 600.952 us; speedup vs baseline: 1.8391x; 1.1956x over previous
//
#include <hip/hip_runtime.h>
#include <math.h>

#define E_Nc 50000
#define F_Nc 25000
#define M_Nc 100000
#define P_Nc 75000
// D=128, HD=384, HEADS=3, DH=128

typedef unsigned short ushort;
typedef unsigned int uint;
typedef __attribute__((ext_vector_type(8))) short short8v;
typedef __attribute__((ext_vector_type(4))) float float4v;
typedef __attribute__((ext_vector_type(4))) _Float16 half4v;
typedef __attribute__((ext_vector_type(8))) _Float16 half8v;

static inline int cdiv(long a, long b) { return (int)((a + b - 1) / b); }

// ---------------------------------------------------------------------------
__device__ inline ushort f2b(float f) {  // RNE fp32 -> bf16
    uint u = __float_as_uint(f);
    u += 0x7fffu + ((u >> 16) & 1u);
    return (ushort)(u >> 16);
}
__device__ inline float b2f(ushort b) { return __uint_as_float((uint)b << 16); }

// Bijective XCD-chunked block swizzle (m204).
__device__ inline int xcd_swz(int bid, int nb) {
    int q = nb >> 3, r = nb & 7;
    int xcd = bid & 7, w = bid >> 3;
    return (xcd < r ? xcd * (q + 1) : r * (q + 1) + (xcd - r) * q) + w;
}

// 32-lane sum (within each 32-half of the wave), result in all lanes.
__device__ inline float rsum32(float v) {
    v += __uint_as_float(__builtin_amdgcn_update_dpp(
        0, __float_as_uint(v), 0xB1, 0xF, 0xF, true));   // quad_perm xor1
    v += __uint_as_float(__builtin_amdgcn_update_dpp(
        0, __float_as_uint(v), 0x4E, 0xF, 0xF, true));   // quad_perm xor2
    v += __uint_as_float(__builtin_amdgcn_update_dpp(
        0, __float_as_uint(v), 0x124, 0xF, 0xF, true));  // row_ror:4
    v += __uint_as_float(__builtin_amdgcn_update_dpp(
        0, __float_as_uint(v), 0x128, 0xF, 0xF, true));  // row_ror:8
    v += __shfl_xor(v, 16);
    return v;
}

// ---------------------------------------------------------------------------
__global__ void zero_f(float* __restrict__ p, int n) {
    int i = blockIdx.x * blockDim.x + threadIdx.x;
    if (i < n) p[i] = 0.f;
}

// ---------------------------------------------------------------------------
// Batched CSR build: 3 graphs in y-indexed jobs, 7 dispatches total.
// Scatter writes packed {src, aux} per edge.
struct CsrJob {
    const int* idx3;
    int col, srccol, P, n;
    int* cnt;
    int* rp;
    int2* epack;
    int* bsum;
};
struct CsrJobs { CsrJob j[3]; };

__global__ __launch_bounds__(256) void csr_zero(CsrJobs js) {
    const CsrJob& j = js.j[blockIdx.y];
    int i = blockIdx.x * 256 + threadIdx.x;
    if (i < j.n) j.cnt[i] = 0;
}

__global__ __launch_bounds__(256) void csr_count(CsrJobs js) {
    const CsrJob& j = js.j[blockIdx.y];
    int i = blockIdx.x * 256 + threadIdx.x;
    if (i < j.P) atomicAdd(&j.cnt[j.idx3[(size_t)i * 3 + j.col]], 1);
}

__global__ __launch_bounds__(256) void csr_scan_partial(CsrJobs js) {
    const CsrJob& j = js.j[blockIdx.y];
    __shared__ int lds[256];
    int b = blockIdx.x, t = threadIdx.x;
    int base = b * 1024 + t * 4;
    int s = 0;
    #pragma unroll
    for (int k = 0; k < 4; k++) { int i = base + k; if (i < j.n) s += j.cnt[i]; }
    lds[t] = s;
    __syncthreads();
    for (int off = 128; off > 0; off >>= 1) {
        if (t < off) lds[t] += lds[t + off];
        __syncthreads();
    }
    if (t == 0) j.bsum[b] = lds[0];
}

__global__ __launch_bounds__(64) void csr_scan_bsum(CsrJobs js) {
    const CsrJob& j = js.j[blockIdx.y];
    __shared__ int lds[64];
    int t = threadIdx.x;
    int v = j.bsum[t];
    lds[t] = v;
    __syncthreads();
    for (int off = 1; off < 64; off <<= 1) {
        int x = (t >= off) ? lds[t - off] : 0;
        __syncthreads();
        lds[t] += x;
        __syncthreads();
    }
    j.bsum[t] = lds[t] - v;  // exclusive
}

__global__ __launch_bounds__(256) void csr_scan_final(CsrJobs js) {
    const CsrJob& j = js.j[blockIdx.y];
    __shared__ int lds[256];
    int b = blockIdx.x, t = threadIdx.x;
    int base = b * 1024 + t * 4;
    int v[4];
    int s = 0;
    #pragma unroll
    for (int k = 0; k < 4; k++) {
        int i = base + k;
        v[k] = (i < j.n) ? j.cnt[i] : 0;
        s += v[k];
    }
    lds[t] = s;
    __syncthreads();
    for (int off = 1; off < 256; off <<= 1) {
        int x = (t >= off) ? lds[t - off] : 0;
        __syncthreads();
        lds[t] += x;
        __syncthreads();
    }
    int pre = j.bsum[b] + lds[t] - s;
    #pragma unroll
    for (int k = 0; k < 4; k++) {
        int i = base + k;
        if (i < j.n) j.rp[i] = pre;
        pre += v[k];
        if (i == j.n - 1) j.rp[j.n] = pre;
    }
}

__global__ __launch_bounds__(256) void csr_scatter(CsrJobs js) {
    const CsrJob& j = js.j[blockIdx.y];
    int i = blockIdx.x * 256 + threadIdx.x;
    if (i >= j.P) return;
    const int* row = j.idx3 + (size_t)i * 3;
    int d = row[j.col];
    int pos = atomicAdd(&j.cnt[d], 1);
    int2 pk;
    pk.x = row[j.srccol];
    pk.y = row[2];
    j.epack[j.rp[d] + pos] = pk;
}

// ---------------------------------------------------------------------------
// Wu_h = Wq_h @ We_h^T and G_h = Wq_h @ Wk_h^T (both fp32)
struct GuArgs { const float* wq[4]; const float* we[4]; const float* wk[4]; };
__global__ __launch_bounds__(256) void compute_gu(GuArgs a,
        float* __restrict__ Wu32, float* __restrict__ G32) {
    int idx = blockIdx.x * 256 + threadIdx.x;
    if (idx >= 2 * 12 * 16384) return;
    int sel = idx / (12 * 16384);
    int rem0 = idx - sel * (12 * 16384);
    int lh = rem0 >> 14;
    int l = lh / 3, h = lh - l * 3;
    int rem = rem0 & 16383;
    int c = rem >> 7, d = rem & 127;
    const float* Wq = a.wq[l];
    const float* Wo = sel ? a.wk[l] : a.we[l];
    float s = 0.f;
    #pragma unroll 4
    for (int jj = 0; jj < 128; jj++)
        s += Wq[d * 384 + h * 128 + jj] * Wo[c * 384 + h * 128 + jj];
    (sel ? G32 : Wu32)[rem0] = s;
}

// wkb[l][h*128+d] = sum_j Wk_l[d, h*128+j] * bq_l[h*128+j]
struct WkbArgs { const float* wk[4]; const float* bq[4]; };
__global__ void wkb_k(WkbArgs a, float* __restrict__ wkb32) {
    int idx = blockIdx.x * blockDim.x + threadIdx.x;
    if (idx >= 4 * 384) return;
    int l = idx / 384;
    int r = idx - l * 384;
    int h = r >> 7, d = r & 127;
    const float* Wk = a.wk[l];
    const float* bq = a.bq[l];
    float s = 0.f;
    for (int jj = 0; jj < 128; jj++)
        s += Wk[d * 384 + h * 128 + jj] * bq[h * 128 + jj];
    wkb32[idx] = s;
}

// bvm[l][c] = mean_h bv_l[h*128+c] -> biasPool slots
struct BvArgs { const float* bv[4]; };
__global__ void bvmean_k(BvArgs a, float* __restrict__ pool) {
    int idx = blockIdx.x * blockDim.x + threadIdx.x;
    if (idx >= 4 * 128) return;
    int l = idx >> 7, c = idx & 127;
    float v = (a.bv[l][c] + a.bv[l][128 + c] + a.bv[l][256 + c]) * (1.f / 3.f);
    pool[(l < 3 ? 3840 + l * 128 : 4224) + c] = v;
}

// bu_h[c] = sum_j bq_h[j] * We[c, h*128+j] -> biasPool slots
struct BuArgs { const float* bq[4]; const float* we[4]; };
__global__ void bias_u(BuArgs a, float* __restrict__ pool) {
    int idx = blockIdx.x * blockDim.x + threadIdx.x;
    if (idx >= 12 * 128) return;
    int lh = idx >> 7, c = idx & 127;
    int l = lh / 3, h = lh - l * 3;
    const float* bq = a.bq[l];
    const float* We = a.we[l];
    float s = 0.f;
    for (int jj = 0; jj < 128; jj++)
        s += bq[h * 128 + jj] * We[c * 384 + h * 128 + jj];
    int slot = (l < 3) ? (l * 960 + 384 + h * 128 + c)
                       : (2880 + 384 + h * 128 + c);
    pool[slot] = s;
}

// plain bias copies into biasPool
struct BDesc { const float* src; int dstoff, n; };
struct BDescs { BDesc d[8]; };
__global__ void copy_bias(BDescs ds, float* __restrict__ pool) {
    const BDesc b = ds.d[blockIdx.y];
    int i = blockIdx.x * 256 + threadIdx.x;
    if (i < b.n) pool[b.dstoff + i] = b.src[i];
}

// ---------------------------------------------------------------------------
// Weight prep: split fp32 weight into bf16 [hi(KK) | lo(KK)] rows, or
// (f16o=1) single IEEE fp16 value per element.
struct WDesc {
    const float* in;
    long outoff;
    int ldin, coloff, NN, KK, trans, ldo, f16o;
};
struct WDescs { WDesc d[44]; int cnt; };

__global__ __launch_bounds__(256) void prep_weights(WDescs ds, ushort* __restrict__ out) {
    const WDesc w = ds.d[blockIdx.y];
    int i = blockIdx.x * 256 + threadIdx.x;
    if (i >= w.NN * w.KK) return;
    int n = i / w.KK, k = i - n * w.KK;
    float v = w.trans ? w.in[(size_t)k * w.ldin + w.coloff + n]
                      : w.in[(size_t)n * w.ldin + w.coloff + k];
    long ro = w.outoff + (size_t)n * w.ldo;
    if (w.f16o) {
        _Float16 hv = (_Float16)v;
        out[ro + k] = *(ushort*)&hv;
    } else {
        ushort hi = f2b(v);
        ushort lo = f2b(v - b2f(hi));
        out[ro + k] = hi;
        out[ro + w.KK + k] = lo;
    }
}

// ---------------------------------------------------------------------------
// CSR gather (fp32 out): aggr[f] = sum sgn * h_dE[e]
__global__ __launch_bounds__(256) void cob_gather(
        const float* __restrict__ h_dE, const int2* __restrict__ epack,
        const int* __restrict__ rp, float* __restrict__ out, int Fn) {
    int wave = (int)((blockIdx.x * (size_t)blockDim.x + threadIdx.x) >> 6);
    int lane = threadIdx.x & 63;
    if (wave >= Fn) return;
    float2 s = make_float2(0.f, 0.f);
    int beg = rp[wave], end = rp[wave + 1];
    for (int e = beg; e < end; e++) {
        int2 sp = epack[e];
        float sg = (float)sp.y;
        float2 v = *(const float2*)(h_dE + (size_t)sp.x * 128 + lane * 2);
        s.x += sg * v.x;
        s.y += sg * v.y;
    }
    *(float2*)(out + (size_t)wave * 128 + lane * 2) = s;
}

// ---------------------------------------------------------------------------
// Persistent-A split-bf16 x-projection GEMM (K = 128, 3-term fp32-accurate).
// Flattened grid + XCD-chunked swizzle. Store guard col < ldc allows narrow
// segments (Kvb ld=4 holds only 3 meaningful kvec cols).
// Per-segment f16 flag: A1/U segments are stored as IEEE fp16.
#define TPB 3
struct SegInfo {
    float* base[5];
    int ld[5];
    int f16[5];
    int start[6];
    int nseg;
};

__global__ __launch_bounds__(256) void gemm_xproj(
        const float* __restrict__ A, int lda, int M,
        const ushort* __restrict__ Wt,
        const float* __restrict__ biasAll,
        SegInfo segs, int nys) {
    __shared__ ushort LDSu[64][264];  // A-stage, then B-tile [hi | lo]
    const int j = xcd_swz(blockIdx.x, gridDim.x);
    const int ys = j % nys;
    const int bm = (j / nys) * 64;
    const int t = threadIdx.x;
    const int lane = t & 63;
    const int wv = t >> 6;
    #pragma unroll
    for (int i = 0; i < 8; i++) {
        int li = t + i * 256;
        int r = li >> 5, q4 = li & 31;
        int m = bm + r;
        float4 v = make_float4(0.f, 0.f, 0.f, 0.f);
        if (m < M) v = *(const float4*)(A + (size_t)m * lda + q4 * 4);
        ushort h0 = f2b(v.x), h1 = f2b(v.y), h2 = f2b(v.z), h3 = f2b(v.w);
        ushort l0 = f2b(v.x - b2f(h0)), l1 = f2b(v.y - b2f(h1));
        ushort l2 = f2b(v.z - b2f(h2)), l3 = f2b(v.w - b2f(h3));
        *(uint2*)&LDSu[r][q4 * 4] =
            make_uint2((uint)h0 | ((uint)h1 << 16), (uint)h2 | ((uint)h3 << 16));
        *(uint2*)&LDSu[r][128 + q4 * 4] =
            make_uint2((uint)l0 | ((uint)l1 << 16), (uint)l2 | ((uint)l3 << 16));
    }
    __syncthreads();
    const int arow = wv * 16 + (lane & 15);
    const int kb = (lane >> 4) * 8;
    const int bcol = lane & 15;
    short8v a_hi[4], a_lo[4];
    #pragma unroll
    for (int kc = 0; kc < 4; kc++) {
        a_hi[kc] = *(const short8v*)&LDSu[arow][kc * 32 + kb];
        a_lo[kc] = *(const short8v*)&LDSu[arow][128 + kc * 32 + kb];
    }
    const int Ntot = segs.start[segs.nseg];
    const int bn0 = ys * (TPB * 64);
    const int bn1 = min(bn0 + TPB * 64, Ntot);
    if (bn0 >= Ntot) return;
    short8v breg[8];
    #pragma unroll
    for (int i = 0; i < 8; i++) {
        int li = t + i * 256;
        int r = li >> 5, g = li & 31;
        breg[i] = *(const short8v*)(Wt + (size_t)(bn0 + r) * 256 + g * 8);
    }
    int seg = 0;
    while (bn0 >= segs.start[seg + 1]) seg++;
    for (int bn = bn0; bn < bn1; bn += 64) {
        while (bn >= segs.start[seg + 1]) seg++;
        __syncthreads();
        #pragma unroll
        for (int i = 0; i < 8; i++) {
            int li = t + i * 256;
            int r = li >> 5, g = li & 31;
            *(short8v*)&LDSu[r][g * 8] = breg[i];
        }
        __syncthreads();
        if (bn + 64 < bn1) {
            #pragma unroll
            for (int i = 0; i < 8; i++) {
                int li = t + i * 256;
                int r = li >> 5, g = li & 31;
                breg[i] = *(const short8v*)(Wt + (size_t)(bn + 64 + r) * 256 + g * 8);
            }
        }
        float4v acc[4] = {{0.f, 0.f, 0.f, 0.f}, {0.f, 0.f, 0.f, 0.f},
                          {0.f, 0.f, 0.f, 0.f}, {0.f, 0.f, 0.f, 0.f}};
        #pragma unroll
        for (int kc = 0; kc < 4; kc++) {
            #pragma unroll
            for (int f = 0; f < 4; f++) {
                short8v bh = *(const short8v*)&LDSu[f * 16 + bcol][kc * 32 + kb];
                short8v bl = *(const short8v*)&LDSu[f * 16 + bcol][128 + kc * 32 + kb];
                acc[f] = __builtin_amdgcn_mfma_f32_16x16x32_bf16(a_hi[kc], bh, acc[f], 0, 0, 0);
                acc[f] = __builtin_amdgcn_mfma_f32_16x16x32_bf16(a_lo[kc], bh, acc[f], 0, 0, 0);
                acc[f] = __builtin_amdgcn_mfma_f32_16x16x32_bf16(a_hi[kc], bl, acc[f], 0, 0, 0);
            }
        }
        float* Cb = segs.base[seg];
        const int ldc = segs.ld[seg];
        const int coff = segs.start[seg];
        const int isf16 = segs.f16[seg];
        const int rb = bm + wv * 16 + ((lane >> 4) << 2);
        #pragma unroll
        for (int f = 0; f < 4; f++) {
            int ng = bn + f * 16 + bcol;
            float bias = biasAll[ng];
            int col = ng - coff;
            #pragma unroll
            for (int r = 0; r < 4; r++) {
                int row = rb + r;
                if (row < M && col < ldc) {
                    float val = acc[f][r] + bias;
                    if (isf16) {
                        ((_Float16*)Cb)[(size_t)row * ldc + col] = (_Float16)val;
                    } else {
                        Cb[(size_t)row * ldc + col] = val;
                    }
                }
            }
        }
    }
}

// ---------------------------------------------------------------------------
// Split-bf16 3-term GEMM, direct-register A (stage 2 only).
template <int OUTM, bool HASBIAS>
__global__ __launch_bounds__(256) void gemm_split(
        const float* __restrict__ A, int lda,
        const ushort* __restrict__ Wt, int ldw,
        const float* __restrict__ bias,
        float* __restrict__ C, int ldc,
        int M, int N, int kper) {
    __shared__ ushort Bs[64][264];
    const int koff = blockIdx.z * kper;
    const int bm = blockIdx.x * 64;
    const int bn = blockIdx.y * 64;
    const int t = threadIdx.x;
    const int lane = t & 63;
    const int wv = t >> 6;
    const int arow = wv * 16 + (lane & 15);
    const int kb = (lane >> 4) * 8;
    const int bcol = lane & 15;
    const int m = bm + arow;
    const bool mok = (m < M);
    const float* Arow = A + (size_t)m * lda + koff + kb;
    float4v acc[4] = {{0.f, 0.f, 0.f, 0.f}, {0.f, 0.f, 0.f, 0.f},
                      {0.f, 0.f, 0.f, 0.f}, {0.f, 0.f, 0.f, 0.f}};
    short8v breg[8];
    #pragma unroll
    for (int i = 0; i < 8; i++) {
        int li = t + i * 256;
        int r = li >> 5, g = li & 31;
        breg[i] = *(const short8v*)(Wt + (size_t)(bn + r) * ldw + (koff >> 7) * 256 + g * 8);
    }
    for (int c = 0; c < kper; c += 128) {
        __syncthreads();
        #pragma unroll
        for (int i = 0; i < 8; i++) {
            int li = t + i * 256;
            int r = li >> 5, g = li & 31;
            *(short8v*)&Bs[r][g * 8] = breg[i];
        }
        __syncthreads();
        if (c + 128 < kper) {
            const int nchunk = (koff + c + 128) >> 7;
            #pragma unroll
            for (int i = 0; i < 8; i++) {
                int li = t + i * 256;
                int r = li >> 5, g = li & 31;
                breg[i] = *(const short8v*)(Wt + (size_t)(bn + r) * ldw + nchunk * 256 + g * 8);
            }
        }
        short8v a_hi[4], a_lo[4];
        #pragma unroll
        for (int kc = 0; kc < 4; kc++) {
            float4 v0 = make_float4(0.f, 0.f, 0.f, 0.f);
            float4 v1 = make_float4(0.f, 0.f, 0.f, 0.f);
            if (mok) {
                v0 = *(const float4*)(Arow + c + kc * 32);
                v1 = *(const float4*)(Arow + c + kc * 32 + 4);
            }
            union { short8v v; ushort u[8]; } hi, lo;
            float vv[8] = {v0.x, v0.y, v0.z, v0.w, v1.x, v1.y, v1.z, v1.w};
            #pragma unroll
            for (int jj = 0; jj < 8; jj++) {
                ushort hj = f2b(vv[jj]);
                hi.u[jj] = hj;
                lo.u[jj] = f2b(vv[jj] - b2f(hj));
            }
            a_hi[kc] = hi.v;
            a_lo[kc] = lo.v;
        }
        #pragma unroll
        for (int kc = 0; kc < 4; kc++) {
            #pragma unroll
            for (int f = 0; f < 4; f++) {
                short8v bh = *(const short8v*)&Bs[f * 16 + bcol][kc * 32 + kb];
                short8v bl = *(const short8v*)&Bs[f * 16 + bcol][128 + kc * 32 + kb];
                acc[f] = __builtin_amdgcn_mfma_f32_16x16x32_bf16(a_hi[kc], bh, acc[f], 0, 0, 0);
                acc[f] = __builtin_amdgcn_mfma_f32_16x16x32_bf16(a_lo[kc], bh, acc[f], 0, 0, 0);
                acc[f] = __builtin_amdgcn_mfma_f32_16x16x32_bf16(a_hi[kc], bl, acc[f], 0, 0, 0);
            }
        }
    }
    const int rb = bm + wv * 16 + ((lane >> 4) << 2);
    #pragma unroll
    for (int f = 0; f < 4; f++) {
        int col = bn + f * 16 + bcol;
        #pragma unroll
        for (int r = 0; r < 4; r++) {
            int row = rb + r;
            if (row >= M) continue;
            float val = acc[f][r];
            if (HASBIAS) val += bias[col];
            size_t idx = (size_t)row * ldc + col;
            if (OUTM == 0) {
                C[idx] = val;
            } else if (OUTM == 1) {
                C[idx] += val;
            } else {
                atomicAdd(&C[idx], val);
            }
        }
    }
}

// ---------------------------------------------------------------------------
// YZ -> out projection GEMM, fp16 single-term (native f16 MFMA).
// A row: 768 fp16 (written by attn_fused); W row: 768 fp16.
// Block = 64 rows x 64 cols, K=768 in 6 chunks; ping-pong A regs + B breg
// prefetch through LDS. Epilogue fuses bv-indicator and residual add:
//   HASSEED=true  (stage 3): out[idx] += acc + seed[idx] + ind*bv  (out=h)
//   HASSEED=false (stage 4): out[idx] += acc + ind*bv  (out=dout, pre-seeded)
template <bool HASSEED>
__global__ __launch_bounds__(256) void gemm_yz(
        const ushort* __restrict__ A,
        const ushort* __restrict__ Wt,
        const float* __restrict__ seed,
        float* __restrict__ out,
        const int* __restrict__ rp,
        const float* __restrict__ bvm, int M) {
    __shared__ ushort Bs[64][136];
    const int j = xcd_swz(blockIdx.x, gridDim.x);
    const int by = j & 1;
    const int bm = (j >> 1) * 64;
    const int bn = by * 64;
    const int t = threadIdx.x;
    const int lane = t & 63;
    const int wv = t >> 6;
    const int arow = wv * 16 + (lane & 15);
    const int kb = (lane >> 4) * 8;
    const int bcol = lane & 15;
    const int m = bm + arow;
    const bool mok = (m < M);
    const ushort* Ar = A + (size_t)m * 768 + kb;
    const half8v z8 = {0, 0, 0, 0, 0, 0, 0, 0};
    short8v breg[4];
    #pragma unroll
    for (int i = 0; i < 4; i++) {
        int li = t + i * 256;
        int r = li >> 4, g = li & 15;
        breg[i] = *(const short8v*)(Wt + (size_t)(bn + r) * 768 + g * 8);
    }
    half8v aF[2][4];
    #pragma unroll
    for (int kc = 0; kc < 4; kc++)
        aF[0][kc] = mok ? *(const half8v*)(Ar + kc * 32) : z8;
    float4v acc[4] = {{0.f, 0.f, 0.f, 0.f}, {0.f, 0.f, 0.f, 0.f},
                      {0.f, 0.f, 0.f, 0.f}, {0.f, 0.f, 0.f, 0.f}};
    #pragma unroll
    for (int c = 0; c < 6; c++) {
        const int cur = c & 1, nxt = cur ^ 1;
        __syncthreads();
        #pragma unroll
        for (int i = 0; i < 4; i++) {
            int li = t + i * 256;
            int r = li >> 4, g = li & 15;
            *(short8v*)&Bs[r][g * 8] = breg[i];
        }
        __syncthreads();
        if (c < 5) {
            #pragma unroll
            for (int i = 0; i < 4; i++) {
                int li = t + i * 256;
                int r = li >> 4, g = li & 15;
                breg[i] = *(const short8v*)(Wt + (size_t)(bn + r) * 768 + (c + 1) * 128 + g * 8);
            }
            #pragma unroll
            for (int kc = 0; kc < 4; kc++)
                aF[nxt][kc] = mok ? *(const half8v*)(Ar + (c + 1) * 128 + kc * 32) : z8;
        }
        #pragma unroll
        for (int kc = 0; kc < 4; kc++) {
            half8v ah = aF[cur][kc];
            #pragma unroll
            for (int f = 0; f < 4; f++) {
                half8v bh = *(const half8v*)&Bs[f * 16 + bcol][kc * 32 + kb];
                acc[f] = __builtin_amdgcn_mfma_f32_16x16x32_f16(ah, bh, acc[f], 0, 0, 0);
            }
        }
    }
    const int rb = bm + wv * 16 + ((lane >> 4) << 2);
    float ind[4];
    #pragma unroll
    for (int r = 0; r < 4; r++) {
        int row = rb + r;
        ind[r] = (row < M && rp[row + 1] > rp[row]) ? 1.f : 0.f;
    }
    #pragma unroll
    for (int f = 0; f < 4; f++) {
        int col = bn + f * 16 + bcol;
        float bv = bvm[col];
        #pragma unroll
        for (int r = 0; r < 4; r++) {
            int row = rb + r;
            if (row >= M) continue;
            size_t idx = (size_t)row * 128 + col;
            float val = acc[f][r] + ind[r] * bv;
            if (HASSEED) val += seed[idx];
            out[idx] += val;
        }
    }
}

// ---------------------------------------------------------------------------
// Fused attention: 32 lanes per dst (2 dsts per wave), float4 per lane.
// alpha = (A1[dst]·x_s + U[dst]·ea + kvec[src])/sqrt(128).
// A1/U are stored as fp16 (half read traffic); converted to fp32 on load.
// YZ written as fp16 [y(384)|z(384)] per row for the f16-MFMA gemm_yz.
// Reduce: DPP VALU tree (4 levels) + one xor-16 shfl.
// 3-deep rotating edge prefetch covers gather latency.
template <int EMODE>
__global__ __launch_bounds__(256) void attn_fused(
        const _Float16* __restrict__ A1, const _Float16* __restrict__ U,
        const float* __restrict__ X, const float* __restrict__ Esrc,
        const float* __restrict__ kvec, const int2* __restrict__ epack,
        const int* __restrict__ rp,
        ushort* __restrict__ YZ, int n_dst) {
    int dst = (int)((blockIdx.x * (size_t)blockDim.x + threadIdx.x) >> 5);
    int lane = threadIdx.x & 31;
    if (dst >= n_dst) return;
    const _Float16* ap = A1 + (size_t)dst * 384;
    const _Float16* up = U + (size_t)dst * 384;
    float4 a1[3], u[3], y[3], za[3];
    float m[3], den[3];
    #pragma unroll
    for (int h = 0; h < 3; h++) {
        half4v av = *(const half4v*)(ap + h * 128 + lane * 4);
        half4v uv = *(const half4v*)(up + h * 128 + lane * 4);
        a1[h] = make_float4((float)av[0], (float)av[1], (float)av[2], (float)av[3]);
        u[h] = make_float4((float)uv[0], (float)uv[1], (float)uv[2], (float)uv[3]);
        y[h] = make_float4(0.f, 0.f, 0.f, 0.f);
        za[h] = make_float4(0.f, 0.f, 0.f, 0.f);
        m[h] = -INFINITY;
        den[h] = 0.f;
    }
    int beg = rp[dst], end = rp[dst + 1];
    auto loadE = [&](int e, float4& xs, float4& ea, float4& kv) {
        int2 sp = epack[e];
        xs = *(const float4*)(X + (size_t)sp.x * 128 + lane * 4);
        if (EMODE == 0) {
            ea = *(const float4*)(Esrc + (size_t)sp.y * 128 + lane * 4);
        } else {
            float sgn = (float)sp.y;
            ea = make_float4(xs.x * sgn, xs.y * sgn, xs.z * sgn, xs.w * sgn);
        }
        kv = *(const float4*)(kvec + (size_t)sp.x * 4);
    };
    float4 xA, eA, kA, xB, eB, kB;
    if (beg < end) loadE(beg, xA, eA, kA);
    if (beg + 1 < end) loadE(beg + 1, xB, eB, kB);
    for (int e = beg; e < end; e++) {
        float4 xC, eC, kC;
        if (e + 2 < end) loadE(e + 2, xC, eC, kC);
        float dot[3];
        #pragma unroll
        for (int h = 0; h < 3; h++)
            dot[h] = a1[h].x * xA.x + a1[h].y * xA.y +
                     a1[h].z * xA.z + a1[h].w * xA.w +
                     u[h].x * eA.x + u[h].y * eA.y +
                     u[h].z * eA.z + u[h].w * eA.w;
        #pragma unroll
        for (int h = 0; h < 3; h++) dot[h] = rsum32(dot[h]);
        float kvh[3] = {kA.x, kA.y, kA.z};
        #pragma unroll
        for (int h = 0; h < 3; h++) {
            float a = (dot[h] + kvh[h]) * 0.08838834764831845f;  // 1/sqrt(128)
            float mn = fmaxf(m[h], a);
            float scale = __expf(m[h] - mn);  // first edge: exp(-inf)=0
            float w = __expf(a - mn);
            den[h] = den[h] * scale + w;
            y[h].x = y[h].x * scale + w * xA.x;
            y[h].y = y[h].y * scale + w * xA.y;
            y[h].z = y[h].z * scale + w * xA.z;
            y[h].w = y[h].w * scale + w * xA.w;
            za[h].x = za[h].x * scale + w * eA.x;
            za[h].y = za[h].y * scale + w * eA.y;
            za[h].z = za[h].z * scale + w * eA.z;
            za[h].w = za[h].w * scale + w * eA.w;
            m[h] = mn;
        }
        xA = xB; eA = eB; kA = kB;
        xB = xC; eB = eC; kB = kC;
    }
    ushort* yrow = YZ + (size_t)dst * 768;
    #pragma unroll
    for (int h = 0; h < 3; h++) {
        float inv = 1.f / (den[h] + 1e-16f) * (1.f / 3.f);
        half4v hy, hz;
        hy[0] = (_Float16)(y[h].x * inv);
        hy[1] = (_Float16)(y[h].y * inv);
        hy[2] = (_Float16)(y[h].z * inv);
        hy[3] = (_Float16)(y[h].w * inv);
        hz[0] = (_Float16)(za[h].x * inv);
        hz[1] = (_Float16)(za[h].y * inv);
        hz[2] = (_Float16)(za[h].z * inv);
        hz[3] = (_Float16)(za[h].w * inv);
        *(half4v*)(yrow + h * 128 + lane * 4) = hy;
        *(half4v*)(yrow + 384 + h * 128 + lane * 4) = hz;
    }
}

// ---------------------------------------------------------------------------
extern "C" void kernel_launch(void* const* d_in, const int* in_sizes, int n_in,
                              void* d_out, int out_size, void* d_ws, size_t ws_size,
                              hipStream_t stream) {
    const float* h_dE  = (const float*)d_in[0];
    const float* h_dF  = (const float*)d_in[1];
    const int*   cob   = (const int*)d_in[2];
    const int*   nn    = (const int*)d_in[3];
    const float* aggrW = (const float*)d_in[4];
    const float* aggrB = (const float*)d_in[5];
    const float* ctrW  = (const float*)d_in[6];
    const float* ctrB  = (const float*)d_in[7];
    const float* f_Wq  = (const float*)d_in[8];
    const float* f_bq  = (const float*)d_in[9];
    const float* f_Wk  = (const float*)d_in[10];
    const float* f_bk  = (const float*)d_in[11];
    const float* f_Wv  = (const float*)d_in[12];
    const float* f_bv  = (const float*)d_in[13];
    const float* f_We  = (const float*)d_in[14];
    const float* f_Ws  = (const float*)d_in[15];
    const float* f_bs  = (const float*)d_in[16];
    const float* e_Wq  = (const float*)d_in[17];
    const float* e_bq  = (const float*)d_in[18];
    const float* e_Wk  = (const float*)d_in[19];
    const float* e_bk  = (const float*)d_in[20];
    const float* e_Wv  = (const float*)d_in[21];
    const float* e_bv  = (const float*)d_in[22];
    const float* e_We  = (const float*)d_in[23];
    const float* e_Ws  = (const float*)d_in[24];
    const float* e_bs  = (const float*)d_in[25];

    const int CH = 25000;  // stage-4 dst chunk

    // ---- workspace ----
    char* base = (char*)d_ws;
    size_t off = 0;
    auto takeB = [&](size_t bytes) {
        char* p = base + off;
        off += (bytes + 15) & ~(size_t)15;
        return p;
    };
    float*  h     = (float*)takeB((size_t)F_Nc * 128 * 4);
    _Float16* A1f = (_Float16*)takeB((size_t)CH * 384 * 2);
    _Float16* Uf  = (_Float16*)takeB((size_t)CH * 384 * 2);
    float*  YZb   = (float*)takeB((size_t)CH * 768 * 2);  // fp16 YZ / fp32 scratch
    float*  Kvb   = (float*)takeB((size_t)CH * 4 * 4);
    float*  Wu32  = (float*)takeB((size_t)12 * 16384 * 4);
    float*  G32   = (float*)takeB((size_t)12 * 16384 * 4);
    float*  wkb32 = (float*)takeB((size_t)4 * 384 * 4);
    float*  biasPool = (float*)takeB(4608 * 4);
    ushort* WtPool = (ushort*)takeB((size_t)2200000 * 2);
    int* rp_nn   = (int*)takeB((F_Nc + 1) * 4);
    int* rp_cobE = (int*)takeB((E_Nc + 1) * 4);
    int* rp_cobF = (int*)takeB((F_Nc + 1) * 4);
    int2* epk_nn = (int2*)takeB((size_t)P_Nc * 8);
    int2* epk_cE = (int2*)takeB((size_t)M_Nc * 8);
    int2* epk_cF = (int2*)takeB((size_t)M_Nc * 8);
    int* cnt_nn  = (int*)takeB((size_t)F_Nc * 4);
    int* cnt_cE  = (int*)takeB((size_t)E_Nc * 4);
    int* cnt_cF  = (int*)takeB((size_t)F_Nc * 4);
    int* bsum3   = (int*)takeB(3 * 64 * 4);
    if (ws_size < off) return;  // fail loud, not a fault

    const int BLK = 256;
    float* dout = (float*)d_out;
    ushort* YZu = (ushort*)YZb;

    const float* Wq4[4] = {f_Wq, f_Wq + 49152, f_Wq + 98304, e_Wq};
    const float* Wk4[4] = {f_Wk, f_Wk + 49152, f_Wk + 98304, e_Wk};
    const float* Wv4[4] = {f_Wv, f_Wv + 49152, f_Wv + 98304, e_Wv};
    const float* We4[4] = {f_We, f_We + 49152, f_We + 98304, e_We};
    const float* Ws4[4] = {f_Ws, f_Ws + 16384, f_Ws + 32768, e_Ws};
    const float* bq4[4] = {f_bq, f_bq + 384, f_bq + 768, e_bq};
    const float* bv4[4] = {f_bv, f_bv + 384, f_bv + 768, e_bv};

    // ---- derived weights (fp32) ----
    zero_f<<<cdiv(4608, BLK), BLK, 0, stream>>>(biasPool, 4608);
    GuArgs gua;
    BuArgs bua;
    WkbArgs wka;
    BvArgs bva;
    for (int l = 0; l < 4; l++) {
        gua.wq[l] = Wq4[l]; gua.we[l] = We4[l]; gua.wk[l] = Wk4[l];
        bua.bq[l] = bq4[l]; bua.we[l] = We4[l];
        wka.wk[l] = Wk4[l]; wka.bq[l] = bq4[l];
        bva.bv[l] = bv4[l];
    }
    compute_gu<<<cdiv(2 * 12 * 16384, BLK), BLK, 0, stream>>>(gua, Wu32, G32);
    bias_u<<<cdiv(12 * 128, BLK), BLK, 0, stream>>>(bua, biasPool);
    wkb_k<<<cdiv(4 * 384, BLK), BLK, 0, stream>>>(wka, wkb32);
    bvmean_k<<<cdiv(4 * 128, BLK), BLK, 0, stream>>>(bva, biasPool);

    // ---- bias copies: bs into xproj bias slots ----
    BDescs bd;
    int bi = 0;
    auto addb = [&](const float* s, int o, int n2) { bd.d[bi].src = s; bd.d[bi].dstoff = o; bd.d[bi].n = n2; bi++; };
    for (int l = 0; l < 3; l++) addb(f_bs + l * 128, l * 960 + 832, 128);
    addb(e_bs, 2880 + 768, 128);
    copy_bias<<<dim3(1, 4), BLK, 0, stream>>>(bd, biasPool);

    // ---- weight prep descriptors ----
    WDescs wd;
    int dc = 0;
    long wto = 0;
    auto addw = [&](const float* in, int ldin, int coloff, long outoff,
                    int NN, int KK, int trans, int ldo, int f16o) {
        wd.d[dc].in = in; wd.d[dc].ldin = ldin; wd.d[dc].coloff = coloff;
        wd.d[dc].outoff = outoff; wd.d[dc].NN = NN; wd.d[dc].KK = KK;
        wd.d[dc].trans = trans; wd.d[dc].ldo = ldo; wd.d[dc].f16o = f16o; dc++;
    };
    long wx[3], w4e, w4h, wyz[4], waggr, wctr;
    for (int l = 0; l < 3; l++) {
        wx[l] = wto;
        addw(G32 + (long)l * 49152, 128, 0, wto, 384, 128, 0, 256, 0);
        addw(Wu32 + (long)l * 49152, 128, 0, wto + 384L * 256, 384, 128, 0, 256, 0);
        addw(wkb32 + (long)l * 384, 128, 0, wto + 768L * 256, 3, 128, 0, 256, 0);
        addw(Ws4[l], 128, 0, wto + 832L * 256, 128, 128, 1, 256, 0);
        wto += 960L * 256;
    }
    w4e = wto;
    addw(G32 + 3L * 49152, 128, 0, wto, 384, 128, 0, 256, 0);
    addw(Wu32 + 3L * 49152, 128, 0, wto + 384L * 256, 384, 128, 0, 256, 0);
    addw(e_Ws, 128, 0, wto + 768L * 256, 128, 128, 1, 256, 0);
    wto += 896L * 256;
    w4h = wto;
    addw(wkb32 + 3L * 384, 128, 0, wto, 3, 128, 0, 256, 0);
    wto += 64L * 256;
    for (int l = 0; l < 4; l++) {
        wyz[l] = wto;
        for (int hh = 0; hh < 3; hh++) {
            addw(Wv4[l], 384, hh * 128, wto + hh * 128, 128, 128, 1, 768, 1);
            addw(We4[l], 384, hh * 128, wto + 384 + hh * 128, 128, 128, 1, 768, 1);
        }
        wto += 128L * 768;
    }
    waggr = wto; addw(aggrW, 128, 0, wto, 128, 128, 1, 256, 0); wto += 128 * 256;
    wctr  = wto; addw(ctrW,  128, 0, wto, 128, 128, 1, 256, 0); wto += 128 * 256;
    wd.cnt = dc;  // 42
    prep_weights<<<dim3(192, dc), BLK, 0, stream>>>(wd, WtPool);

    // ---- batched CSR builds (7 dispatches) ----
    CsrJobs cj;
    cj.j[0] = {nn, 1, 0, P_Nc, F_Nc, cnt_nn, rp_nn, epk_nn, bsum3};
    cj.j[1] = {cob, 0, 1, M_Nc, E_Nc, cnt_cE, rp_cobE, epk_cE, bsum3 + 64};
    cj.j[2] = {cob, 1, 0, M_Nc, F_Nc, cnt_cF, rp_cobF, epk_cF, bsum3 + 128};
    csr_zero<<<dim3(cdiv(E_Nc, BLK), 3), BLK, 0, stream>>>(cj);
    csr_count<<<dim3(cdiv(M_Nc, BLK), 3), BLK, 0, stream>>>(cj);
    csr_scan_partial<<<dim3(cdiv(E_Nc, 1024), 3), BLK, 0, stream>>>(cj);
    csr_scan_bsum<<<dim3(1, 3), 64, 0, stream>>>(cj);
    csr_scan_final<<<dim3(cdiv(E_Nc, 1024), 3), BLK, 0, stream>>>(cj);
    csr_zero<<<dim3(cdiv(E_Nc, BLK), 3), BLK, 0, stream>>>(cj);
    csr_scatter<<<dim3(cdiv(M_Nc, BLK), 3), BLK, 0, stream>>>(cj);

    // ---- stage 1: aggr (fp32, in YZb scratch) ----
    cob_gather<<<cdiv((long)F_Nc * 64, BLK), BLK, 0, stream>>>(
        h_dE, epk_cF, rp_cobF, YZb, F_Nc);

    // ---- stage 2: h = aggr@aggrW + aggrB + h_dF@ctrW + ctrB ----
    gemm_split<0, true><<<dim3(cdiv(F_Nc, 64), 2, 1), BLK, 0, stream>>>(
        YZb, 128, WtPool + waggr, 256, aggrB, h, 128, F_Nc, 128, 128);
    gemm_split<1, true><<<dim3(cdiv(F_Nc, 64), 2, 1), BLK, 0, stream>>>(
        h_dF, 128, WtPool + wctr, 256, ctrB, h, 128, F_Nc, 128, 128);

    const int NXB = cdiv(F_Nc, 64);  // 391

    // ---- stage 3: three residual attention layers ----
    for (int l = 0; l < 3; l++) {
        SegInfo s3;
        s3.base[0] = (float*)A1f; s3.ld[0] = 384; s3.f16[0] = 1;
        s3.base[1] = (float*)Uf;  s3.ld[1] = 384; s3.f16[1] = 1;
        s3.base[2] = Kvb; s3.ld[2] = 4;  s3.f16[2] = 0;  // 3 kvec cols, col<ld guard
        s3.base[3] = dout; s3.ld[3] = 128; s3.f16[3] = 0; // Ws-skip + bs seeded
        s3.base[4] = nullptr; s3.ld[4] = 0; s3.f16[4] = 0;
        s3.start[0] = 0; s3.start[1] = 384; s3.start[2] = 768;
        s3.start[3] = 832; s3.start[4] = 960; s3.start[5] = 960;
        s3.nseg = 4;
        gemm_xproj<<<dim3(NXB * 5), BLK, 0, stream>>>(
            h, 128, F_Nc, WtPool + wx[l], biasPool + l * 960, s3, 5);
        attn_fused<0><<<cdiv((long)F_Nc * 32, BLK), BLK, 0, stream>>>(
            A1f, Uf, h, h_dE, Kvb, epk_nn, rp_nn, YZu, F_Nc);
        gemm_yz<true><<<dim3(NXB * 2), BLK, 0, stream>>>(
            YZu, WtPool + wyz[l], dout, h, rp_nn,
            biasPool + 3840 + l * 128, F_Nc);
    }

    // ---- stage 4: final attention F -> E ----
    {   // kvec for all F src nodes (from h)
        SegInfo s4h;
        s4h.base[0] = Kvb; s4h.ld[0] = 4; s4h.f16[0] = 0;
        s4h.base[1] = nullptr; s4h.base[2] = nullptr; s4h.base[3] = nullptr; s4h.base[4] = nullptr;
        s4h.ld[1] = 0; s4h.ld[2] = 0; s4h.ld[3] = 0; s4h.ld[4] = 0;
        s4h.f16[1] = 0; s4h.f16[2] = 0; s4h.f16[3] = 0; s4h.f16[4] = 0;
        s4h.start[0] = 0; s4h.start[1] = 64; s4h.start[2] = 64;
        s4h.start[3] = 64; s4h.start[4] = 64; s4h.start[5] = 64;
        s4h.nseg = 1;
        gemm_xproj<<<dim3(NXB), BLK, 0, stream>>>(
            h, 128, F_Nc, WtPool + w4h, biasPool + 3776, s4h, 1);
    }
    for (int c = 0; c < 2; c++) {
        int c0 = c * CH;
        SegInfo s4e;
        s4e.base[0] = (float*)A1f; s4e.ld[0] = 384; s4e.f16[0] = 1;
        s4e.base[1] = (float*)Uf;  s4e.ld[1] = 384; s4e.f16[1] = 1;
        s4e.base[2] = dout + (size_t)c0 * 128; s4e.ld[2] = 128; s4e.f16[2] = 0;
        s4e.base[3] = nullptr; s4e.base[4] = nullptr; s4e.ld[3] = 0; s4e.ld[4] = 0;
        s4e.f16[3] = 0; s4e.f16[4] = 0;
        s4e.start[0] = 0; s4e.start[1] = 384; s4e.start[2] = 768;
        s4e.start[3] = 896; s4e.start[4] = 896; s4e.start[5] = 896;
        s4e.nseg = 3;
        gemm_xproj<<<dim3(cdiv(CH, 64) * 5), BLK, 0, stream>>>(
            h_dE + (size_t)c0 * 128, 128, CH, WtPool + w4e, biasPool + 2880, s4e, 5);
        attn_fused<1><<<cdiv((long)CH * 32, BLK), BLK, 0, stream>>>(
            A1f, Uf, h, h, Kvb, epk_cE, rp_cobE + c0, YZu, CH);
        gemm_yz<false><<<dim3(cdiv(CH, 64) * 2), BLK, 0, stream>>>(
            YZu, WtPool + wyz[3], nullptr, dout + (size_t)c0 * 128, rp_cobE + c0,
            biasPool + 4224, CH);
    }
}